// Round 3
// baseline (787.260 us; speedup 1.0000x reference)
//
#include <hip/hip_runtime.h>
#include <math.h>

#define NN    4096
#define DM    128
#define NHD   8
#define HDD   16
#define NE    131072
#define ATT_SCALE 0.25f

static __device__ __forceinline__ float cl(float v) {
  return fminf(fmaxf(v, -1e4f), 1e4f);   // true |values| < ~100; kills garbage exponents
}

// ---------------- sentinel fill (ws_size guard telemetry) ----------------
__global__ __launch_bounds__(256) void k_fill(float* __restrict__ out, float v, int n) {
  int i = blockIdx.x * 256 + threadIdx.x;
  if (i < n) out[i] = v;
}

// ---------------- edge_index layout detect: int64 (odd words all 0) vs int32 ----------------
__global__ void k_detect(const int* __restrict__ EI, int* __restrict__ flag) {
  int v = EI[2 * threadIdx.x + 1];
  for (int off = 1; off < 64; off <<= 1) v |= __shfl_xor(v, off);
  if (threadIdx.x == 0) *flag = (v == 0) ? 1 : 0;
}

// ---------------- generic GEMM:  C[m,n] = epi( sum_k A[m,k]*W[n,k] + Bias[n] ) ----------------
// A = concat(A0[:, :ksplit], A1[:, :K-ksplit]); fp32 everywhere, fp32 accum.
// act: 0 = none, 1 = exact gelu, 2 = gate: g=sigmoid(v); out = g*E0[oi] + (1-g)*E1[oi]
__global__ __launch_bounds__(256) void gemm_bt(
    const float* __restrict__ A0, int lda0,
    const float* __restrict__ A1, int lda1, int ksplit,
    const float* __restrict__ Wt, const float* __restrict__ Bias,
    const float* __restrict__ Res,
    const float* __restrict__ E0, const float* __restrict__ E1,
    float* __restrict__ C, int Nt, int K, int act)
{
  __shared__ float As[16][68];
  __shared__ float Ws[16][68];
  const int m0 = blockIdx.x * 64;
  const int n0 = blockIdx.y * 64;
  const int tid = threadIdx.x;
  const int tx = tid & 15, ty = tid >> 4;
  const int lmm = tid >> 2;          // 0..63: row within tile
  const int lkk = (tid & 3) * 4;     // 0,4,8,12: k within 16-chunk
  float acc[4][4] = {};

  for (int k0 = 0; k0 < K; k0 += 16) {
    const int kg = k0 + lkk;
    float4 av;
    if (kg < ksplit)
      av = *(const float4*)(A0 + (size_t)(m0 + lmm) * lda0 + kg);
    else
      av = *(const float4*)(A1 + (size_t)(m0 + lmm) * lda1 + (kg - ksplit));
    const float4 wv = *(const float4*)(Wt + (size_t)(n0 + lmm) * K + kg);
    __syncthreads();
    As[lkk+0][lmm] = cl(av.x); As[lkk+1][lmm] = cl(av.y);
    As[lkk+2][lmm] = cl(av.z); As[lkk+3][lmm] = cl(av.w);
    Ws[lkk+0][lmm] = cl(wv.x); Ws[lkk+1][lmm] = cl(wv.y);
    Ws[lkk+2][lmm] = cl(wv.z); Ws[lkk+3][lmm] = cl(wv.w);
    __syncthreads();
#pragma unroll
    for (int kk = 0; kk < 16; ++kk) {
      float a[4], b[4];
#pragma unroll
      for (int i = 0; i < 4; i++) a[i] = As[kk][ty*4+i];
#pragma unroll
      for (int j = 0; j < 4; j++) b[j] = Ws[kk][tx*4+j];
#pragma unroll
      for (int i = 0; i < 4; i++)
#pragma unroll
        for (int j = 0; j < 4; j++) acc[i][j] = fmaf(a[i], b[j], acc[i][j]);
    }
  }
#pragma unroll
  for (int i = 0; i < 4; i++) {
    const int m = m0 + ty*4 + i;
#pragma unroll
    for (int j = 0; j < 4; j++) {
      const int n = n0 + tx*4 + j;
      float v = acc[i][j] + cl(Bias[n]);
      size_t oi = (size_t)m * Nt + n;
      if (act == 1) {
        v = 0.5f * v * (1.0f + erff(v * 0.70710678118654752f));
      } else if (act == 2) {
        float g = 1.0f / (1.0f + __expf(fminf(fmaxf(-v, -80.f), 80.f)));
        v = g * E0[oi] + (1.0f - g) * E1[oi];
      }
      if (Res) v += Res[oi];
      C[oi] = v;
    }
  }
}

// ---------------- LayerNorm (one wave per 128-wide row) ----------------
__global__ __launch_bounds__(256) void k_ln(const float* __restrict__ X,
    const float* __restrict__ G, const float* __restrict__ B, float* __restrict__ O) {
  int row = blockIdx.x * 4 + (threadIdx.x >> 6);
  int lane = threadIdx.x & 63;
  float v0 = cl(X[(size_t)row*DM + lane]);
  float v1 = cl(X[(size_t)row*DM + 64 + lane]);
  float s = v0 + v1;
  for (int off = 1; off < 64; off <<= 1) s += __shfl_xor(s, off);
  float mean = s * (1.0f/128.0f);
  float d0 = v0 - mean, d1 = v1 - mean;
  float s2 = d0*d0 + d1*d1;
  for (int off = 1; off < 64; off <<= 1) s2 += __shfl_xor(s2, off);
  float rstd = rsqrtf(s2 * (1.0f/128.0f) + 1e-5f);
  O[(size_t)row*DM + lane]      = d0*rstd*cl(G[lane])    + cl(B[lane]);
  O[(size_t)row*DM + 64 + lane] = d1*rstd*cl(G[64+lane]) + cl(B[64+lane]);
}

// h = x + relu(ln(T, G, B))
__global__ __launch_bounds__(256) void k_ln_relu_res(const float* __restrict__ T,
    const float* __restrict__ G, const float* __restrict__ B,
    const float* __restrict__ X, float* __restrict__ H) {
  int row = blockIdx.x * 4 + (threadIdx.x >> 6);
  int lane = threadIdx.x & 63;
  float v0 = cl(T[(size_t)row*DM + lane]);
  float v1 = cl(T[(size_t)row*DM + 64 + lane]);
  float s = v0 + v1;
  for (int off = 1; off < 64; off <<= 1) s += __shfl_xor(s, off);
  float mean = s * (1.0f/128.0f);
  float d0 = v0 - mean, d1 = v1 - mean;
  float s2 = d0*d0 + d1*d1;
  for (int off = 1; off < 64; off <<= 1) s2 += __shfl_xor(s2, off);
  float rstd = rsqrtf(s2 * (1.0f/128.0f) + 1e-5f);
  float f0 = d0*rstd*cl(G[lane])    + cl(B[lane]);
  float f1 = d1*rstd*cl(G[64+lane]) + cl(B[64+lane]);
  f0 = f0 > 0.f ? f0 : 0.f;
  f1 = f1 > 0.f ? f1 : 0.f;
  H[(size_t)row*DM + lane]      = cl(X[(size_t)row*DM + lane]) + f0;
  H[(size_t)row*DM + 64 + lane] = cl(X[(size_t)row*DM + 64 + lane]) + f1;
}

// ---------------- edge attention ----------------
// exp(score) per (edge, head) -> EB; segment-sum into SS[dst,h] via atomics.
// No segment-max (softmax invariant; scores ~N(0,1); exp clamped for safety).
__global__ __launch_bounds__(256) void k_edge_attn(const int* __restrict__ EI,
    const int* __restrict__ FLG,
    const float* __restrict__ Q, const float* __restrict__ Kl,
    float* __restrict__ EB, float* __restrict__ SS) {
  int e = blockIdx.x * 256 + threadIdx.x;
  if (e >= NE) return;
  int is64 = *FLG;
  int s = is64 ? EI[2*e]        : EI[e];
  int d = is64 ? EI[2*(NE+e)]   : EI[NE+e];
  s = min(max(s, 0), NN-1); d = min(max(d, 0), NN-1);
  const float4* q4 = (const float4*)(Q  + (size_t)d * DM);
  const float4* k4 = (const float4*)(Kl + (size_t)s * DM);
  float acc[8] = {};
#pragma unroll
  for (int c = 0; c < 32; c++) {
    float4 qa = q4[c], ka = k4[c];
    acc[c >> 2] += cl(qa.x)*cl(ka.x) + cl(qa.y)*cl(ka.y) + cl(qa.z)*cl(ka.z) + cl(qa.w)*cl(ka.w);
  }
#pragma unroll
  for (int h = 0; h < 8; h++) {
    float sc = fminf(acc[h] * ATT_SCALE, 60.0f);
    float ex = __expf(sc);
    EB[(size_t)e*8 + h] = ex;
    atomicAdd(&SS[d*8 + h], ex);
  }
}

// agg[dst] += V[src] * alpha  (one thread per (edge, 4-dim chunk))
__global__ __launch_bounds__(256) void k_edge_agg(const int* __restrict__ EI,
    const int* __restrict__ FLG,
    const float* __restrict__ Vl, const float* __restrict__ EB,
    const float* __restrict__ SS, float* __restrict__ AG) {
  int gid = blockIdx.x * 256 + threadIdx.x;
  int e = gid >> 5, c = gid & 31;
  int is64 = *FLG;
  int s = is64 ? EI[2*e]        : EI[e];
  int d = is64 ? EI[2*(NE+e)]   : EI[NE+e];
  s = min(max(s, 0), NN-1); d = min(max(d, 0), NN-1);
  int h = c >> 2;
  float alpha = EB[(size_t)e*8 + h] / fmaxf(SS[d*8 + h], 1e-30f);
  float4 v = *((const float4*)(Vl + (size_t)s * DM) + c);
  float* o = AG + (size_t)d * DM + c * 4;
  atomicAdd(o+0, cl(v.x)*alpha);
  atomicAdd(o+1, cl(v.y)*alpha);
  atomicAdd(o+2, cl(v.z)*alpha);
  atomicAdd(o+3, cl(v.w)*alpha);
}

// ---------------- global dense attention ----------------
// block = (head, 64 q-rows); 2 q-rows per thread; K/V 64-key tiles staged in LDS.
__global__ __launch_bounds__(256) void k_gattn(const float* __restrict__ Qg,
    const float* __restrict__ Kg, const float* __restrict__ Vg, float* __restrict__ O) {
  __shared__ float Kt[64][20];
  __shared__ float Vt[64][20];
  const int h    = blockIdx.x >> 6;
  const int tile = blockIdx.x & 63;
  const int t = threadIdx.x;
  const int qr2 = t >> 3;
  const int l8  = t & 7;
  const int r0 = tile * 64 + qr2 * 2;
  float q0[16], q1[16], o0[16] = {}, o1[16] = {};
  float ls0 = 0.f, ls1 = 0.f;
#pragma unroll
  for (int d = 0; d < 16; d++) {
    q0[d] = cl(Qg[(size_t)r0     * DM + h*HDD + d]) * ATT_SCALE;
    q1[d] = cl(Qg[(size_t)(r0+1) * DM + h*HDD + d]) * ATT_SCALE;
  }
  const int kr = t >> 2, kc = (t & 3) * 4;
  for (int t0 = 0; t0 < NN; t0 += 64) {
    float4 ka = *(const float4*)(Kg + (size_t)(t0+kr) * DM + h*HDD + kc);
    float4 va = *(const float4*)(Vg + (size_t)(t0+kr) * DM + h*HDD + kc);
    __syncthreads();
    Kt[kr][kc+0] = cl(ka.x); Kt[kr][kc+1] = cl(ka.y); Kt[kr][kc+2] = cl(ka.z); Kt[kr][kc+3] = cl(ka.w);
    Vt[kr][kc+0] = cl(va.x); Vt[kr][kc+1] = cl(va.y); Vt[kr][kc+2] = cl(va.z); Vt[kr][kc+3] = cl(va.w);
    __syncthreads();
#pragma unroll
    for (int jj = 0; jj < 8; jj++) {
      int j = l8 + jj * 8;
      float s0 = 0.f, s1 = 0.f;
#pragma unroll
      for (int d = 0; d < 16; d++) { float kv = Kt[j][d]; s0 += q0[d]*kv; s1 += q1[d]*kv; }
      s0 = fminf(s0, 60.0f); s1 = fminf(s1, 60.0f);
      float e0 = __expf(s0), e1 = __expf(s1);
      ls0 += e0; ls1 += e1;
#pragma unroll
      for (int d = 0; d < 16; d++) { float vv = Vt[j][d]; o0[d] += e0*vv; o1[d] += e1*vv; }
    }
  }
  for (int off = 1; off < 8; off <<= 1) {
    ls0 += __shfl_xor(ls0, off);
    ls1 += __shfl_xor(ls1, off);
#pragma unroll
    for (int d = 0; d < 16; d++) { o0[d] += __shfl_xor(o0[d], off); o1[d] += __shfl_xor(o1[d], off); }
  }
  if (l8 == 0) {
    float i0 = 1.0f/fmaxf(ls0, 1e-30f), i1 = 1.0f/fmaxf(ls1, 1e-30f);
#pragma unroll
    for (int d = 0; d < 16; d++) {
      O[(size_t)r0     * DM + h*HDD + d] = o0[d]*i0;
      O[(size_t)(r0+1) * DM + h*HDD + d] = o1[d]*i1;
    }
  }
}

extern "C" void kernel_launch(void* const* d_in, const int* in_sizes, int n_in,
                              void* d_out, int out_size, void* d_ws, size_t ws_size,
                              hipStream_t stream) {
  const float* x     = (const float*)d_in[0];
  const int*   ei    = (const int*)  d_in[1];
  const float* wq_l  = (const float*)d_in[2];  const float* bq_l = (const float*)d_in[3];
  const float* wk_l  = (const float*)d_in[4];  const float* bk_l = (const float*)d_in[5];
  const float* wv_l  = (const float*)d_in[6];  const float* bv_l = (const float*)d_in[7];
  const float* wg    = (const float*)d_in[8];  const float* bg   = (const float*)d_in[9];
  const float* wq_g  = (const float*)d_in[10]; const float* bq_g = (const float*)d_in[11];
  const float* wk_g  = (const float*)d_in[12]; const float* bk_g = (const float*)d_in[13];
  const float* wv_g  = (const float*)d_in[14]; const float* bv_g = (const float*)d_in[15];
  const float* wo_g  = (const float*)d_in[16]; const float* bo_g = (const float*)d_in[17];
  const float* wf    = (const float*)d_in[18]; const float* bff  = (const float*)d_in[19];
  const float* gf    = (const float*)d_in[20]; const float* betaf= (const float*)d_in[21];
  const float* w1    = (const float*)d_in[22]; const float* b1   = (const float*)d_in[23];
  const float* w2    = (const float*)d_in[24]; const float* b2   = (const float*)d_in[25];
  const float* g1    = (const float*)d_in[26]; const float* be1  = (const float*)d_in[27];
  const float* g2    = (const float*)d_in[28]; const float* be2  = (const float*)d_in[29];
  float* out = (float*)d_out;

  // ws_size guard: if scratch is too small, emit sentinel 100.0 (absmax ~107 tells us)
  const size_t NEED = 12800000;
  if (ws_size < NEED) {
    k_fill<<<2048, 256, 0, stream>>>(out, 100.0f, NN*DM);
    return;
  }

  // fp32 workspace slots (element offsets), lifetime-reused:
  float* W = (float*)d_ws;
  float* A  = W + 0;        // xq   -> local -> h2
  float* B  = W + 524288;   // xk   -> xn -> go        (t1 starts here)
  float* Cc = W + 1048576;  // xv   -> qg -> gop
  float* D0 = W + 1572864;  // eb[0:] -> kg -> tmpf
  float* D1 = W + 2097152;  //        -> vg
  float* E  = W + 2621440;  // agg  -> h
  float* F  = W + 3145728;  // ssum (32768)
  int*  flag = (int*)(W + 3178496);
  float* eb  = D0;          // NE*8 = 1048576 floats spans D0..D1
  float* t1  = B;           // 4096*512 = 2097152 floats spans B..D1

  dim3 b256(256);
  dim3 gN128(64, 2);
  dim3 gN512(64, 8);

  // local Q,K,V projections
  gemm_bt<<<gN128, b256, 0, stream>>>(x,128, nullptr,0,128, wq_l, bq_l, nullptr,nullptr,nullptr, A,  128, 128, 0);
  gemm_bt<<<gN128, b256, 0, stream>>>(x,128, nullptr,0,128, wk_l, bk_l, nullptr,nullptr,nullptr, B,  128, 128, 0);
  gemm_bt<<<gN128, b256, 0, stream>>>(x,128, nullptr,0,128, wv_l, bv_l, nullptr,nullptr,nullptr, Cc, 128, 128, 0);

  // edge segment softmax + aggregation
  k_detect<<<1, 64, 0, stream>>>(ei, flag);
  hipMemsetAsync(F, 0, (size_t)NN*NHD*sizeof(float), stream);
  hipMemsetAsync(E, 0, (size_t)NN*DM*sizeof(float), stream);
  k_edge_attn<<<512, b256, 0, stream>>>(ei, flag, A, B, eb, F);
  k_edge_agg<<<16384, b256, 0, stream>>>(ei, flag, Cc, eb, F, E);

  // gate: g = sigmoid(concat(x, agg) @ wg.T + bg); local = g*agg + (1-g)*x
  gemm_bt<<<gN128, b256, 0, stream>>>(x,128, E,128,128, wg, bg, nullptr, E, x, A, 128, 256, 2);

  // global branch
  k_ln<<<1024, b256, 0, stream>>>(x, g1, be1, B);
  gemm_bt<<<gN128, b256, 0, stream>>>(B,128, nullptr,0,128, wq_g, bq_g, nullptr,nullptr,nullptr, Cc, 128, 128, 0);
  gemm_bt<<<gN128, b256, 0, stream>>>(B,128, nullptr,0,128, wk_g, bk_g, nullptr,nullptr,nullptr, D0, 128, 128, 0);
  gemm_bt<<<gN128, b256, 0, stream>>>(B,128, nullptr,0,128, wv_g, bv_g, nullptr,nullptr,nullptr, D1, 128, 128, 0);
  k_gattn<<<512, b256, 0, stream>>>(Cc, D0, D1, B);
  gemm_bt<<<gN128, b256, 0, stream>>>(B,128, nullptr,0,128, wo_g, bo_g, nullptr,nullptr,nullptr, Cc, 128, 128, 0);

  // fusion + residual: tmpf = concat(local, gop) @ wf.T + bf; h = x + relu(ln(tmpf))
  gemm_bt<<<gN128, b256, 0, stream>>>(A,128, Cc,128,128, wf, bff, nullptr,nullptr,nullptr, D0, 128, 256, 0);
  k_ln_relu_res<<<1024, b256, 0, stream>>>(D0, gf, betaf, x, E);

  // FFN: h2 = ln(h); out = h + gelu(h2@w1.T+b1) @ w2.T + b2
  k_ln<<<1024, b256, 0, stream>>>(E, g2, be2, A);
  gemm_bt<<<gN512, b256, 0, stream>>>(A,128, nullptr,0,128, w1, b1, nullptr,nullptr,nullptr, t1, 512, 128, 1);
  gemm_bt<<<gN128, b256, 0, stream>>>(t1,512, nullptr,0,512, w2, b2, E, nullptr,nullptr, out, 128, 512, 0);
}

// Round 4
// 386.746 us; speedup vs baseline: 2.0356x; 2.0356x over previous
//
#include <hip/hip_runtime.h>
#include <math.h>

#define NN    4096
#define DM    128
#define NE    131072
#define ATT_SCALE 0.25f

typedef short short8 __attribute__((ext_vector_type(8)));
typedef float f32x4  __attribute__((ext_vector_type(4)));

static __device__ __forceinline__ unsigned short f2b(float f) {
  union { float f; unsigned u; } v; v.f = f;
  return (unsigned short)((v.u + 0x7fffu + ((v.u >> 16) & 1u)) >> 16);  // RNE fp32->bf16
}
static __device__ __forceinline__ short8 cvt8(float4 a, float4 b) {
  short8 r;
  r[0]=(short)f2b(a.x); r[1]=(short)f2b(a.y); r[2]=(short)f2b(a.z); r[3]=(short)f2b(a.w);
  r[4]=(short)f2b(b.x); r[5]=(short)f2b(b.y); r[6]=(short)f2b(b.z); r[7]=(short)f2b(b.w);
  return r;
}

// ---------------- sentinel fill (ws_size guard telemetry) ----------------
__global__ __launch_bounds__(256) void k_fill(float* __restrict__ out, float v, int n) {
  int i = blockIdx.x * 256 + threadIdx.x;
  if (i < n) out[i] = v;
}

// ---------------- edge_index layout detect: int64 (odd words all 0) vs int32 ----------------
__global__ void k_detect(const int* __restrict__ EI, int* __restrict__ flag) {
  int v = EI[2 * threadIdx.x + 1];
  for (int off = 1; off < 64; off <<= 1) v |= __shfl_xor(v, off);
  if (threadIdx.x == 0) *flag = (v == 0) ? 1 : 0;
}

// ---------------- MFMA GEMM: C[m,n] = epi( sum_k A[m,k]*W[n,k] + Bias[n] ) ----------------
// A = concat(A0[:, :ksplit], A1[:, :K-ksplit]) fp32; W fp32 (cvt bf16 in staging).
// act: 0 none, 1 exact gelu, 2 gate (g=sigmoid(v); v=g*E0+(1-g)*E1). Res added after act.
// omode: 0 fp32 [m][n]; 1 bf16 [m][n]; 2 bf16 [n][m] (feat-major, for V^T).
__global__ __launch_bounds__(256) void gemm_mfma(
    const float* __restrict__ A0, int lda0,
    const float* __restrict__ A1, int lda1, int ksplit,
    const float* __restrict__ Wt, const float* __restrict__ Bias,
    const float* __restrict__ Res, const float* __restrict__ E0, const float* __restrict__ E1,
    void* __restrict__ Cp, int Nt, int K, int act, int omode)
{
  __shared__ short Asm[64][40];   // 64 rows x 32 k, pad 8 (2-way banks = free)
  __shared__ short Wsm[64][40];
  const int m0 = blockIdx.x * 64, n0 = blockIdx.y * 64;
  const int tid = threadIdx.x;
  const int srow = tid >> 2, koff = (tid & 3) * 8;  // staging: 4 thr/row, 8 elems each
  const int lane = tid & 63, wave = tid >> 6;
  const int quad = lane >> 4, m16 = lane & 15;
  f32x4 acc[4];
#pragma unroll
  for (int i = 0; i < 4; i++) acc[i] = {0.f, 0.f, 0.f, 0.f};

  for (int k0 = 0; k0 < K; k0 += 32) {
    const int kg = k0 + koff;
    const float* ap = (kg < ksplit) ? (A0 + (size_t)(m0 + srow) * lda0 + kg)
                                    : (A1 + (size_t)(m0 + srow) * lda1 + (kg - ksplit));
    float4 a0 = *(const float4*)ap, a1 = *(const float4*)(ap + 4);
    const float* wp = Wt + (size_t)(n0 + srow) * K + kg;
    float4 w0 = *(const float4*)wp, w1v = *(const float4*)(wp + 4);
    __syncthreads();
    *(short8*)&Asm[srow][koff] = cvt8(a0, a1);
    *(short8*)&Wsm[srow][koff] = cvt8(w0, w1v);
    __syncthreads();
    short8 af = *(short8*)&Asm[wave * 16 + m16][quad * 8];
#pragma unroll
    for (int nt = 0; nt < 4; nt++) {
      short8 bf = *(short8*)&Wsm[nt * 16 + m16][quad * 8];
      acc[nt] = __builtin_amdgcn_mfma_f32_16x16x32_bf16(af, bf, acc[nt], 0, 0, 0);
    }
  }
#pragma unroll
  for (int nt = 0; nt < 4; nt++) {
#pragma unroll
    for (int r = 0; r < 4; r++) {
      const int m = m0 + wave * 16 + quad * 4 + r;   // C-layout: row = quad*4+reg
      const int n = n0 + nt * 16 + m16;              //           col = lane&15
      float v = acc[nt][r] + Bias[n];
      size_t oi = (size_t)m * Nt + n;
      if (act == 1) v = 0.5f * v * (1.0f + erff(v * 0.70710678118654752f));
      else if (act == 2) {
        float g = 1.0f / (1.0f + __expf(fminf(fmaxf(-v, -80.f), 80.f)));
        v = g * E0[oi] + (1.0f - g) * E1[oi];
      }
      if (Res) v += Res[oi];
      if (omode == 0)      ((float*)Cp)[oi] = v;
      else if (omode == 1) ((unsigned short*)Cp)[oi] = f2b(v);
      else                 ((unsigned short*)Cp)[(size_t)n * NN + m] = f2b(v);
    }
  }
}

// ---------------- MFMA global attention ----------------
// block = (head, 64 q-rows), 4 waves x 16 q-rows. Q/K bf16 row-major, V^T bf16 feat-major.
// QK^T: d padded 16->32 (quads 2,3 zero). P -> wave-private LDS -> A-frag -> PV MFMA.
__global__ __launch_bounds__(256) void k_gattn_mfma(
    const unsigned short* __restrict__ Qb, const unsigned short* __restrict__ Kb,
    const unsigned short* __restrict__ VT, float* __restrict__ O)
{
  __shared__ short P[4][16][40];   // per-wave P-tile, pad to 40 (2-way banks)
  const int h = blockIdx.x >> 6, qt = blockIdx.x & 63;
  const int tid = threadIdx.x, lane = tid & 63, wave = tid >> 6;
  const int quad = lane >> 4, m16 = lane & 15;
  const int r0 = qt * 64 + wave * 16;
  const short8 z8 = {0,0,0,0,0,0,0,0};
  const f32x4  z4 = {0.f,0.f,0.f,0.f};
  short8 qf = z8;
  if (quad < 2) qf = *(const short8*)(Qb + (size_t)(r0 + m16) * DM + h * 16 + quad * 8);
  f32x4 acc = z4, ls = z4;
  for (int kt = 0; kt < NN / 32; kt++) {
    const int key0 = kt * 32;
    short8 bk0 = z8, bk1 = z8;
    if (quad < 2) {
      bk0 = *(const short8*)(Kb + (size_t)(key0 + m16) * DM + h * 16 + quad * 8);
      bk1 = *(const short8*)(Kb + (size_t)(key0 + 16 + m16) * DM + h * 16 + quad * 8);
    }
    f32x4 s0 = __builtin_amdgcn_mfma_f32_16x16x32_bf16(qf, bk0, z4, 0, 0, 0);
    f32x4 s1 = __builtin_amdgcn_mfma_f32_16x16x32_bf16(qf, bk1, z4, 0, 0, 0);
#pragma unroll
    for (int r = 0; r < 4; r++) {
      float e0 = __expf(fminf(s0[r] * ATT_SCALE, 60.f));
      float e1 = __expf(fminf(s1[r] * ATT_SCALE, 60.f));
      ls[r] += e0 + e1;
      P[wave][quad * 4 + r][m16]      = (short)f2b(e0);   // C-layout scatter
      P[wave][quad * 4 + r][16 + m16] = (short)f2b(e1);
    }
    // in-wave lockstep: compiler inserts lgkmcnt wait between LDS write/read
    short8 pf = *(short8*)&P[wave][m16][quad * 8];        // A-frag: [m=lane&15][k=quad*8+j]
    short8 bv = *(const short8*)(VT + (size_t)(h * 16 + m16) * NN + key0 + quad * 8);
    acc = __builtin_amdgcn_mfma_f32_16x16x32_bf16(pf, bv, acc, 0, 0, 0);
  }
  for (int o = 1; o < 16; o <<= 1) {    // row-sums: reduce 16 lanes sharing a quad
#pragma unroll
    for (int r = 0; r < 4; r++) ls[r] += __shfl_xor(ls[r], o);
  }
#pragma unroll
  for (int r = 0; r < 4; r++) {
    float inv = 1.0f / fmaxf(ls[r], 1e-30f);
    O[(size_t)(r0 + quad * 4 + r) * DM + h * 16 + m16] = acc[r] * inv;
  }
}

// ---------------- LayerNorm (one wave per 128-wide row) ----------------
__global__ __launch_bounds__(256) void k_ln(const float* __restrict__ X,
    const float* __restrict__ G, const float* __restrict__ B, float* __restrict__ O) {
  int row = blockIdx.x * 4 + (threadIdx.x >> 6);
  int lane = threadIdx.x & 63;
  float v0 = X[(size_t)row*DM + lane];
  float v1 = X[(size_t)row*DM + 64 + lane];
  float s = v0 + v1;
  for (int off = 1; off < 64; off <<= 1) s += __shfl_xor(s, off);
  float mean = s * (1.0f/128.0f);
  float d0 = v0 - mean, d1 = v1 - mean;
  float s2 = d0*d0 + d1*d1;
  for (int off = 1; off < 64; off <<= 1) s2 += __shfl_xor(s2, off);
  float rstd = rsqrtf(s2 * (1.0f/128.0f) + 1e-5f);
  O[(size_t)row*DM + lane]      = d0*rstd*G[lane]    + B[lane];
  O[(size_t)row*DM + 64 + lane] = d1*rstd*G[64+lane] + B[64+lane];
}

// h = x + relu(ln(T, G, B))
__global__ __launch_bounds__(256) void k_ln_relu_res(const float* __restrict__ T,
    const float* __restrict__ G, const float* __restrict__ B,
    const float* __restrict__ X, float* __restrict__ H) {
  int row = blockIdx.x * 4 + (threadIdx.x >> 6);
  int lane = threadIdx.x & 63;
  float v0 = T[(size_t)row*DM + lane];
  float v1 = T[(size_t)row*DM + 64 + lane];
  float s = v0 + v1;
  for (int off = 1; off < 64; off <<= 1) s += __shfl_xor(s, off);
  float mean = s * (1.0f/128.0f);
  float d0 = v0 - mean, d1 = v1 - mean;
  float s2 = d0*d0 + d1*d1;
  for (int off = 1; off < 64; off <<= 1) s2 += __shfl_xor(s2, off);
  float rstd = rsqrtf(s2 * (1.0f/128.0f) + 1e-5f);
  float f0 = d0*rstd*G[lane]    + B[lane];
  float f1 = d1*rstd*G[64+lane] + B[64+lane];
  f0 = f0 > 0.f ? f0 : 0.f;
  f1 = f1 > 0.f ? f1 : 0.f;
  H[(size_t)row*DM + lane]      = X[(size_t)row*DM + lane] + f0;
  H[(size_t)row*DM + 64 + lane] = X[(size_t)row*DM + 64 + lane] + f1;
}

// ---------------- edge attention: exp(score) per (edge, head) -> EB (no atomics) ----------------
__global__ __launch_bounds__(256) void k_edge_attn(const int* __restrict__ EI,
    const int* __restrict__ FLG,
    const float* __restrict__ Q, const float* __restrict__ Kl, float* __restrict__ EB) {
  int e = blockIdx.x * 256 + threadIdx.x;
  if (e >= NE) return;
  int is64 = *FLG;
  int s = is64 ? EI[2*e]      : EI[e];
  int d = is64 ? EI[2*(NE+e)] : EI[NE+e];
  s = min(max(s, 0), NN-1); d = min(max(d, 0), NN-1);
  const float4* q4 = (const float4*)(Q  + (size_t)d * DM);
  const float4* k4 = (const float4*)(Kl + (size_t)s * DM);
  float acc[8] = {};
#pragma unroll
  for (int c = 0; c < 32; c++) {
    float4 qa = q4[c], ka = k4[c];
    acc[c >> 2] += qa.x*ka.x + qa.y*ka.y + qa.z*ka.z + qa.w*ka.w;
  }
#pragma unroll
  for (int h = 0; h < 8; h++)
    EB[(size_t)e*8 + h] = __expf(fminf(acc[h] * ATT_SCALE, 60.0f));
}

// ---------------- CSR-by-dst build ----------------
__global__ __launch_bounds__(256) void k_hist(const int* __restrict__ EI,
    const int* __restrict__ FLG, int* __restrict__ deg) {
  int e = blockIdx.x * 256 + threadIdx.x;
  if (e >= NE) return;
  int is64 = *FLG;
  int d = is64 ? EI[2*(NE+e)] : EI[NE+e];
  d = min(max(d, 0), NN-1);
  atomicAdd(&deg[d], 1);
}
__global__ __launch_bounds__(256) void k_scan(const int* __restrict__ deg,
    int* __restrict__ offs, int* __restrict__ cursor) {
  __shared__ int sums[256];
  int t = threadIdx.x;
  int loc[16];
  int s = 0;
#pragma unroll
  for (int i = 0; i < 16; i++) { loc[i] = s; s += deg[t*16 + i]; }
  sums[t] = s;
  __syncthreads();
  for (int d = 1; d < 256; d <<= 1) {
    int v = (t >= d) ? sums[t - d] : 0;
    __syncthreads();
    sums[t] += v;
    __syncthreads();
  }
  int base = sums[t] - s;   // exclusive prefix of this thread's chunk
#pragma unroll
  for (int i = 0; i < 16; i++) {
    offs[t*16 + i] = base + loc[i];
    cursor[t*16 + i] = base + loc[i];
  }
}
__global__ __launch_bounds__(256) void k_scatter(const int* __restrict__ EI,
    const int* __restrict__ FLG, int* __restrict__ cursor, int* __restrict__ elist) {
  int e = blockIdx.x * 256 + threadIdx.x;
  if (e >= NE) return;
  int is64 = *FLG;
  int d = is64 ? EI[2*(NE+e)] : EI[NE+e];
  d = min(max(d, 0), NN-1);
  int slot = atomicAdd(&cursor[d], 1);
  elist[slot] = e;
}

// ---------------- per-dst aggregation (atomic-free) ----------------
// one wave per dst: softmax denom via 8-lane-per-head partials, then coalesced V gather.
__global__ __launch_bounds__(256) void k_edge_agg2(const int* __restrict__ EI,
    const int* __restrict__ FLG, const int* __restrict__ deg, const int* __restrict__ offs,
    const int* __restrict__ elist, const float* __restrict__ Vl,
    const float* __restrict__ EB, float* __restrict__ AG) {
  int d = blockIdx.x * 4 + (threadIdx.x >> 6);
  int lane = threadIdx.x & 63;
  int is64 = *FLG;
  int degd = deg[d], start = offs[d];
  int hh = lane >> 3;                  // head for dims (2*lane, 2*lane+1)
  float ss = 0.f;
  for (int i = lane & 7; i < degd; i += 8)
    ss += EB[(size_t)elist[start + i] * 8 + hh];
  for (int o = 1; o < 8; o <<= 1) ss += __shfl_xor(ss, o);
  float inv = 1.0f / fmaxf(ss, 1e-30f);
  float ax = 0.f, ay = 0.f;
  for (int i = 0; i < degd; i++) {
    int e = elist[start + i];
    int s = is64 ? EI[2*e] : EI[e];
    s = min(max(s, 0), NN-1);
    float a = EB[(size_t)e*8 + hh] * inv;
    float2 v = *(const float2*)(Vl + (size_t)s * DM + 2 * lane);
    ax += a * v.x; ay += a * v.y;
  }
  float2 r; r.x = ax; r.y = ay;
  *(float2*)(AG + (size_t)d * DM + 2 * lane) = r;
}

extern "C" void kernel_launch(void* const* d_in, const int* in_sizes, int n_in,
                              void* d_out, int out_size, void* d_ws, size_t ws_size,
                              hipStream_t stream) {
  const float* x     = (const float*)d_in[0];
  const int*   ei    = (const int*)  d_in[1];
  const float* wq_l  = (const float*)d_in[2];  const float* bq_l = (const float*)d_in[3];
  const float* wk_l  = (const float*)d_in[4];  const float* bk_l = (const float*)d_in[5];
  const float* wv_l  = (const float*)d_in[6];  const float* bv_l = (const float*)d_in[7];
  const float* wg    = (const float*)d_in[8];  const float* bg   = (const float*)d_in[9];
  const float* wq_g  = (const float*)d_in[10]; const float* bq_g = (const float*)d_in[11];
  const float* wk_g  = (const float*)d_in[12]; const float* bk_g = (const float*)d_in[13];
  const float* wv_g  = (const float*)d_in[14]; const float* bv_g = (const float*)d_in[15];
  const float* wo_g  = (const float*)d_in[16]; const float* bo_g = (const float*)d_in[17];
  const float* wf    = (const float*)d_in[18]; const float* bff  = (const float*)d_in[19];
  const float* gf    = (const float*)d_in[20]; const float* betaf= (const float*)d_in[21];
  const float* w1    = (const float*)d_in[22]; const float* b1   = (const float*)d_in[23];
  const float* w2    = (const float*)d_in[24]; const float* b2   = (const float*)d_in[25];
  const float* g1    = (const float*)d_in[26]; const float* be1  = (const float*)d_in[27];
  const float* g2    = (const float*)d_in[28]; const float* be2  = (const float*)d_in[29];
  float* out = (float*)d_out;

  // ws_size guard: sentinel 100.0 if scratch too small (absmax ~107 tells us)
  const size_t NEED = (size_t)(3178512 + 131072) * 4;
  if (ws_size < NEED) {
    k_fill<<<2048, 256, 0, stream>>>(out, 100.0f, NN*DM);
    return;
  }

  // fp32 workspace slots (element offsets), lifetime-reused
  float* W  = (float*)d_ws;
  float* A  = W + 0;        // local Q -> local -> h2
  float* B  = W + 524288;   // local K -> xn -> go   (t1 spans B..E)
  float* Cc = W + 1048576;  // local V -> qgb(bf16) -> gop
  float* D0 = W + 1572864;  // eb[0:]  -> kgb(bf16) -> tmpf
  float* D1 = W + 2097152;  // eb[1:]  -> vgT(bf16)
  float* E  = W + 2621440;  // agg -> h
  int* deg    = (int*)(W + 3145728);
  int* cursor = deg + 4096;
  int* offs   = deg + 8192;
  int* flag   = (int*)(W + 3178496);
  int* elist  = (int*)(W + 3178512);   // 131072 ints
  float* eb = D0;                      // NE*8 floats spans D0..D1
  unsigned short* qgb = (unsigned short*)Cc;
  unsigned short* kgb = (unsigned short*)D0;
  unsigned short* vgT = (unsigned short*)D1;
  float* t1 = B;                       // 4096*512 fp32 spans B..E

  dim3 b256(256);
  dim3 gN128(64, 2);
  dim3 gN512(64, 8);

  // local Q,K,V projections (fp32 out for edge kernels)
  gemm_mfma<<<gN128, b256, 0, stream>>>(x,128, nullptr,0,128, wq_l, bq_l, nullptr,nullptr,nullptr, A,  128, 128, 0, 0);
  gemm_mfma<<<gN128, b256, 0, stream>>>(x,128, nullptr,0,128, wk_l, bk_l, nullptr,nullptr,nullptr, B,  128, 128, 0, 0);
  gemm_mfma<<<gN128, b256, 0, stream>>>(x,128, nullptr,0,128, wv_l, bv_l, nullptr,nullptr,nullptr, Cc, 128, 128, 0, 0);

  // edge segment softmax + aggregation (CSR, atomic-free aggregation)
  k_detect<<<1, 64, 0, stream>>>(ei, flag);
  hipMemsetAsync(deg, 0, 4096 * sizeof(int), stream);
  k_hist<<<512, b256, 0, stream>>>(ei, flag, deg);
  k_scan<<<1, b256, 0, stream>>>(deg, offs, cursor);
  k_scatter<<<512, b256, 0, stream>>>(ei, flag, cursor, elist);
  k_edge_attn<<<512, b256, 0, stream>>>(ei, flag, A, B, eb);
  k_edge_agg2<<<1024, b256, 0, stream>>>(ei, flag, deg, offs, elist, Cc, eb, E);

  // gate: g = sigmoid(concat(x, agg) @ wg.T + bg); local = g*agg + (1-g)*x
  gemm_mfma<<<gN128, b256, 0, stream>>>(x,128, E,128,128, wg, bg, nullptr, E, x, A, 128, 256, 2, 0);

  // global branch: ln -> Q/K (bf16 row-major), V (bf16 feat-major) -> MFMA attention
  k_ln<<<1024, b256, 0, stream>>>(x, g1, be1, B);
  gemm_mfma<<<gN128, b256, 0, stream>>>(B,128, nullptr,0,128, wq_g, bq_g, nullptr,nullptr,nullptr, qgb, 128, 128, 0, 1);
  gemm_mfma<<<gN128, b256, 0, stream>>>(B,128, nullptr,0,128, wk_g, bk_g, nullptr,nullptr,nullptr, kgb, 128, 128, 0, 1);
  gemm_mfma<<<gN128, b256, 0, stream>>>(B,128, nullptr,0,128, wv_g, bv_g, nullptr,nullptr,nullptr, vgT, 128, 128, 0, 2);
  k_gattn_mfma<<<512, b256, 0, stream>>>(qgb, kgb, vgT, B);
  gemm_mfma<<<gN128, b256, 0, stream>>>(B,128, nullptr,0,128, wo_g, bo_g, nullptr,nullptr,nullptr, Cc, 128, 128, 0, 0);

  // fusion + residual: tmpf = concat(local, gop) @ wf.T + bf; h = x + relu(ln(tmpf))
  gemm_mfma<<<gN128, b256, 0, stream>>>(A,128, Cc,128,128, wf, bff, nullptr,nullptr,nullptr, D0, 128, 256, 0, 0);
  k_ln_relu_res<<<1024, b256, 0, stream>>>(D0, gf, betaf, x, E);

  // FFN: h2 = ln(h); out = h + gelu(h2@w1.T+b1) @ w2.T + b2
  k_ln<<<1024, b256, 0, stream>>>(E, g2, be2, A);
  gemm_mfma<<<gN512, b256, 0, stream>>>(A,128, nullptr,0,128, w1, b1, nullptr,nullptr,nullptr, t1, 512, 128, 1, 0);
  gemm_mfma<<<gN128, b256, 0, stream>>>(t1,512, nullptr,0,512, w2, b2, E, nullptr,nullptr, out, 128, 512, 0, 0);
}

// Round 6
// 380.210 us; speedup vs baseline: 2.0706x; 1.0172x over previous
//
#include <hip/hip_runtime.h>
#include <math.h>

#define NN 4096
#define DM 128
#define NE 131072
#define QSCALE 0.36067376022224085f   // 0.25 * log2(e): exp(S/4) == exp2(S_prescaled)

typedef short short8 __attribute__((ext_vector_type(8)));
typedef float f32x4  __attribute__((ext_vector_type(4)));

static __device__ __forceinline__ unsigned short f2b(float f) {
  union { float f; unsigned u; } v; v.f = f;
  return (unsigned short)((v.u + 0x7fffu + ((v.u >> 16) & 1u)) >> 16);  // RNE
}
// round-half-up pack of two fp32 -> bf16x2
static __device__ __forceinline__ unsigned pk2(float lo, float hi) {
  union { float f; unsigned u; } a, b; a.f = lo; b.f = hi;
  return ((b.u + 0x8000u) & 0xffff0000u) | ((a.u + 0x8000u) >> 16);
}
static __device__ __forceinline__ short8 cvt8(float4 a, float4 b) {
  short8 r;
  r[0]=(short)f2b(a.x); r[1]=(short)f2b(a.y); r[2]=(short)f2b(a.z); r[3]=(short)f2b(a.w);
  r[4]=(short)f2b(b.x); r[5]=(short)f2b(b.y); r[6]=(short)f2b(b.z); r[7]=(short)f2b(b.w);
  return r;
}

// ---------------- sentinel fill (ws_size guard telemetry) ----------------
__global__ __launch_bounds__(256) void k_fill(float* __restrict__ out, float v, int n) {
  int i = blockIdx.x * 256 + threadIdx.x;
  if (i < n) out[i] = v;
}

// ---------------- detect edge_index layout (int64 vs int32) + zero deg ----------------
__global__ __launch_bounds__(256) void k_detect(const int* __restrict__ EI,
                                                int* __restrict__ flag, int* __restrict__ deg) {
  int i = blockIdx.x * 256 + threadIdx.x;
  if (i < 4096) deg[i] = 0;
  if (blockIdx.x == 0 && threadIdx.x < 64) {
    int v = EI[2 * threadIdx.x + 1];
    for (int off = 1; off < 64; off <<= 1) v |= __shfl_xor(v, off);
    if (threadIdx.x == 0) *flag = (v == 0) ? 1 : 0;
  }
}

// ---------------- MFMA GEMM (R4-proven structure): C = epi(A @ W^T + Bias) * oscale ----------------
// A = concat(A0[:, :ksplit], A1[:, :K-ksplit]) fp32; W fp32 (cvt bf16 in staging).
// act: 0 none, 1 exact gelu, 2 gate (g=sigmoid(v); v=g*E0+(1-g)*E1). Res added after act.
// omode: 0 fp32 [m][n]; 1 bf16 [m][n]; 2 bf16 [n][NN+m] (feat-major V^T).
__global__ __launch_bounds__(256) void gemm_mfma(
    const float* __restrict__ A0, int lda0,
    const float* __restrict__ A1, int lda1, int ksplit,
    const float* __restrict__ Wt, const float* __restrict__ Bias,
    const float* __restrict__ Res, const float* __restrict__ E0, const float* __restrict__ E1,
    void* __restrict__ Cp, int Nt, int K, int act, int omode, float oscale)
{
  __shared__ short Asm[64][40];   // 64 rows x 32 k, pad 8 (2-way banks = free)
  __shared__ short Wsm[64][40];
  const int m0 = blockIdx.x * 64, n0 = blockIdx.y * 64;
  const int tid = threadIdx.x;
  const int srow = tid >> 2, koff = (tid & 3) * 8;
  const int lane = tid & 63, wave = tid >> 6;
  const int quad = lane >> 4, m16 = lane & 15;
  f32x4 acc[4];
#pragma unroll
  for (int i = 0; i < 4; i++) acc[i] = {0.f, 0.f, 0.f, 0.f};

  for (int k0 = 0; k0 < K; k0 += 32) {
    const int kg = k0 + koff;
    const float* ap = (kg < ksplit) ? (A0 + (size_t)(m0 + srow) * lda0 + kg)
                                    : (A1 + (size_t)(m0 + srow) * lda1 + (kg - ksplit));
    float4 a0 = *(const float4*)ap, a1 = *(const float4*)(ap + 4);
    const float* wp = Wt + (size_t)(n0 + srow) * K + kg;
    float4 w0 = *(const float4*)wp, w1v = *(const float4*)(wp + 4);
    __syncthreads();
    *(short8*)&Asm[srow][koff] = cvt8(a0, a1);
    *(short8*)&Wsm[srow][koff] = cvt8(w0, w1v);
    __syncthreads();
    short8 af = *(short8*)&Asm[wave * 16 + m16][quad * 8];
#pragma unroll
    for (int nt = 0; nt < 4; nt++) {
      short8 bf = *(short8*)&Wsm[nt * 16 + m16][quad * 8];
      acc[nt] = __builtin_amdgcn_mfma_f32_16x16x32_bf16(af, bf, acc[nt], 0, 0, 0);
    }
  }
#pragma unroll
  for (int nt = 0; nt < 4; nt++) {
#pragma unroll
    for (int r = 0; r < 4; r++) {
      const int m = m0 + wave * 16 + quad * 4 + r;   // C-layout: row = quad*4+reg
      const int n = n0 + nt * 16 + m16;              //           col = lane&15
      float v = acc[nt][r] + Bias[n];
      size_t oi = (size_t)m * Nt + n;
      if (act == 1) v = 0.5f * v * (1.0f + erff(v * 0.70710678118654752f));
      else if (act == 2) {
        float g = 1.0f / (1.0f + __expf(fminf(fmaxf(-v, -80.f), 80.f)));
        v = g * E0[oi] + (1.0f - g) * E1[oi];
      }
      if (Res) v += Res[oi];
      v *= oscale;
      if (omode == 0)      ((float*)Cp)[oi] = v;
      else if (omode == 1) ((unsigned short*)Cp)[oi] = f2b(v);
      else                 ((unsigned short*)Cp)[(size_t)n * NN + m] = f2b(v);
    }
  }
}

// ---------------- global attention, LDS-free K-loop ----------------
// grid 2048 = head(8) x 16-row q-tile(256); 4 waves = 4 key quarters; LDS combine at end.
// S^T = K_perm . Q^T : A-row m holds key key0+(m>>2)*8+(m&3), so C(row=quad*4+r) = key
// quad*8+r (s0) / quad*8+4+r (s1) -- exactly the B-operand layout for O^T = V^T . P^T.
__global__ __launch_bounds__(256) void k_gattn2(
    const unsigned short* __restrict__ Qb, const unsigned short* __restrict__ Kb,
    const unsigned short* __restrict__ VT, float* __restrict__ O)
{
  __shared__ float LO[4][16][16];
  __shared__ float LL[4][16];
  const int h = blockIdx.x >> 8, qt = blockIdx.x & 255;
  const int tid = threadIdx.x, lane = tid & 63, wave = tid >> 6;
  const int quad = lane >> 4, m16 = lane & 15;
  const int r0 = qt * 16;
  const short8 z8 = {0,0,0,0,0,0,0,0};
  const f32x4  z4 = {0.f,0.f,0.f,0.f};
  short8 qf = z8;                      // Q^T B-operand (pre-scaled by QSCALE)
  if (quad < 2) qf = *(const short8*)(Qb + (size_t)(r0 + m16) * DM + h * 16 + quad * 8);
  const int kperm = (m16 >> 2) * 8 + (m16 & 3);
  f32x4 acc = z4;
  float ls = 0.f;
  const int kbase = wave * 1024;
  for (int kt = 0; kt < 32; kt++) {
    const int key0 = kbase + kt * 32;
    short8 a0 = z8, a1 = z8;
    if (quad < 2) {
      a0 = *(const short8*)(Kb + (size_t)(key0 + kperm)     * DM + h * 16 + quad * 8);
      a1 = *(const short8*)(Kb + (size_t)(key0 + kperm + 4) * DM + h * 16 + quad * 8);
    }
    f32x4 s0 = __builtin_amdgcn_mfma_f32_16x16x32_bf16(a0, qf, z4, 0, 0, 0);
    f32x4 s1 = __builtin_amdgcn_mfma_f32_16x16x32_bf16(a1, qf, z4, 0, 0, 0);
    float e0 = exp2f(fminf(s0[0], 80.f)), e1 = exp2f(fminf(s0[1], 80.f));
    float e2 = exp2f(fminf(s0[2], 80.f)), e3 = exp2f(fminf(s0[3], 80.f));
    float e4 = exp2f(fminf(s1[0], 80.f)), e5 = exp2f(fminf(s1[1], 80.f));
    float e6 = exp2f(fminf(s1[2], 80.f)), e7 = exp2f(fminf(s1[3], 80.f));
    ls += (e0 + e1) + (e2 + e3) + (e4 + e5) + (e6 + e7);
    unsigned u0 = pk2(e0, e1), u1 = pk2(e2, e3), u2 = pk2(e4, e5), u3 = pk2(e6, e7);
    short8 p;
    p[0] = (short)(u0 & 0xffffu); p[1] = (short)(u0 >> 16);
    p[2] = (short)(u1 & 0xffffu); p[3] = (short)(u1 >> 16);
    p[4] = (short)(u2 & 0xffffu); p[5] = (short)(u2 >> 16);
    p[6] = (short)(u3 & 0xffffu); p[7] = (short)(u3 >> 16);
    short8 av = *(const short8*)(VT + (size_t)(h * 16 + m16) * NN + key0 + quad * 8);
    acc = __builtin_amdgcn_mfma_f32_16x16x32_bf16(av, p, acc, 0, 0, 0);
  }
  ls += __shfl_xor(ls, 16); ls += __shfl_xor(ls, 32);   // reduce over quads (same q=m16)
  float4 a4; a4.x = acc[0]; a4.y = acc[1]; a4.z = acc[2]; a4.w = acc[3];
  *(float4*)&LO[wave][m16][quad * 4] = a4;              // LO[q][dim] partial (O^T C-layout)
  if (lane < 16) LL[wave][lane] = ls;
  __syncthreads();
  if (wave == 0) {
    float4 o = *(float4*)&LO[0][m16][quad * 4];
    float lt = LL[0][m16];
#pragma unroll
    for (int w = 1; w < 4; w++) {
      float4 t = *(float4*)&LO[w][m16][quad * 4];
      o.x += t.x; o.y += t.y; o.z += t.z; o.w += t.w;
      lt += LL[w][m16];
    }
    float inv = 1.0f / fmaxf(lt, 1e-30f);
    float4 r4; r4.x = o.x * inv; r4.y = o.y * inv; r4.z = o.z * inv; r4.w = o.w * inv;
    *(float4*)(O + (size_t)(r0 + m16) * DM + h * 16 + quad * 4) = r4;
  }
}

// ---------------- LayerNorm (one wave per 128-wide row) ----------------
__global__ __launch_bounds__(256) void k_ln(const float* __restrict__ X,
    const float* __restrict__ G, const float* __restrict__ B, float* __restrict__ O) {
  int row = blockIdx.x * 4 + (threadIdx.x >> 6);
  int lane = threadIdx.x & 63;
  float v0 = X[(size_t)row*DM + lane];
  float v1 = X[(size_t)row*DM + 64 + lane];
  float s = v0 + v1;
  for (int off = 1; off < 64; off <<= 1) s += __shfl_xor(s, off);
  float mean = s * (1.0f/128.0f);
  float d0 = v0 - mean, d1 = v1 - mean;
  float s2 = d0*d0 + d1*d1;
  for (int off = 1; off < 64; off <<= 1) s2 += __shfl_xor(s2, off);
  float rstd = rsqrtf(s2 * (1.0f/128.0f) + 1e-5f);
  O[(size_t)row*DM + lane]      = d0*rstd*G[lane]    + B[lane];
  O[(size_t)row*DM + 64 + lane] = d1*rstd*G[64+lane] + B[64+lane];
}

// h = x + relu(ln(T, G, B))
__global__ __launch_bounds__(256) void k_ln_relu_res(const float* __restrict__ T,
    const float* __restrict__ G, const float* __restrict__ B,
    const float* __restrict__ X, float* __restrict__ H) {
  int row = blockIdx.x * 4 + (threadIdx.x >> 6);
  int lane = threadIdx.x & 63;
  float v0 = T[(size_t)row*DM + lane];
  float v1 = T[(size_t)row*DM + 64 + lane];
  float s = v0 + v1;
  for (int off = 1; off < 64; off <<= 1) s += __shfl_xor(s, off);
  float mean = s * (1.0f/128.0f);
  float d0 = v0 - mean, d1 = v1 - mean;
  float s2 = d0*d0 + d1*d1;
  for (int off = 1; off < 64; off <<= 1) s2 += __shfl_xor(s2, off);
  float rstd = rsqrtf(s2 * (1.0f/128.0f) + 1e-5f);
  float f0 = d0*rstd*G[lane]    + B[lane];
  float f1 = d1*rstd*G[64+lane] + B[64+lane];
  f0 = f0 > 0.f ? f0 : 0.f;
  f1 = f1 > 0.f ? f1 : 0.f;
  H[(size_t)row*DM + lane]      = X[(size_t)row*DM + lane] + f0;
  H[(size_t)row*DM + 64 + lane] = X[(size_t)row*DM + 64 + lane] + f1;
}

// ---------------- edge attention: exp(score) per (edge, head) -> EB ----------------
__global__ __launch_bounds__(256) void k_edge_attn(const int* __restrict__ EI,
    const int* __restrict__ FLG,
    const float* __restrict__ Q, const float* __restrict__ Kl, float* __restrict__ EB) {
  int e = blockIdx.x * 256 + threadIdx.x;
  if (e >= NE) return;
  int is64 = *FLG;
  int s = is64 ? EI[2*e]      : EI[e];
  int d = is64 ? EI[2*(NE+e)] : EI[NE+e];
  s = min(max(s, 0), NN-1); d = min(max(d, 0), NN-1);
  const float4* q4 = (const float4*)(Q  + (size_t)d * DM);
  const float4* k4 = (const float4*)(Kl + (size_t)s * DM);
  float acc[8] = {};
#pragma unroll
  for (int c = 0; c < 32; c++) {
    float4 qa = q4[c], ka = k4[c];
    acc[c >> 2] += qa.x*ka.x + qa.y*ka.y + qa.z*ka.z + qa.w*ka.w;
  }
#pragma unroll
  for (int h = 0; h < 8; h++)
    EB[(size_t)e*8 + h] = __expf(fminf(acc[h] * 0.25f, 60.0f));
}

// ---------------- CSR-by-dst build ----------------
__global__ __launch_bounds__(256) void k_hist(const int* __restrict__ EI,
    const int* __restrict__ FLG, int* __restrict__ deg) {
  int e = blockIdx.x * 256 + threadIdx.x;
  if (e >= NE) return;
  int is64 = *FLG;
  int d = is64 ? EI[2*(NE+e)] : EI[NE+e];
  d = min(max(d, 0), NN-1);
  atomicAdd(&deg[d], 1);
}
__global__ __launch_bounds__(256) void k_scan(const int* __restrict__ deg,
    int* __restrict__ offs, int* __restrict__ cursor) {
  __shared__ int sums[256];
  int t = threadIdx.x;
  int loc[16];
  int s = 0;
#pragma unroll
  for (int i = 0; i < 16; i++) { loc[i] = s; s += deg[t*16 + i]; }
  sums[t] = s;
  __syncthreads();
  for (int d = 1; d < 256; d <<= 1) {
    int v = (t >= d) ? sums[t - d] : 0;
    __syncthreads();
    sums[t] += v;
    __syncthreads();
  }
  int base = sums[t] - s;
#pragma unroll
  for (int i = 0; i < 16; i++) {
    offs[t*16 + i] = base + loc[i];
    cursor[t*16 + i] = base + loc[i];
  }
}
__global__ __launch_bounds__(256) void k_scatter(const int* __restrict__ EI,
    const int* __restrict__ FLG, int* __restrict__ cursor, int* __restrict__ elist) {
  int e = blockIdx.x * 256 + threadIdx.x;
  if (e >= NE) return;
  int is64 = *FLG;
  int d = is64 ? EI[2*(NE+e)] : EI[NE+e];
  d = min(max(d, 0), NN-1);
  int slot = atomicAdd(&cursor[d], 1);
  elist[slot] = e;
}

// ---------------- per-dst aggregation (atomic-free) ----------------
__global__ __launch_bounds__(256) void k_edge_agg2(const int* __restrict__ EI,
    const int* __restrict__ FLG, const int* __restrict__ deg, const int* __restrict__ offs,
    const int* __restrict__ elist, const float* __restrict__ Vl,
    const float* __restrict__ EB, float* __restrict__ AG) {
  int d = blockIdx.x * 4 + (threadIdx.x >> 6);
  int lane = threadIdx.x & 63;
  int is64 = *FLG;
  int degd = deg[d], start = offs[d];
  int hh = lane >> 3;
  float ss = 0.f;
  for (int i = lane & 7; i < degd; i += 8)
    ss += EB[(size_t)elist[start + i] * 8 + hh];
  for (int o = 1; o < 8; o <<= 1) ss += __shfl_xor(ss, o);
  float inv = 1.0f / fmaxf(ss, 1e-30f);
  float ax = 0.f, ay = 0.f;
  for (int i = 0; i < degd; i++) {
    int e = elist[start + i];
    int s = is64 ? EI[2*e] : EI[e];
    s = min(max(s, 0), NN-1);
    float a = EB[(size_t)e*8 + hh] * inv;
    float2 v = *(const float2*)(Vl + (size_t)s * DM + 2 * lane);
    ax += a * v.x; ay += a * v.y;
  }
  float2 r; r.x = ax; r.y = ay;
  *(float2*)(AG + (size_t)d * DM + 2 * lane) = r;
}

extern "C" void kernel_launch(void* const* d_in, const int* in_sizes, int n_in,
                              void* d_out, int out_size, void* d_ws, size_t ws_size,
                              hipStream_t stream) {
  const float* x     = (const float*)d_in[0];
  const int*   ei    = (const int*)  d_in[1];
  const float* wq_l  = (const float*)d_in[2];  const float* bq_l = (const float*)d_in[3];
  const float* wk_l  = (const float*)d_in[4];  const float* bk_l = (const float*)d_in[5];
  const float* wv_l  = (const float*)d_in[6];  const float* bv_l = (const float*)d_in[7];
  const float* wg    = (const float*)d_in[8];  const float* bg   = (const float*)d_in[9];
  const float* wq_g  = (const float*)d_in[10]; const float* bq_g = (const float*)d_in[11];
  const float* wk_g  = (const float*)d_in[12]; const float* bk_g = (const float*)d_in[13];
  const float* wv_g  = (const float*)d_in[14]; const float* bv_g = (const float*)d_in[15];
  const float* wo_g  = (const float*)d_in[16]; const float* bo_g = (const float*)d_in[17];
  const float* wf    = (const float*)d_in[18]; const float* bff  = (const float*)d_in[19];
  const float* gf    = (const float*)d_in[20]; const float* betaf= (const float*)d_in[21];
  const float* w1    = (const float*)d_in[22]; const float* b1   = (const float*)d_in[23];
  const float* w2    = (const float*)d_in[24]; const float* b2   = (const float*)d_in[25];
  const float* g1    = (const float*)d_in[26]; const float* be1  = (const float*)d_in[27];
  const float* g2    = (const float*)d_in[28]; const float* be2  = (const float*)d_in[29];
  float* out = (float*)d_out;

  const size_t NEED = (size_t)(3178512 + 131072) * 4;
  if (ws_size < NEED) {
    k_fill<<<2048, 256, 0, stream>>>(out, 100.0f, NN*DM);
    return;
  }

  float* W  = (float*)d_ws;
  float* A  = W + 0;        // localQ -> local -> h2
  float* B  = W + 524288;   // localK -> xn -> go   (t1 spans B..E)
  float* Cc = W + 1048576;  // localV -> qgb(bf16) -> gop
  float* D0 = W + 1572864;  // eb[lo] -> kgb(bf16) -> tmpf
  float* D1 = W + 2097152;  // eb[hi] -> vgT(bf16)
  float* E  = W + 2621440;  // agg -> h
  int* deg    = (int*)(W + 3145728);
  int* cursor = deg + 4096;
  int* offs   = deg + 8192;
  int* flag   = (int*)(W + 3178496);
  int* elist  = (int*)(W + 3178512);
  float* eb = D0;
  unsigned short* qgb = (unsigned short*)Cc;
  unsigned short* kgb = (unsigned short*)D0;
  unsigned short* vgT = (unsigned short*)D1;
  float* t1 = B;

  dim3 b256(256);
  dim3 gN128(64, 2);
  dim3 gN512(64, 8);

  // local Q,K,V projections (fp32 out for edge kernels)
  gemm_mfma<<<gN128, b256, 0, stream>>>(x,128, nullptr,0,128, wq_l, bq_l, nullptr,nullptr,nullptr, A,  128, 128, 0, 0, 1.f);
  gemm_mfma<<<gN128, b256, 0, stream>>>(x,128, nullptr,0,128, wk_l, bk_l, nullptr,nullptr,nullptr, B,  128, 128, 0, 0, 1.f);
  gemm_mfma<<<gN128, b256, 0, stream>>>(x,128, nullptr,0,128, wv_l, bv_l, nullptr,nullptr,nullptr, Cc, 128, 128, 0, 0, 1.f);

  // edge segment softmax + aggregation (CSR, atomic-free aggregation)
  k_detect<<<16, b256, 0, stream>>>(ei, flag, deg);
  k_hist<<<512, b256, 0, stream>>>(ei, flag, deg);
  k_scan<<<1, b256, 0, stream>>>(deg, offs, cursor);
  k_scatter<<<512, b256, 0, stream>>>(ei, flag, cursor, elist);
  k_edge_attn<<<512, b256, 0, stream>>>(ei, flag, A, B, eb);
  k_edge_agg2<<<1024, b256, 0, stream>>>(ei, flag, deg, offs, elist, Cc, eb, E);

  // gate: g = sigmoid(concat(x, agg) @ wg.T + bg); local = g*agg + (1-g)*x
  gemm_mfma<<<gN128, b256, 0, stream>>>(x,128, E,128,128, wg, bg, nullptr, E, x, A, 128, 256, 2, 0, 1.f);

  // global branch: ln -> Q (pre-scaled bf16), K (bf16), V^T (feat-major bf16) -> attention
  k_ln<<<1024, b256, 0, stream>>>(x, g1, be1, B);
  gemm_mfma<<<gN128, b256, 0, stream>>>(B,128, nullptr,0,128, wq_g, bq_g, nullptr,nullptr,nullptr, qgb, 128, 128, 0, 1, QSCALE);
  gemm_mfma<<<gN128, b256, 0, stream>>>(B,128, nullptr,0,128, wk_g, bk_g, nullptr,nullptr,nullptr, kgb, 128, 128, 0, 1, 1.f);
  gemm_mfma<<<gN128, b256, 0, stream>>>(B,128, nullptr,0,128, wv_g, bv_g, nullptr,nullptr,nullptr, vgT, 128, 128, 0, 2, 1.f);
  k_gattn2<<<2048, b256, 0, stream>>>(qgb, kgb, vgT, B);
  gemm_mfma<<<gN128, b256, 0, stream>>>(B,128, nullptr,0,128, wo_g, bo_g, nullptr,nullptr,nullptr, Cc, 128, 128, 0, 0, 1.f);

  // fusion + residual: tmpf = concat(local, gop) @ wf.T + bf; h = x + relu(ln(tmpf))
  gemm_mfma<<<gN128, b256, 0, stream>>>(A,128, Cc,128,128, wf, bff, nullptr,nullptr,nullptr, D0, 128, 256, 0, 0, 1.f);
  k_ln_relu_res<<<1024, b256, 0, stream>>>(D0, gf, betaf, x, E);

  // FFN: h2 = ln(h); out = h + gelu(h2@w1.T+b1) @ w2.T + b2
  k_ln<<<1024, b256, 0, stream>>>(E, g2, be2, A);
  gemm_mfma<<<gN512, b256, 0, stream>>>(A,128, nullptr,0,128, w1, b1, nullptr,nullptr,nullptr, t1, 512, 128, 1, 0, 1.f);
  gemm_mfma<<<gN128, b256, 0, stream>>>(t1,512, nullptr,0,512, w2, b2, E, nullptr,nullptr, out, 128, 512, 0, 0, 1.f);
}

// Round 7
// 371.988 us; speedup vs baseline: 2.1164x; 1.0221x over previous
//
#include <hip/hip_runtime.h>
#include <math.h>

#define NN 4096
#define DM 128
#define NE 131072
#define QSCALE 0.36067376022224085f   // 0.25 * log2(e): exp(S/4) == exp2(S_prescaled)

typedef short short8 __attribute__((ext_vector_type(8)));
typedef float f32x4  __attribute__((ext_vector_type(4)));

// round-half-up pack of two fp32 -> bf16x2 (3-4 ops)
static __device__ __forceinline__ unsigned pk2(float lo, float hi) {
  union { float f; unsigned u; } a, b; a.f = lo; b.f = hi;
  return ((b.u + 0x8000u) & 0xffff0000u) | ((a.u + 0x8000u) >> 16);
}
// truncating pack (folds toward v_perm)
static __device__ __forceinline__ unsigned pkt(float lo, float hi) {
  union { float f; unsigned u; } a, b; a.f = lo; b.f = hi;
  return (b.u & 0xffff0000u) | (a.u >> 16);
}
// round-half-up single fp32 -> bf16 (2 ops)
static __device__ __forceinline__ unsigned short f2bh(float f) {
  union { float f; unsigned u; } v; v.f = f;
  return (unsigned short)((v.u + 0x8000u) >> 16);
}
static __device__ __forceinline__ short8 cvt8(float4 a, float4 b) {
  unsigned u0 = pk2(a.x, a.y), u1 = pk2(a.z, a.w);
  unsigned u2 = pk2(b.x, b.y), u3 = pk2(b.z, b.w);
  short8 r;
  r[0]=(short)(u0 & 0xffffu); r[1]=(short)(u0 >> 16);
  r[2]=(short)(u1 & 0xffffu); r[3]=(short)(u1 >> 16);
  r[4]=(short)(u2 & 0xffffu); r[5]=(short)(u2 >> 16);
  r[6]=(short)(u3 & 0xffffu); r[7]=(short)(u3 >> 16);
  return r;
}
// per-wave inline edge_index layout detect: int64 (odd words all 0) -> 1, else 0
static __device__ __forceinline__ int detect64(const int* __restrict__ EI) {
  int v = EI[2 * (threadIdx.x & 63) + 1];
  for (int off = 1; off < 64; off <<= 1) v |= __shfl_xor(v, off);
  return (v == 0) ? 1 : 0;
}

// ---------------- sentinel fill (ws_size guard telemetry) ----------------
__global__ __launch_bounds__(256) void k_fill(float* __restrict__ out, float v, int n) {
  int i = blockIdx.x * 256 + threadIdx.x;
  if (i < n) out[i] = v;
}

// ---------------- MFMA GEMM: C = epi(A @ W^T + Bias) * oscale ----------------
// A = concat(A0[:, :ksplit], A1[:, :K-ksplit]) fp32; W fp32 (cvt bf16 in staging).
// act: 0 none, 1 exact gelu, 2 gate (g=sigmoid(v); v=g*E0+(1-g)*E1). Res added after act.
// omode: 0 fp32 [m][n]; 1 bf16 [m][n]; 2 bf16 [n][NN+m] (feat-major V^T).
__global__ __launch_bounds__(256) void gemm_mfma(
    const float* __restrict__ A0, int lda0,
    const float* __restrict__ A1, int lda1, int ksplit,
    const float* __restrict__ Wt, const float* __restrict__ Bias,
    const float* __restrict__ Res, const float* __restrict__ E0, const float* __restrict__ E1,
    void* __restrict__ Cp, int Nt, int K, int act, int omode, float oscale)
{
  __shared__ short Asm[64][40];
  __shared__ short Wsm[64][40];
  const int m0 = blockIdx.x * 64, n0 = blockIdx.y * 64;
  const int tid = threadIdx.x;
  const int srow = tid >> 2, koff = (tid & 3) * 8;
  const int lane = tid & 63, wave = tid >> 6;
  const int quad = lane >> 4, m16 = lane & 15;
  f32x4 acc[4];
#pragma unroll
  for (int i = 0; i < 4; i++) acc[i] = {0.f, 0.f, 0.f, 0.f};

  for (int k0 = 0; k0 < K; k0 += 32) {
    const int kg = k0 + koff;
    const float* ap = (kg < ksplit) ? (A0 + (size_t)(m0 + srow) * lda0 + kg)
                                    : (A1 + (size_t)(m0 + srow) * lda1 + (kg - ksplit));
    float4 a0 = *(const float4*)ap, a1 = *(const float4*)(ap + 4);
    const float* wp = Wt + (size_t)(n0 + srow) * K + kg;
    float4 w0 = *(const float4*)wp, w1v = *(const float4*)(wp + 4);
    __syncthreads();
    *(short8*)&Asm[srow][koff] = cvt8(a0, a1);
    *(short8*)&Wsm[srow][koff] = cvt8(w0, w1v);
    __syncthreads();
    short8 af = *(short8*)&Asm[wave * 16 + m16][quad * 8];
#pragma unroll
    for (int nt = 0; nt < 4; nt++) {
      short8 bf = *(short8*)&Wsm[nt * 16 + m16][quad * 8];
      acc[nt] = __builtin_amdgcn_mfma_f32_16x16x32_bf16(af, bf, acc[nt], 0, 0, 0);
    }
  }
#pragma unroll
  for (int nt = 0; nt < 4; nt++) {
#pragma unroll
    for (int r = 0; r < 4; r++) {
      const int m = m0 + wave * 16 + quad * 4 + r;
      const int n = n0 + nt * 16 + m16;
      float v = acc[nt][r] + Bias[n];
      size_t oi = (size_t)m * Nt + n;
      if (act == 1) v = 0.5f * v * (1.0f + erff(v * 0.70710678118654752f));
      else if (act == 2) {
        float g = 1.0f / (1.0f + __expf(fminf(fmaxf(-v, -80.f), 80.f)));
        v = g * E0[oi] + (1.0f - g) * E1[oi];
      }
      if (Res) v += Res[oi];
      v *= oscale;
      if (omode == 0)      ((float*)Cp)[oi] = v;
      else if (omode == 1) ((unsigned short*)Cp)[oi] = f2bh(v);
      else                 ((unsigned short*)Cp)[(size_t)n * NN + m] = f2bh(v);
    }
  }
}

// ---------------- fused triple GEMM (shared A, K=Nt=128): grid (64, 6) ----------------
__global__ __launch_bounds__(256) void gemm_qkv(
    const float* __restrict__ A,
    const float* __restrict__ W0, const float* __restrict__ W1, const float* __restrict__ W2,
    const float* __restrict__ B0, const float* __restrict__ B1, const float* __restrict__ B2,
    void* __restrict__ O0, void* __restrict__ O1, void* __restrict__ O2,
    int om0, int om1, int om2, float os0, float os1, float os2)
{
  __shared__ short Asm[64][40];
  __shared__ short Wsm[64][40];
  const int g = blockIdx.y >> 1;
  const float* Wt  = (g == 0) ? W0 : (g == 1) ? W1 : W2;
  const float* Bia = (g == 0) ? B0 : (g == 1) ? B1 : B2;
  void* Cp         = (g == 0) ? O0 : (g == 1) ? O1 : O2;
  const int omode  = (g == 0) ? om0 : (g == 1) ? om1 : om2;
  const float osc  = (g == 0) ? os0 : (g == 1) ? os1 : os2;
  const int m0 = blockIdx.x * 64, n0 = (blockIdx.y & 1) * 64;
  const int tid = threadIdx.x;
  const int srow = tid >> 2, koff = (tid & 3) * 8;
  const int lane = tid & 63, wave = tid >> 6;
  const int quad = lane >> 4, m16 = lane & 15;
  f32x4 acc[4];
#pragma unroll
  for (int i = 0; i < 4; i++) acc[i] = {0.f, 0.f, 0.f, 0.f};

  for (int k0 = 0; k0 < 128; k0 += 32) {
    const int kg = k0 + koff;
    const float* ap = A + (size_t)(m0 + srow) * 128 + kg;
    float4 a0 = *(const float4*)ap, a1 = *(const float4*)(ap + 4);
    const float* wp = Wt + (size_t)(n0 + srow) * 128 + kg;
    float4 w0 = *(const float4*)wp, w1v = *(const float4*)(wp + 4);
    __syncthreads();
    *(short8*)&Asm[srow][koff] = cvt8(a0, a1);
    *(short8*)&Wsm[srow][koff] = cvt8(w0, w1v);
    __syncthreads();
    short8 af = *(short8*)&Asm[wave * 16 + m16][quad * 8];
#pragma unroll
    for (int nt = 0; nt < 4; nt++) {
      short8 bf = *(short8*)&Wsm[nt * 16 + m16][quad * 8];
      acc[nt] = __builtin_amdgcn_mfma_f32_16x16x32_bf16(af, bf, acc[nt], 0, 0, 0);
    }
  }
#pragma unroll
  for (int nt = 0; nt < 4; nt++) {
#pragma unroll
    for (int r = 0; r < 4; r++) {
      const int m = m0 + wave * 16 + quad * 4 + r;
      const int n = n0 + nt * 16 + m16;
      float v = (acc[nt][r] + Bia[n]) * osc;
      size_t oi = (size_t)m * 128 + n;
      if (omode == 0)      ((float*)Cp)[oi] = v;
      else if (omode == 1) ((unsigned short*)Cp)[oi] = f2bh(v);
      else                 ((unsigned short*)Cp)[(size_t)n * NN + m] = f2bh(v);
    }
  }
}

// ---------------- global attention, LDS-free K-loop (R6 dataflow + VALU diet) ----------------
// grid 2048 = head(8) x 16-row q-tile(256); 4 waves = 4 key quarters; LDS combine at end.
// S^T = K_perm . Q^T ; C(row=quad*4+r) = key quad*8+r / +4+r == B-operand layout of P^T for
// O^T = V^T . P^T. No conditional K-loads: quads 2/3 load dup addresses (col quad&1), B-side zero.
__global__ __launch_bounds__(256) void k_gattn3(
    const unsigned short* __restrict__ Qb, const unsigned short* __restrict__ Kb,
    const unsigned short* __restrict__ VT, float* __restrict__ O)
{
  __shared__ float LO[4][16][16];
  __shared__ float LL[4][16];
  const int h = blockIdx.x >> 8, qt = blockIdx.x & 255;
  const int tid = threadIdx.x, lane = tid & 63, wave = tid >> 6;
  const int quad = lane >> 4, m16 = lane & 15;
  const int r0 = qt * 16;
  const short8 z8 = {0,0,0,0,0,0,0,0};
  const f32x4  z4 = {0.f,0.f,0.f,0.f};
  short8 qf = z8;
  if (quad < 2) qf = *(const short8*)(Qb + (size_t)(r0 + m16) * DM + h * 16 + quad * 8);
  const int kperm = (m16 >> 2) * 8 + (m16 & 3);
  const int kcol = h * 16 + (quad & 1) * 8;
  const int kstart = wave * 1024;
  const unsigned short* kp0 = Kb + (size_t)(kstart + kperm) * DM + kcol;
  const unsigned short* kp1 = kp0 + 4 * DM;
  const unsigned short* vp  = VT + (size_t)(h * 16 + m16) * NN + kstart + quad * 8;
  f32x4 acc = z4;
  float ls = 0.f;
  for (int kt = 0; kt < 32; kt++) {
    short8 a0 = *(const short8*)kp0;
    short8 a1 = *(const short8*)kp1;
    short8 av = *(const short8*)vp;
    kp0 += 32 * DM; kp1 += 32 * DM; vp += 32;
    f32x4 s0 = __builtin_amdgcn_mfma_f32_16x16x32_bf16(a0, qf, z4, 0, 0, 0);
    f32x4 s1 = __builtin_amdgcn_mfma_f32_16x16x32_bf16(a1, qf, z4, 0, 0, 0);
    float e0 = exp2f(fminf(s0[0], 80.f)), e1 = exp2f(fminf(s0[1], 80.f));
    float e2 = exp2f(fminf(s0[2], 80.f)), e3 = exp2f(fminf(s0[3], 80.f));
    float e4 = exp2f(fminf(s1[0], 80.f)), e5 = exp2f(fminf(s1[1], 80.f));
    float e6 = exp2f(fminf(s1[2], 80.f)), e7 = exp2f(fminf(s1[3], 80.f));
    ls += (e0 + e1) + (e2 + e3) + (e4 + e5) + (e6 + e7);
    unsigned u0 = pkt(e0, e1), u1 = pkt(e2, e3), u2 = pkt(e4, e5), u3 = pkt(e6, e7);
    short8 p;
    p[0] = (short)(u0 & 0xffffu); p[1] = (short)(u0 >> 16);
    p[2] = (short)(u1 & 0xffffu); p[3] = (short)(u1 >> 16);
    p[4] = (short)(u2 & 0xffffu); p[5] = (short)(u2 >> 16);
    p[6] = (short)(u3 & 0xffffu); p[7] = (short)(u3 >> 16);
    acc = __builtin_amdgcn_mfma_f32_16x16x32_bf16(av, p, acc, 0, 0, 0);
  }
  ls += __shfl_xor(ls, 16); ls += __shfl_xor(ls, 32);
  float4 a4; a4.x = acc[0]; a4.y = acc[1]; a4.z = acc[2]; a4.w = acc[3];
  *(float4*)&LO[wave][m16][quad * 4] = a4;
  if (lane < 16) LL[wave][lane] = ls;
  __syncthreads();
  if (wave == 0) {
    float4 o = *(float4*)&LO[0][m16][quad * 4];
    float lt = LL[0][m16];
#pragma unroll
    for (int w = 1; w < 4; w++) {
      float4 t = *(float4*)&LO[w][m16][quad * 4];
      o.x += t.x; o.y += t.y; o.z += t.z; o.w += t.w;
      lt += LL[w][m16];
    }
    float inv = 1.0f / fmaxf(lt, 1e-30f);
    float4 r4; r4.x = o.x * inv; r4.y = o.y * inv; r4.z = o.z * inv; r4.w = o.w * inv;
    *(float4*)(O + (size_t)(r0 + m16) * DM + h * 16 + quad * 4) = r4;
  }
}

// ---------------- LayerNorm (one wave per 128-wide row) ----------------
__global__ __launch_bounds__(256) void k_ln(const float* __restrict__ X,
    const float* __restrict__ G, const float* __restrict__ B, float* __restrict__ O) {
  int row = blockIdx.x * 4 + (threadIdx.x >> 6);
  int lane = threadIdx.x & 63;
  float v0 = X[(size_t)row*DM + lane];
  float v1 = X[(size_t)row*DM + 64 + lane];
  float s = v0 + v1;
  for (int off = 1; off < 64; off <<= 1) s += __shfl_xor(s, off);
  float mean = s * (1.0f/128.0f);
  float d0 = v0 - mean, d1 = v1 - mean;
  float s2 = d0*d0 + d1*d1;
  for (int off = 1; off < 64; off <<= 1) s2 += __shfl_xor(s2, off);
  float rstd = rsqrtf(s2 * (1.0f/128.0f) + 1e-5f);
  O[(size_t)row*DM + lane]      = d0*rstd*G[lane]    + B[lane];
  O[(size_t)row*DM + 64 + lane] = d1*rstd*G[64+lane] + B[64+lane];
}

// ---------------- fused: H = X + relu(ln1(T)); H2 = ln2(H) ----------------
__global__ __launch_bounds__(256) void k_ln2(const float* __restrict__ T,
    const float* __restrict__ G1, const float* __restrict__ Be1,
    const float* __restrict__ X,
    const float* __restrict__ G2, const float* __restrict__ Be2,
    float* __restrict__ H, float* __restrict__ H2) {
  int row = blockIdx.x * 4 + (threadIdx.x >> 6);
  int lane = threadIdx.x & 63;
  float v0 = T[(size_t)row*DM + lane];
  float v1 = T[(size_t)row*DM + 64 + lane];
  float s = v0 + v1;
  for (int off = 1; off < 64; off <<= 1) s += __shfl_xor(s, off);
  float mean = s * (1.0f/128.0f);
  float d0 = v0 - mean, d1 = v1 - mean;
  float s2 = d0*d0 + d1*d1;
  for (int off = 1; off < 64; off <<= 1) s2 += __shfl_xor(s2, off);
  float rstd = rsqrtf(s2 * (1.0f/128.0f) + 1e-5f);
  float f0 = d0*rstd*G1[lane]    + Be1[lane];
  float f1 = d1*rstd*G1[64+lane] + Be1[64+lane];
  f0 = f0 > 0.f ? f0 : 0.f;
  f1 = f1 > 0.f ? f1 : 0.f;
  float h0 = X[(size_t)row*DM + lane]      + f0;
  float h1 = X[(size_t)row*DM + 64 + lane] + f1;
  H[(size_t)row*DM + lane]      = h0;
  H[(size_t)row*DM + 64 + lane] = h1;
  float t = h0 + h1;
  for (int off = 1; off < 64; off <<= 1) t += __shfl_xor(t, off);
  float mean2 = t * (1.0f/128.0f);
  float e0 = h0 - mean2, e1 = h1 - mean2;
  float t2 = e0*e0 + e1*e1;
  for (int off = 1; off < 64; off <<= 1) t2 += __shfl_xor(t2, off);
  float rstd2 = rsqrtf(t2 * (1.0f/128.0f) + 1e-5f);
  H2[(size_t)row*DM + lane]      = e0*rstd2*G2[lane]    + Be2[lane];
  H2[(size_t)row*DM + 64 + lane] = e1*rstd2*G2[64+lane] + Be2[64+lane];
}

// ---------------- edge attention: exp(score) per (edge, head) -> EB ----------------
__global__ __launch_bounds__(256) void k_edge_attn(const int* __restrict__ EI,
    const float* __restrict__ Q, const float* __restrict__ Kl, float* __restrict__ EB) {
  int is64 = detect64(EI);
  int e = blockIdx.x * 256 + threadIdx.x;
  int s = is64 ? EI[2*e]      : EI[e];
  int d = is64 ? EI[2*(NE+e)] : EI[NE+e];
  s = min(max(s, 0), NN-1); d = min(max(d, 0), NN-1);
  const float4* q4 = (const float4*)(Q  + (size_t)d * DM);
  const float4* k4 = (const float4*)(Kl + (size_t)s * DM);
  float acc[8] = {};
#pragma unroll
  for (int c = 0; c < 32; c++) {
    float4 qa = q4[c], ka = k4[c];
    acc[c >> 2] += qa.x*ka.x + qa.y*ka.y + qa.z*ka.z + qa.w*ka.w;
  }
#pragma unroll
  for (int h = 0; h < 8; h++)
    EB[(size_t)e*8 + h] = __expf(fminf(acc[h] * 0.25f, 60.0f));
}

// ---------------- CSR-by-dst build ----------------
__global__ __launch_bounds__(256) void k_hist(const int* __restrict__ EI, int* __restrict__ deg) {
  int is64 = detect64(EI);
  int e = blockIdx.x * 256 + threadIdx.x;
  int d = is64 ? EI[2*(NE+e)] : EI[NE+e];
  d = min(max(d, 0), NN-1);
  atomicAdd(&deg[d], 1);
}
__global__ __launch_bounds__(256) void k_scan(const int* __restrict__ deg,
    int* __restrict__ offs, int* __restrict__ cursor) {
  __shared__ int sums[256];
  int t = threadIdx.x;
  int loc[16];
  int s = 0;
#pragma unroll
  for (int i = 0; i < 16; i++) { loc[i] = s; s += deg[t*16 + i]; }
  sums[t] = s;
  __syncthreads();
  for (int d = 1; d < 256; d <<= 1) {
    int v = (t >= d) ? sums[t - d] : 0;
    __syncthreads();
    sums[t] += v;
    __syncthreads();
  }
  int base = sums[t] - s;
#pragma unroll
  for (int i = 0; i < 16; i++) {
    offs[t*16 + i] = base + loc[i];
    cursor[t*16 + i] = base + loc[i];
  }
}
__global__ __launch_bounds__(256) void k_scatter(const int* __restrict__ EI,
    int* __restrict__ cursor, int* __restrict__ elist) {
  int is64 = detect64(EI);
  int e = blockIdx.x * 256 + threadIdx.x;
  int d = is64 ? EI[2*(NE+e)] : EI[NE+e];
  d = min(max(d, 0), NN-1);
  int slot = atomicAdd(&cursor[d], 1);
  elist[slot] = e;
}

// ---------------- per-dst aggregation (atomic-free) ----------------
__global__ __launch_bounds__(256) void k_edge_agg2(const int* __restrict__ EI,
    const int* __restrict__ deg, const int* __restrict__ offs,
    const int* __restrict__ elist, const float* __restrict__ Vl,
    const float* __restrict__ EB, float* __restrict__ AG) {
  int is64 = detect64(EI);
  int d = blockIdx.x * 4 + (threadIdx.x >> 6);
  int lane = threadIdx.x & 63;
  int degd = deg[d], start = offs[d];
  int hh = lane >> 3;
  float ss = 0.f;
  for (int i = lane & 7; i < degd; i += 8)
    ss += EB[(size_t)elist[start + i] * 8 + hh];
  for (int o = 1; o < 8; o <<= 1) ss += __shfl_xor(ss, o);
  float inv = 1.0f / fmaxf(ss, 1e-30f);
  float ax = 0.f, ay = 0.f;
  for (int i = 0; i < degd; i++) {
    int e = elist[start + i];
    int s = is64 ? EI[2*e] : EI[e];
    s = min(max(s, 0), NN-1);
    float a = EB[(size_t)e*8 + hh] * inv;
    float2 v = *(const float2*)(Vl + (size_t)s * DM + 2 * lane);
    ax += a * v.x; ay += a * v.y;
  }
  float2 r; r.x = ax; r.y = ay;
  *(float2*)(AG + (size_t)d * DM + 2 * lane) = r;
}

extern "C" void kernel_launch(void* const* d_in, const int* in_sizes, int n_in,
                              void* d_out, int out_size, void* d_ws, size_t ws_size,
                              hipStream_t stream) {
  const float* x     = (const float*)d_in[0];
  const int*   ei    = (const int*)  d_in[1];
  const float* wq_l  = (const float*)d_in[2];  const float* bq_l = (const float*)d_in[3];
  const float* wk_l  = (const float*)d_in[4];  const float* bk_l = (const float*)d_in[5];
  const float* wv_l  = (const float*)d_in[6];  const float* bv_l = (const float*)d_in[7];
  const float* wg    = (const float*)d_in[8];  const float* bg   = (const float*)d_in[9];
  const float* wq_g  = (const float*)d_in[10]; const float* bq_g = (const float*)d_in[11];
  const float* wk_g  = (const float*)d_in[12]; const float* bk_g = (const float*)d_in[13];
  const float* wv_g  = (const float*)d_in[14]; const float* bv_g = (const float*)d_in[15];
  const float* wo_g  = (const float*)d_in[16]; const float* bo_g = (const float*)d_in[17];
  const float* wf    = (const float*)d_in[18]; const float* bff  = (const float*)d_in[19];
  const float* gf    = (const float*)d_in[20]; const float* betaf= (const float*)d_in[21];
  const float* w1    = (const float*)d_in[22]; const float* b1   = (const float*)d_in[23];
  const float* w2    = (const float*)d_in[24]; const float* b2   = (const float*)d_in[25];
  const float* g1    = (const float*)d_in[26]; const float* be1  = (const float*)d_in[27];
  const float* g2    = (const float*)d_in[28]; const float* be2  = (const float*)d_in[29];
  float* out = (float*)d_out;

  const size_t NEED = (size_t)(3178512 + 131072) * 4;
  if (ws_size < NEED) {
    k_fill<<<2048, 256, 0, stream>>>(out, 100.0f, NN*DM);
    return;
  }

  float* W  = (float*)d_ws;
  float* A  = W + 0;        // localQ -> local -> h2
  float* B  = W + 524288;   // localK -> xn -> go   (t1 spans B..E)
  float* Cc = W + 1048576;  // localV -> qgb(bf16) -> gop
  float* D0 = W + 1572864;  // eb[lo] -> kgb(bf16) -> tmpf
  float* D1 = W + 2097152;  // eb[hi] -> vgT(bf16)
  float* E  = W + 2621440;  // agg -> h
  int* deg    = (int*)(W + 3145728);
  int* cursor = deg + 4096;
  int* offs   = deg + 8192;
  int* elist  = (int*)(W + 3178512);
  float* eb = D0;
  unsigned short* qgb = (unsigned short*)Cc;
  unsigned short* kgb = (unsigned short*)D0;
  unsigned short* vgT = (unsigned short*)D1;
  float* t1 = B;

  dim3 b256(256);
  dim3 gQKV(64, 6);
  dim3 gN128(64, 2);
  dim3 gN512(64, 8);

  hipMemsetAsync(deg, 0, 4096 * sizeof(int), stream);

  // local Q,K,V projections (fused, fp32 out)
  gemm_qkv<<<gQKV, b256, 0, stream>>>(x, wq_l, wk_l, wv_l, bq_l, bk_l, bv_l,
                                      A, B, Cc, 0, 0, 0, 1.f, 1.f, 1.f);

  // edge segment softmax + aggregation (CSR, atomic-free aggregation)
  k_hist<<<512, b256, 0, stream>>>(ei, deg);
  k_scan<<<1, b256, 0, stream>>>(deg, offs, cursor);
  k_scatter<<<512, b256, 0, stream>>>(ei, cursor, elist);
  k_edge_attn<<<512, b256, 0, stream>>>(ei, A, B, eb);
  k_edge_agg2<<<1024, b256, 0, stream>>>(ei, deg, offs, elist, Cc, eb, E);

  // gate: g = sigmoid(concat(x, agg) @ wg.T + bg); local = g*agg + (1-g)*x
  gemm_mfma<<<gN128, b256, 0, stream>>>(x,128, E,128,128, wg, bg, nullptr, E, x, A, 128, 256, 2, 0, 1.f);

  // global branch: ln -> fused QKV (Q pre-scaled bf16, K bf16, V^T feat-major) -> attention
  k_ln<<<1024, b256, 0, stream>>>(x, g1, be1, B);
  gemm_qkv<<<gQKV, b256, 0, stream>>>(B, wq_g, wk_g, wv_g, bq_g, bk_g, bv_g,
                                      qgb, kgb, vgT, 1, 1, 2, QSCALE, 1.f, 1.f);
  k_gattn3<<<2048, b256, 0, stream>>>(qgb, kgb, vgT, B);
  gemm_mfma<<<gN128, b256, 0, stream>>>(B,128, nullptr,0,128, wo_g, bo_g, nullptr,nullptr,nullptr, Cc, 128, 128, 0, 0, 1.f);

  // fusion + residual: tmpf = concat(local, gop) @ wf.T + bf; h = x + relu(ln(tmpf)); h2 = ln(h)
  gemm_mfma<<<gN128, b256, 0, stream>>>(A,128, Cc,128,128, wf, bff, nullptr,nullptr,nullptr, D0, 128, 256, 0, 0, 1.f);
  k_ln2<<<1024, b256, 0, stream>>>(D0, gf, betaf, x, g2, be2, E, A);

  // FFN: out = h + gelu(h2@w1.T+b1) @ w2.T + b2
  gemm_mfma<<<gN512, b256, 0, stream>>>(A,128, nullptr,0,128, w1, b1, nullptr,nullptr,nullptr, t1, 512, 128, 1, 0, 1.f);
  gemm_mfma<<<gN128, b256, 0, stream>>>(t1,512, nullptr,0,512, w2, b2, E, nullptr,nullptr, out, 128, 512, 0, 0, 1.f);
}

// Round 8
// 350.398 us; speedup vs baseline: 2.2468x; 1.0616x over previous
//
#include <hip/hip_runtime.h>
#include <math.h>

#define NN 4096
#define DM 128
#define NE 131072
#define QSCALE 0.36067376022224085f   // 0.25 * log2(e): exp(S/4) == exp2(S_prescaled)
#define ESCALE 0.36067376022224085f   // same fold for edge softmax (base-2 softmax == base-e)

typedef short short8 __attribute__((ext_vector_type(8)));
typedef float f32x4  __attribute__((ext_vector_type(4)));
typedef unsigned int uint4v __attribute__((ext_vector_type(4)));

// round-half-up pack of two fp32 -> bf16x2
static __device__ __forceinline__ unsigned pk2(float lo, float hi) {
  union { float f; unsigned u; } a, b; a.f = lo; b.f = hi;
  return ((b.u + 0x8000u) & 0xffff0000u) | ((a.u + 0x8000u) >> 16);
}
// truncating pack
static __device__ __forceinline__ unsigned pkt(float lo, float hi) {
  union { float f; unsigned u; } a, b; a.f = lo; b.f = hi;
  return (b.u & 0xffff0000u) | (a.u >> 16);
}
// round-half-up single fp32 -> bf16
static __device__ __forceinline__ unsigned short f2bh(float f) {
  union { float f; unsigned u; } v; v.f = f;
  return (unsigned short)((v.u + 0x8000u) >> 16);
}
static __device__ __forceinline__ short8 cvt8(float4 a, float4 b) {
  unsigned u0 = pk2(a.x, a.y), u1 = pk2(a.z, a.w);
  unsigned u2 = pk2(b.x, b.y), u3 = pk2(b.z, b.w);
  short8 r;
  r[0]=(short)(u0 & 0xffffu); r[1]=(short)(u0 >> 16);
  r[2]=(short)(u1 & 0xffffu); r[3]=(short)(u1 >> 16);
  r[4]=(short)(u2 & 0xffffu); r[5]=(short)(u2 >> 16);
  r[6]=(short)(u3 & 0xffffu); r[7]=(short)(u3 >> 16);
  return r;
}
// per-wave inline edge_index layout detect: int64 (odd words all 0) -> 1, else 0
static __device__ __forceinline__ int detect64(const int* __restrict__ EI) {
  int v = EI[2 * (threadIdx.x & 63) + 1];
  for (int off = 1; off < 64; off <<= 1) v |= __shfl_xor(v, off);
  return (v == 0) ? 1 : 0;
}

// ---------------- sentinel fill (ws_size guard telemetry) ----------------
__global__ __launch_bounds__(256) void k_fill(float* __restrict__ out, float v, int n) {
  int i = blockIdx.x * 256 + threadIdx.x;
  if (i < n) out[i] = v;
}

// ---------------- MFMA GEMM: C = epi(A @ W^T + Bias) * oscale ----------------
// A = concat(A0[:, :ksplit], A1[:, :K-ksplit]) fp32; W fp32 (cvt bf16 in staging).
// act: 0 none, 1 exact gelu, 2 gate (g=sigmoid(v); v=g*E0+(1-g)*E1). Res added after act.
// omode: 0 fp32 [m][n]; 1 bf16 [m][n]; 2 bf16 [n][NN+m] (feat-major V^T).
__global__ __launch_bounds__(256) void gemm_mfma(
    const float* __restrict__ A0, int lda0,
    const float* __restrict__ A1, int lda1, int ksplit,
    const float* __restrict__ Wt, const float* __restrict__ Bias,
    const float* __restrict__ Res, const float* __restrict__ E0, const float* __restrict__ E1,
    void* __restrict__ Cp, int Nt, int K, int act, int omode, float oscale)
{
  __shared__ short Asm[64][40];
  __shared__ short Wsm[64][40];
  const int m0 = blockIdx.x * 64, n0 = blockIdx.y * 64;
  const int tid = threadIdx.x;
  const int srow = tid >> 2, koff = (tid & 3) * 8;
  const int lane = tid & 63, wave = tid >> 6;
  const int quad = lane >> 4, m16 = lane & 15;
  f32x4 acc[4];
#pragma unroll
  for (int i = 0; i < 4; i++) acc[i] = {0.f, 0.f, 0.f, 0.f};

  for (int k0 = 0; k0 < K; k0 += 32) {
    const int kg = k0 + koff;
    const float* ap = (kg < ksplit) ? (A0 + (size_t)(m0 + srow) * lda0 + kg)
                                    : (A1 + (size_t)(m0 + srow) * lda1 + (kg - ksplit));
    float4 a0 = *(const float4*)ap, a1 = *(const float4*)(ap + 4);
    const float* wp = Wt + (size_t)(n0 + srow) * K + kg;
    float4 w0 = *(const float4*)wp, w1v = *(const float4*)(wp + 4);
    __syncthreads();
    *(short8*)&Asm[srow][koff] = cvt8(a0, a1);
    *(short8*)&Wsm[srow][koff] = cvt8(w0, w1v);
    __syncthreads();
    short8 af = *(short8*)&Asm[wave * 16 + m16][quad * 8];
#pragma unroll
    for (int nt = 0; nt < 4; nt++) {
      short8 bf = *(short8*)&Wsm[nt * 16 + m16][quad * 8];
      acc[nt] = __builtin_amdgcn_mfma_f32_16x16x32_bf16(af, bf, acc[nt], 0, 0, 0);
    }
  }
#pragma unroll
  for (int nt = 0; nt < 4; nt++) {
#pragma unroll
    for (int r = 0; r < 4; r++) {
      const int m = m0 + wave * 16 + quad * 4 + r;
      const int n = n0 + nt * 16 + m16;
      float v = acc[nt][r] + Bias[n];
      size_t oi = (size_t)m * Nt + n;
      if (act == 1) v = 0.5f * v * (1.0f + erff(v * 0.70710678118654752f));
      else if (act == 2) {
        float g = 1.0f / (1.0f + __expf(fminf(fmaxf(-v, -80.f), 80.f)));
        v = g * E0[oi] + (1.0f - g) * E1[oi];
      }
      if (Res) v += Res[oi];
      v *= oscale;
      if (omode == 0)      ((float*)Cp)[oi] = v;
      else if (omode == 1) ((unsigned short*)Cp)[oi] = f2bh(v);
      else                 ((unsigned short*)Cp)[(size_t)n * NN + m] = f2bh(v);
    }
  }
}

// ---------------- fused triple GEMM (shared A, K=Nt=128): grid (64, 6) ----------------
__global__ __launch_bounds__(256) void gemm_qkv(
    const float* __restrict__ A,
    const float* __restrict__ W0, const float* __restrict__ W1, const float* __restrict__ W2,
    const float* __restrict__ B0, const float* __restrict__ B1, const float* __restrict__ B2,
    void* __restrict__ O0, void* __restrict__ O1, void* __restrict__ O2,
    int om0, int om1, int om2, float os0, float os1, float os2)
{
  __shared__ short Asm[64][40];
  __shared__ short Wsm[64][40];
  const int g = blockIdx.y >> 1;
  const float* Wt  = (g == 0) ? W0 : (g == 1) ? W1 : W2;
  const float* Bia = (g == 0) ? B0 : (g == 1) ? B1 : B2;
  void* Cp         = (g == 0) ? O0 : (g == 1) ? O1 : O2;
  const int omode  = (g == 0) ? om0 : (g == 1) ? om1 : om2;
  const float osc  = (g == 0) ? os0 : (g == 1) ? os1 : os2;
  const int m0 = blockIdx.x * 64, n0 = (blockIdx.y & 1) * 64;
  const int tid = threadIdx.x;
  const int srow = tid >> 2, koff = (tid & 3) * 8;
  const int lane = tid & 63, wave = tid >> 6;
  const int quad = lane >> 4, m16 = lane & 15;
  f32x4 acc[4];
#pragma unroll
  for (int i = 0; i < 4; i++) acc[i] = {0.f, 0.f, 0.f, 0.f};

  for (int k0 = 0; k0 < 128; k0 += 32) {
    const int kg = k0 + koff;
    const float* ap = A + (size_t)(m0 + srow) * 128 + kg;
    float4 a0 = *(const float4*)ap, a1 = *(const float4*)(ap + 4);
    const float* wp = Wt + (size_t)(n0 + srow) * 128 + kg;
    float4 w0 = *(const float4*)wp, w1v = *(const float4*)(wp + 4);
    __syncthreads();
    *(short8*)&Asm[srow][koff] = cvt8(a0, a1);
    *(short8*)&Wsm[srow][koff] = cvt8(w0, w1v);
    __syncthreads();
    short8 af = *(short8*)&Asm[wave * 16 + m16][quad * 8];
#pragma unroll
    for (int nt = 0; nt < 4; nt++) {
      short8 bf = *(short8*)&Wsm[nt * 16 + m16][quad * 8];
      acc[nt] = __builtin_amdgcn_mfma_f32_16x16x32_bf16(af, bf, acc[nt], 0, 0, 0);
    }
  }
#pragma unroll
  for (int nt = 0; nt < 4; nt++) {
#pragma unroll
    for (int r = 0; r < 4; r++) {
      const int m = m0 + wave * 16 + quad * 4 + r;
      const int n = n0 + nt * 16 + m16;
      float v = (acc[nt][r] + Bia[n]) * osc;
      size_t oi = (size_t)m * 128 + n;
      if (omode == 0)      ((float*)Cp)[oi] = v;
      else if (omode == 1) ((unsigned short*)Cp)[oi] = f2bh(v);
      else                 ((unsigned short*)Cp)[(size_t)n * NN + m] = f2bh(v);
    }
  }
}

// ---------------- global attention, LDS-free K-loop, 64 keys/iter ----------------
// grid 2048 = head(8) x 16-row q-tile(256); 4 waves = 4 key quarters; LDS combine at end.
// S^T = K_perm . Q^T ; C(row=quad*4+r) maps to key quad*8+r (+4 for a1) == B-operand layout
// of P^T for O^T = V^T . P^T (register-only P). ls summed on the MFMA pipe via ones-A MFMA:
// every C row equals the column sum, so each lane reads its q's ls from acc2[0].
__global__ __launch_bounds__(256) void k_gattn4(
    const unsigned short* __restrict__ Qb, const unsigned short* __restrict__ Kb,
    const unsigned short* __restrict__ VT, float* __restrict__ O)
{
  __shared__ float LO[4][16][16];
  __shared__ float LL[4][16];
  const int h = blockIdx.x >> 8, qt = blockIdx.x & 255;
  const int tid = threadIdx.x, lane = tid & 63, wave = tid >> 6;
  const int quad = lane >> 4, m16 = lane & 15;
  const int r0 = qt * 16;
  const short8 z8 = {0,0,0,0,0,0,0,0};
  const f32x4  z4 = {0.f,0.f,0.f,0.f};
  short8 qf = z8;
  if (quad < 2) qf = *(const short8*)(Qb + (size_t)(r0 + m16) * DM + h * 16 + quad * 8);
  short8 ones;
#pragma unroll
  for (int i = 0; i < 8; i++) ones[i] = (short)0x3F80;   // bf16 1.0
  const int kperm = (m16 >> 2) * 8 + (m16 & 3);
  const int kbase = wave * 1024;
  f32x4 acc = z4, acc2 = z4;
  short8 a0 = z8, a1 = z8, a2 = z8, a3 = z8;   // zero-init ONCE; masked loads keep quads 2/3 zero
  for (int kt = 0; kt < 16; kt++) {
    const int key0 = kbase + kt * 64;
    if (quad < 2) {
      const unsigned short* kp = Kb + (size_t)(key0 + kperm) * DM + h * 16 + quad * 8;
      a0 = *(const short8*)kp;
      a1 = *(const short8*)(kp + 4 * DM);
      a2 = *(const short8*)(kp + 32 * DM);
      a3 = *(const short8*)(kp + 36 * DM);
    }
    const unsigned short* vp = VT + (size_t)(h * 16 + m16) * NN + key0 + quad * 8;
    short8 av0 = *(const short8*)vp;
    short8 av1 = *(const short8*)(vp + 32);
    f32x4 s0 = __builtin_amdgcn_mfma_f32_16x16x32_bf16(a0, qf, z4, 0, 0, 0);
    f32x4 s1 = __builtin_amdgcn_mfma_f32_16x16x32_bf16(a1, qf, z4, 0, 0, 0);
    f32x4 s2 = __builtin_amdgcn_mfma_f32_16x16x32_bf16(a2, qf, z4, 0, 0, 0);
    f32x4 s3 = __builtin_amdgcn_mfma_f32_16x16x32_bf16(a3, qf, z4, 0, 0, 0);
    float e0 = exp2f(fminf(s0[0], 30.f)), e1 = exp2f(fminf(s0[1], 30.f));
    float e2 = exp2f(fminf(s0[2], 30.f)), e3 = exp2f(fminf(s0[3], 30.f));
    float e4 = exp2f(fminf(s1[0], 30.f)), e5 = exp2f(fminf(s1[1], 30.f));
    float e6 = exp2f(fminf(s1[2], 30.f)), e7 = exp2f(fminf(s1[3], 30.f));
    uint4v u;
    u.x = pkt(e0, e1); u.y = pkt(e2, e3); u.z = pkt(e4, e5); u.w = pkt(e6, e7);
    short8 p0 = __builtin_bit_cast(short8, u);
    float f0 = exp2f(fminf(s2[0], 30.f)), f1 = exp2f(fminf(s2[1], 30.f));
    float f2 = exp2f(fminf(s2[2], 30.f)), f3 = exp2f(fminf(s2[3], 30.f));
    float f4 = exp2f(fminf(s3[0], 30.f)), f5 = exp2f(fminf(s3[1], 30.f));
    float f6 = exp2f(fminf(s3[2], 30.f)), f7 = exp2f(fminf(s3[3], 30.f));
    uint4v w;
    w.x = pkt(f0, f1); w.y = pkt(f2, f3); w.z = pkt(f4, f5); w.w = pkt(f6, f7);
    short8 p1 = __builtin_bit_cast(short8, w);
    acc  = __builtin_amdgcn_mfma_f32_16x16x32_bf16(av0, p0, acc, 0, 0, 0);
    acc  = __builtin_amdgcn_mfma_f32_16x16x32_bf16(av1, p1, acc, 0, 0, 0);
    acc2 = __builtin_amdgcn_mfma_f32_16x16x32_bf16(ones, p0, acc2, 0, 0, 0);
    acc2 = __builtin_amdgcn_mfma_f32_16x16x32_bf16(ones, p1, acc2, 0, 0, 0);
  }
  float4 a4; a4.x = acc[0]; a4.y = acc[1]; a4.z = acc[2]; a4.w = acc[3];
  *(float4*)&LO[wave][m16][quad * 4] = a4;      // LO[q][dim] partial (O^T C-layout)
  if (lane < 16) LL[wave][lane] = acc2[0];      // quad0: acc2[0] = sum_e for q=m16
  __syncthreads();
  if (wave == 0) {
    float4 o = *(float4*)&LO[0][m16][quad * 4];
    float lt = LL[0][m16];
#pragma unroll
    for (int w2 = 1; w2 < 4; w2++) {
      float4 t = *(float4*)&LO[w2][m16][quad * 4];
      o.x += t.x; o.y += t.y; o.z += t.z; o.w += t.w;
      lt += LL[w2][m16];
    }
    float inv = 1.0f / fmaxf(lt, 1e-30f);
    float4 r4; r4.x = o.x * inv; r4.y = o.y * inv; r4.z = o.z * inv; r4.w = o.w * inv;
    *(float4*)(O + (size_t)(r0 + m16) * DM + h * 16 + quad * 4) = r4;
  }
}

// ---------------- LayerNorm (one wave per 128-wide row) ----------------
__global__ __launch_bounds__(256) void k_ln(const float* __restrict__ X,
    const float* __restrict__ G, const float* __restrict__ B, float* __restrict__ O) {
  int row = blockIdx.x * 4 + (threadIdx.x >> 6);
  int lane = threadIdx.x & 63;
  float v0 = X[(size_t)row*DM + lane];
  float v1 = X[(size_t)row*DM + 64 + lane];
  float s = v0 + v1;
  for (int off = 1; off < 64; off <<= 1) s += __shfl_xor(s, off);
  float mean = s * (1.0f/128.0f);
  float d0 = v0 - mean, d1 = v1 - mean;
  float s2 = d0*d0 + d1*d1;
  for (int off = 1; off < 64; off <<= 1) s2 += __shfl_xor(s2, off);
  float rstd = rsqrtf(s2 * (1.0f/128.0f) + 1e-5f);
  O[(size_t)row*DM + lane]      = d0*rstd*G[lane]    + B[lane];
  O[(size_t)row*DM + 64 + lane] = d1*rstd*G[64+lane] + B[64+lane];
}

// ---------------- fused: H = X + relu(ln1(T)); H2 = ln2(H) ----------------
__global__ __launch_bounds__(256) void k_ln2(const float* __restrict__ T,
    const float* __restrict__ G1, const float* __restrict__ Be1,
    const float* __restrict__ X,
    const float* __restrict__ G2, const float* __restrict__ Be2,
    float* __restrict__ H, float* __restrict__ H2) {
  int row = blockIdx.x * 4 + (threadIdx.x >> 6);
  int lane = threadIdx.x & 63;
  float v0 = T[(size_t)row*DM + lane];
  float v1 = T[(size_t)row*DM + 64 + lane];
  float s = v0 + v1;
  for (int off = 1; off < 64; off <<= 1) s += __shfl_xor(s, off);
  float mean = s * (1.0f/128.0f);
  float d0 = v0 - mean, d1 = v1 - mean;
  float s2 = d0*d0 + d1*d1;
  for (int off = 1; off < 64; off <<= 1) s2 += __shfl_xor(s2, off);
  float rstd = rsqrtf(s2 * (1.0f/128.0f) + 1e-5f);
  float f0 = d0*rstd*G1[lane]    + Be1[lane];
  float f1 = d1*rstd*G1[64+lane] + Be1[64+lane];
  f0 = f0 > 0.f ? f0 : 0.f;
  f1 = f1 > 0.f ? f1 : 0.f;
  float h0 = X[(size_t)row*DM + lane]      + f0;
  float h1 = X[(size_t)row*DM + 64 + lane] + f1;
  H[(size_t)row*DM + lane]      = h0;
  H[(size_t)row*DM + 64 + lane] = h1;
  float t = h0 + h1;
  for (int off = 1; off < 64; off <<= 1) t += __shfl_xor(t, off);
  float mean2 = t * (1.0f/128.0f);
  float e0 = h0 - mean2, e1 = h1 - mean2;
  float t2 = e0*e0 + e1*e1;
  for (int off = 1; off < 64; off <<= 1) t2 += __shfl_xor(t2, off);
  float rstd2 = rsqrtf(t2 * (1.0f/128.0f) + 1e-5f);
  H2[(size_t)row*DM + lane]      = e0*rstd2*G2[lane]    + Be2[lane];
  H2[(size_t)row*DM + 64 + lane] = e1*rstd2*G2[64+lane] + Be2[64+lane];
}

// ---------------- edge attention: exp(score) per (edge, head) -> EB ----------------
__global__ __launch_bounds__(256) void k_edge_attn(const int* __restrict__ EI,
    const float* __restrict__ Q, const float* __restrict__ Kl, float* __restrict__ EB) {
  int is64 = detect64(EI);
  int e = blockIdx.x * 256 + threadIdx.x;
  int s = is64 ? EI[2*e]      : EI[e];
  int d = is64 ? EI[2*(NE+e)] : EI[NE+e];
  s = min(max(s, 0), NN-1); d = min(max(d, 0), NN-1);
  const float4* q4 = (const float4*)(Q  + (size_t)d * DM);
  const float4* k4 = (const float4*)(Kl + (size_t)s * DM);
  float acc[8] = {};
#pragma unroll
  for (int c = 0; c < 32; c++) {
    float4 qa = q4[c], ka = k4[c];
    acc[c >> 2] += qa.x*ka.x + qa.y*ka.y + qa.z*ka.z + qa.w*ka.w;
  }
#pragma unroll
  for (int h = 0; h < 8; h++)
    EB[(size_t)e*8 + h] = exp2f(fminf(acc[h] * ESCALE, 43.0f));   // base-2 softmax == base-e
}

// ---------------- CSR-by-dst build ----------------
__global__ __launch_bounds__(256) void k_hist(const int* __restrict__ EI, int* __restrict__ deg) {
  int is64 = detect64(EI);
  int e = blockIdx.x * 256 + threadIdx.x;
  int d = is64 ? EI[2*(NE+e)] : EI[NE+e];
  d = min(max(d, 0), NN-1);
  atomicAdd(&deg[d], 1);
}
__global__ __launch_bounds__(256) void k_scan(const int* __restrict__ deg,
    int* __restrict__ offs, int* __restrict__ cursor) {
  __shared__ int sums[256];
  int t = threadIdx.x;
  int loc[16];
  int s = 0;
#pragma unroll
  for (int i = 0; i < 16; i++) { loc[i] = s; s += deg[t*16 + i]; }
  sums[t] = s;
  __syncthreads();
  for (int d = 1; d < 256; d <<= 1) {
    int v = (t >= d) ? sums[t - d] : 0;
    __syncthreads();
    sums[t] += v;
    __syncthreads();
  }
  int base = sums[t] - s;
#pragma unroll
  for (int i = 0; i < 16; i++) {
    offs[t*16 + i] = base + loc[i];
    cursor[t*16 + i] = base + loc[i];
  }
}
__global__ __launch_bounds__(256) void k_scatter(const int* __restrict__ EI,
    int* __restrict__ cursor, int* __restrict__ elist) {
  int is64 = detect64(EI);
  int e = blockIdx.x * 256 + threadIdx.x;
  int d = is64 ? EI[2*(NE+e)] : EI[NE+e];
  d = min(max(d, 0), NN-1);
  int slot = atomicAdd(&cursor[d], 1);
  elist[slot] = e;
}

// ---------------- per-dst aggregation (atomic-free) ----------------
__global__ __launch_bounds__(256) void k_edge_agg2(const int* __restrict__ EI,
    const int* __restrict__ deg, const int* __restrict__ offs,
    const int* __restrict__ elist, const float* __restrict__ Vl,
    const float* __restrict__ EB, float* __restrict__ AG) {
  int is64 = detect64(EI);
  int d = blockIdx.x * 4 + (threadIdx.x >> 6);
  int lane = threadIdx.x & 63;
  int degd = deg[d], start = offs[d];
  int hh = lane >> 3;
  float ss = 0.f;
  for (int i = lane & 7; i < degd; i += 8)
    ss += EB[(size_t)elist[start + i] * 8 + hh];
  for (int o = 1; o < 8; o <<= 1) ss += __shfl_xor(ss, o);
  float inv = 1.0f / fmaxf(ss, 1e-30f);
  float ax = 0.f, ay = 0.f;
  for (int i = 0; i < degd; i++) {
    int e = elist[start + i];
    int s = is64 ? EI[2*e] : EI[e];
    s = min(max(s, 0), NN-1);
    float a = EB[(size_t)e*8 + hh] * inv;
    float2 v = *(const float2*)(Vl + (size_t)s * DM + 2 * lane);
    ax += a * v.x; ay += a * v.y;
  }
  float2 r; r.x = ax; r.y = ay;
  *(float2*)(AG + (size_t)d * DM + 2 * lane) = r;
}

extern "C" void kernel_launch(void* const* d_in, const int* in_sizes, int n_in,
                              void* d_out, int out_size, void* d_ws, size_t ws_size,
                              hipStream_t stream) {
  const float* x     = (const float*)d_in[0];
  const int*   ei    = (const int*)  d_in[1];
  const float* wq_l  = (const float*)d_in[2];  const float* bq_l = (const float*)d_in[3];
  const float* wk_l  = (const float*)d_in[4];  const float* bk_l = (const float*)d_in[5];
  const float* wv_l  = (const float*)d_in[6];  const float* bv_l = (const float*)d_in[7];
  const float* wg    = (const float*)d_in[8];  const float* bg   = (const float*)d_in[9];
  const float* wq_g  = (const float*)d_in[10]; const float* bq_g = (const float*)d_in[11];
  const float* wk_g  = (const float*)d_in[12]; const float* bk_g = (const float*)d_in[13];
  const float* wv_g  = (const float*)d_in[14]; const float* bv_g = (const float*)d_in[15];
  const float* wo_g  = (const float*)d_in[16]; const float* bo_g = (const float*)d_in[17];
  const float* wf    = (const float*)d_in[18]; const float* bff  = (const float*)d_in[19];
  const float* gf    = (const float*)d_in[20]; const float* betaf= (const float*)d_in[21];
  const float* w1    = (const float*)d_in[22]; const float* b1   = (const float*)d_in[23];
  const float* w2    = (const float*)d_in[24]; const float* b2   = (const float*)d_in[25];
  const float* g1    = (const float*)d_in[26]; const float* be1  = (const float*)d_in[27];
  const float* g2    = (const float*)d_in[28]; const float* be2  = (const float*)d_in[29];
  float* out = (float*)d_out;

  const size_t NEED = (size_t)(3178512 + 131072) * 4;
  if (ws_size < NEED) {
    k_fill<<<2048, 256, 0, stream>>>(out, 100.0f, NN*DM);
    return;
  }

  float* W  = (float*)d_ws;
  float* A  = W + 0;        // localQ -> local -> h2
  float* B  = W + 524288;   // localK -> xn -> go   (t1 spans B..E)
  float* Cc = W + 1048576;  // localV -> qgb(bf16) -> gop
  float* D0 = W + 1572864;  // eb[lo] -> kgb(bf16) -> tmpf
  float* D1 = W + 2097152;  // eb[hi] -> vgT(bf16)
  float* E  = W + 2621440;  // agg -> h
  int* deg    = (int*)(W + 3145728);
  int* cursor = deg + 4096;
  int* offs   = deg + 8192;
  int* elist  = (int*)(W + 3178512);
  float* eb = D0;
  unsigned short* qgb = (unsigned short*)Cc;
  unsigned short* kgb = (unsigned short*)D0;
  unsigned short* vgT = (unsigned short*)D1;
  float* t1 = B;

  dim3 b256(256);
  dim3 gQKV(64, 6);
  dim3 gN128(64, 2);
  dim3 gN512(64, 8);

  hipMemsetAsync(deg, 0, 4096 * sizeof(int), stream);

  // local Q,K,V projections (fused, fp32 out)
  gemm_qkv<<<gQKV, b256, 0, stream>>>(x, wq_l, wk_l, wv_l, bq_l, bk_l, bv_l,
                                      A, B, Cc, 0, 0, 0, 1.f, 1.f, 1.f);

  // edge segment softmax + aggregation (CSR, atomic-free aggregation)
  k_hist<<<512, b256, 0, stream>>>(ei, deg);
  k_scan<<<1, b256, 0, stream>>>(deg, offs, cursor);
  k_scatter<<<512, b256, 0, stream>>>(ei, cursor, elist);
  k_edge_attn<<<512, b256, 0, stream>>>(ei, A, B, eb);
  k_edge_agg2<<<1024, b256, 0, stream>>>(ei, deg, offs, elist, Cc, eb, E);

  // gate: g = sigmoid(concat(x, agg) @ wg.T + bg); local = g*agg + (1-g)*x
  gemm_mfma<<<gN128, b256, 0, stream>>>(x,128, E,128,128, wg, bg, nullptr, E, x, A, 128, 256, 2, 0, 1.f);

  // global branch: ln -> fused QKV (Q pre-scaled bf16, K bf16, V^T feat-major) -> attention
  k_ln<<<1024, b256, 0, stream>>>(x, g1, be1, B);
  gemm_qkv<<<gQKV, b256, 0, stream>>>(B, wq_g, wk_g, wv_g, bq_g, bk_g, bv_g,
                                      qgb, kgb, vgT, 1, 1, 2, QSCALE, 1.f, 1.f);
  k_gattn4<<<2048, b256, 0, stream>>>(qgb, kgb, vgT, B);
  gemm_mfma<<<gN128, b256, 0, stream>>>(B,128, nullptr,0,128, wo_g, bo_g, nullptr,nullptr,nullptr, Cc, 128, 128, 0, 0, 1.f);

  // fusion + residual: tmpf = concat(local, gop) @ wf.T + bf; h = x + relu(ln(tmpf)); h2 = ln(h)
  gemm_mfma<<<gN128, b256, 0, stream>>>(A,128, Cc,128,128, wf, bff, nullptr,nullptr,nullptr, D0, 128, 256, 0, 0, 1.f);
  k_ln2<<<1024, b256, 0, stream>>>(D0, gf, betaf, x, g2, be2, E, A);

  // FFN: out = h + gelu(h2@w1.T+b1) @ w2.T + b2
  gemm_mfma<<<gN512, b256, 0, stream>>>(A,128, nullptr,0,128, w1, b1, nullptr,nullptr,nullptr, t1, 512, 128, 1, 0, 1.f);
  gemm_mfma<<<gN128, b256, 0, stream>>>(t1,512, nullptr,0,512, w2, b2, E, nullptr,nullptr, out, 128, 512, 0, 0, 1.f);
}

// Round 9
// 327.221 us; speedup vs baseline: 2.4059x; 1.0708x over previous
//
#include <hip/hip_runtime.h>
#include <math.h>

#define NN 4096
#define DM 128
#define NE 131072
#define QSCALE 0.36067376022224085f   // 0.25 * log2(e): exp(S/4) == exp2(S_prescaled)
#define ESCALE 0.36067376022224085f

typedef short short8 __attribute__((ext_vector_type(8)));
typedef float f32x4  __attribute__((ext_vector_type(4)));
typedef unsigned int uint4v __attribute__((ext_vector_type(4)));

static __device__ __forceinline__ unsigned pk2(float lo, float hi) {
  union { float f; unsigned u; } a, b; a.f = lo; b.f = hi;
  return ((b.u + 0x8000u) & 0xffff0000u) | ((a.u + 0x8000u) >> 16);
}
static __device__ __forceinline__ unsigned pkt(float lo, float hi) {
  union { float f; unsigned u; } a, b; a.f = lo; b.f = hi;
  return (b.u & 0xffff0000u) | (a.u >> 16);
}
static __device__ __forceinline__ unsigned short f2bh(float f) {
  union { float f; unsigned u; } v; v.f = f;
  return (unsigned short)((v.u + 0x8000u) >> 16);
}
static __device__ __forceinline__ float b2f16(unsigned short u) {
  union { unsigned u; float f; } v; v.u = ((unsigned)u) << 16; return v.f;
}
static __device__ __forceinline__ short8 cvt8(float4 a, float4 b) {
  unsigned u0 = pk2(a.x, a.y), u1 = pk2(a.z, a.w);
  unsigned u2 = pk2(b.x, b.y), u3 = pk2(b.z, b.w);
  short8 r;
  r[0]=(short)(u0 & 0xffffu); r[1]=(short)(u0 >> 16);
  r[2]=(short)(u1 & 0xffffu); r[3]=(short)(u1 >> 16);
  r[4]=(short)(u2 & 0xffffu); r[5]=(short)(u2 >> 16);
  r[6]=(short)(u3 & 0xffffu); r[7]=(short)(u3 >> 16);
  return r;
}
static __device__ __forceinline__ int detect64(const int* __restrict__ EI) {
  int v = EI[2 * (threadIdx.x & 63) + 1];
  for (int off = 1; off < 64; off <<= 1) v |= __shfl_xor(v, off);
  return (v == 0) ? 1 : 0;
}

__global__ __launch_bounds__(256) void k_fill(float* __restrict__ out, float v, int n) {
  int i = blockIdx.x * 256 + threadIdx.x;
  if (i < n) out[i] = v;
}

// ---------------- MFMA GEMM: C = epi(A @ W^T + Bias) * oscale ----------------
// omode: 0 fp32 [m][n]; 1 bf16 [m][n]; 2 bf16 [n][NN+m] (feat-major V^T).
__global__ __launch_bounds__(256) void gemm_mfma(
    const float* __restrict__ A0, int lda0,
    const float* __restrict__ A1, int lda1, int ksplit,
    const float* __restrict__ Wt, const float* __restrict__ Bias,
    const float* __restrict__ Res, const float* __restrict__ E0, const float* __restrict__ E1,
    void* __restrict__ Cp, int Nt, int K, int act, int omode, float oscale)
{
  __shared__ short Asm[64][40];
  __shared__ short Wsm[64][40];
  const int m0 = blockIdx.x * 64, n0 = blockIdx.y * 64;
  const int tid = threadIdx.x;
  const int srow = tid >> 2, koff = (tid & 3) * 8;
  const int lane = tid & 63, wave = tid >> 6;
  const int quad = lane >> 4, m16 = lane & 15;
  f32x4 acc[4];
#pragma unroll
  for (int i = 0; i < 4; i++) acc[i] = {0.f, 0.f, 0.f, 0.f};

  for (int k0 = 0; k0 < K; k0 += 32) {
    const int kg = k0 + koff;
    const float* ap = (kg < ksplit) ? (A0 + (size_t)(m0 + srow) * lda0 + kg)
                                    : (A1 + (size_t)(m0 + srow) * lda1 + (kg - ksplit));
    float4 a0 = *(const float4*)ap, a1 = *(const float4*)(ap + 4);
    const float* wp = Wt + (size_t)(n0 + srow) * K + kg;
    float4 w0 = *(const float4*)wp, w1v = *(const float4*)(wp + 4);
    __syncthreads();
    *(short8*)&Asm[srow][koff] = cvt8(a0, a1);
    *(short8*)&Wsm[srow][koff] = cvt8(w0, w1v);
    __syncthreads();
    short8 af = *(short8*)&Asm[wave * 16 + m16][quad * 8];
#pragma unroll
    for (int nt = 0; nt < 4; nt++) {
      short8 bf = *(short8*)&Wsm[nt * 16 + m16][quad * 8];
      acc[nt] = __builtin_amdgcn_mfma_f32_16x16x32_bf16(af, bf, acc[nt], 0, 0, 0);
    }
  }
#pragma unroll
  for (int nt = 0; nt < 4; nt++) {
#pragma unroll
    for (int r = 0; r < 4; r++) {
      const int m = m0 + wave * 16 + quad * 4 + r;
      const int n = n0 + nt * 16 + m16;
      float v = acc[nt][r] + Bias[n];
      size_t oi = (size_t)m * Nt + n;
      if (act == 1) v = 0.5f * v * (1.0f + erff(v * 0.70710678118654752f));
      else if (act == 2) {
        float g = 1.0f / (1.0f + __expf(fminf(fmaxf(-v, -80.f), 80.f)));
        v = g * E0[oi] + (1.0f - g) * E1[oi];
      }
      if (Res) v += Res[oi];
      v *= oscale;
      if (omode == 0)      ((float*)Cp)[oi] = v;
      else if (omode == 1) ((unsigned short*)Cp)[oi] = f2bh(v);
      else                 ((unsigned short*)Cp)[(size_t)n * NN + m] = f2bh(v);
    }
  }
}

// ---------------- six-way QKV GEMM: grid (64,12); g = y>>1 selects projection ----------------
// g 0..2: local Q,K,V from X; g 3..5: global Q,K,V from XN. K=Nt=128.
__global__ __launch_bounds__(256) void gemm_six(
    const float* __restrict__ X, const float* __restrict__ XN,
    const float* __restrict__ W0, const float* __restrict__ W1, const float* __restrict__ W2,
    const float* __restrict__ W3, const float* __restrict__ W4, const float* __restrict__ W5,
    const float* __restrict__ B0, const float* __restrict__ B1, const float* __restrict__ B2,
    const float* __restrict__ B3, const float* __restrict__ B4, const float* __restrict__ B5,
    void* __restrict__ O0, void* __restrict__ O1, void* __restrict__ O2,
    void* __restrict__ O3, void* __restrict__ O4, void* __restrict__ O5)
{
  __shared__ short Asm[64][40];
  __shared__ short Wsm[64][40];
  const int g = blockIdx.y >> 1;
  const float* A   = (g < 3) ? X : XN;
  const float* Wt  = (g==0)?W0:(g==1)?W1:(g==2)?W2:(g==3)?W3:(g==4)?W4:W5;
  const float* Bia = (g==0)?B0:(g==1)?B1:(g==2)?B2:(g==3)?B3:(g==4)?B4:B5;
  void* Cp         = (g==0)?O0:(g==1)?O1:(g==2)?O2:(g==3)?O3:(g==4)?O4:O5;
  const int omode  = (g==2)?1:(g>=3)?((g==5)?2:1):0;   // lV bf16, qg/kg bf16, vgT feat-major
  const float osc  = (g==3)? QSCALE : 1.f;
  const int m0 = blockIdx.x * 64, n0 = (blockIdx.y & 1) * 64;
  const int tid = threadIdx.x;
  const int srow = tid >> 2, koff = (tid & 3) * 8;
  const int lane = tid & 63, wave = tid >> 6;
  const int quad = lane >> 4, m16 = lane & 15;
  f32x4 acc[4];
#pragma unroll
  for (int i = 0; i < 4; i++) acc[i] = {0.f, 0.f, 0.f, 0.f};

  for (int k0 = 0; k0 < 128; k0 += 32) {
    const int kg = k0 + koff;
    const float* ap = A + (size_t)(m0 + srow) * 128 + kg;
    float4 a0 = *(const float4*)ap, a1 = *(const float4*)(ap + 4);
    const float* wp = Wt + (size_t)(n0 + srow) * 128 + kg;
    float4 w0 = *(const float4*)wp, w1v = *(const float4*)(wp + 4);
    __syncthreads();
    *(short8*)&Asm[srow][koff] = cvt8(a0, a1);
    *(short8*)&Wsm[srow][koff] = cvt8(w0, w1v);
    __syncthreads();
    short8 af = *(short8*)&Asm[wave * 16 + m16][quad * 8];
#pragma unroll
    for (int nt = 0; nt < 4; nt++) {
      short8 bf = *(short8*)&Wsm[nt * 16 + m16][quad * 8];
      acc[nt] = __builtin_amdgcn_mfma_f32_16x16x32_bf16(af, bf, acc[nt], 0, 0, 0);
    }
  }
#pragma unroll
  for (int nt = 0; nt < 4; nt++) {
#pragma unroll
    for (int r = 0; r < 4; r++) {
      const int m = m0 + wave * 16 + quad * 4 + r;
      const int n = n0 + nt * 16 + m16;
      float v = (acc[nt][r] + Bia[n]) * osc;
      size_t oi = (size_t)m * 128 + n;
      if (omode == 0)      ((float*)Cp)[oi] = v;
      else if (omode == 1) ((unsigned short*)Cp)[oi] = f2bh(v);
      else                 ((unsigned short*)Cp)[(size_t)n * NN + m] = f2bh(v);
    }
  }
}

// ---------------- dual GEMM: y<2 = gate (K=256, act2), y>=2 = wo (K=128) ----------------
__global__ __launch_bounds__(256) void gemm_dual(
    const float* __restrict__ X, const float* __restrict__ AGG,
    const float* __restrict__ GO,
    const float* __restrict__ Wg, const float* __restrict__ Bg,
    const float* __restrict__ Wo, const float* __restrict__ Bo,
    float* __restrict__ LOCAL, float* __restrict__ GOP)
{
  __shared__ short Asm[64][40];
  __shared__ short Wsm[64][40];
  const int isGate = (blockIdx.y < 2);
  const float* A0  = isGate ? X   : GO;
  const float* A1  = isGate ? AGG : GO;
  const int ksplit = 128;
  const int K      = isGate ? 256 : 128;
  const float* Wt  = isGate ? Wg : Wo;
  const float* Bia = isGate ? Bg : Bo;
  float* Cp        = isGate ? LOCAL : GOP;
  const int m0 = blockIdx.x * 64, n0 = (blockIdx.y & 1) * 64;
  const int tid = threadIdx.x;
  const int srow = tid >> 2, koff = (tid & 3) * 8;
  const int lane = tid & 63, wave = tid >> 6;
  const int quad = lane >> 4, m16 = lane & 15;
  f32x4 acc[4];
#pragma unroll
  for (int i = 0; i < 4; i++) acc[i] = {0.f, 0.f, 0.f, 0.f};

  for (int k0 = 0; k0 < K; k0 += 32) {
    const int kg = k0 + koff;
    const float* ap = (kg < ksplit) ? (A0 + (size_t)(m0 + srow) * 128 + kg)
                                    : (A1 + (size_t)(m0 + srow) * 128 + (kg - ksplit));
    float4 a0 = *(const float4*)ap, a1 = *(const float4*)(ap + 4);
    const float* wp = Wt + (size_t)(n0 + srow) * K + kg;
    float4 w0 = *(const float4*)wp, w1v = *(const float4*)(wp + 4);
    __syncthreads();
    *(short8*)&Asm[srow][koff] = cvt8(a0, a1);
    *(short8*)&Wsm[srow][koff] = cvt8(w0, w1v);
    __syncthreads();
    short8 af = *(short8*)&Asm[wave * 16 + m16][quad * 8];
#pragma unroll
    for (int nt = 0; nt < 4; nt++) {
      short8 bf = *(short8*)&Wsm[nt * 16 + m16][quad * 8];
      acc[nt] = __builtin_amdgcn_mfma_f32_16x16x32_bf16(af, bf, acc[nt], 0, 0, 0);
    }
  }
#pragma unroll
  for (int nt = 0; nt < 4; nt++) {
#pragma unroll
    for (int r = 0; r < 4; r++) {
      const int m = m0 + wave * 16 + quad * 4 + r;
      const int n = n0 + nt * 16 + m16;
      float v = acc[nt][r] + Bia[n];
      size_t oi = (size_t)m * 128 + n;
      if (isGate) {
        float g = 1.0f / (1.0f + __expf(fminf(fmaxf(-v, -80.f), 80.f)));
        v = g * AGG[oi] + (1.0f - g) * X[oi];
      }
      Cp[oi] = v;
    }
  }
}

// ---------------- global attention (R8-proven), LDS-free K-loop ----------------
__global__ __launch_bounds__(256) void k_gattn4(
    const unsigned short* __restrict__ Qb, const unsigned short* __restrict__ Kb,
    const unsigned short* __restrict__ VT, float* __restrict__ O)
{
  __shared__ float LO[4][16][16];
  __shared__ float LL[4][16];
  const int h = blockIdx.x >> 8, qt = blockIdx.x & 255;
  const int tid = threadIdx.x, lane = tid & 63, wave = tid >> 6;
  const int quad = lane >> 4, m16 = lane & 15;
  const int r0 = qt * 16;
  const short8 z8 = {0,0,0,0,0,0,0,0};
  const f32x4  z4 = {0.f,0.f,0.f,0.f};
  short8 qf = z8;
  if (quad < 2) qf = *(const short8*)(Qb + (size_t)(r0 + m16) * DM + h * 16 + quad * 8);
  short8 ones;
#pragma unroll
  for (int i = 0; i < 8; i++) ones[i] = (short)0x3F80;
  const int kperm = (m16 >> 2) * 8 + (m16 & 3);
  const int kbase = wave * 1024;
  f32x4 acc = z4, acc2 = z4;
  short8 a0 = z8, a1 = z8, a2 = z8, a3 = z8;
  for (int kt = 0; kt < 16; kt++) {
    const int key0 = kbase + kt * 64;
    if (quad < 2) {
      const unsigned short* kp = Kb + (size_t)(key0 + kperm) * DM + h * 16 + quad * 8;
      a0 = *(const short8*)kp;
      a1 = *(const short8*)(kp + 4 * DM);
      a2 = *(const short8*)(kp + 32 * DM);
      a3 = *(const short8*)(kp + 36 * DM);
    }
    const unsigned short* vp = VT + (size_t)(h * 16 + m16) * NN + key0 + quad * 8;
    short8 av0 = *(const short8*)vp;
    short8 av1 = *(const short8*)(vp + 32);
    f32x4 s0 = __builtin_amdgcn_mfma_f32_16x16x32_bf16(a0, qf, z4, 0, 0, 0);
    f32x4 s1 = __builtin_amdgcn_mfma_f32_16x16x32_bf16(a1, qf, z4, 0, 0, 0);
    f32x4 s2 = __builtin_amdgcn_mfma_f32_16x16x32_bf16(a2, qf, z4, 0, 0, 0);
    f32x4 s3 = __builtin_amdgcn_mfma_f32_16x16x32_bf16(a3, qf, z4, 0, 0, 0);
    float e0 = exp2f(fminf(s0[0], 30.f)), e1 = exp2f(fminf(s0[1], 30.f));
    float e2 = exp2f(fminf(s0[2], 30.f)), e3 = exp2f(fminf(s0[3], 30.f));
    float e4 = exp2f(fminf(s1[0], 30.f)), e5 = exp2f(fminf(s1[1], 30.f));
    float e6 = exp2f(fminf(s1[2], 30.f)), e7 = exp2f(fminf(s1[3], 30.f));
    uint4v u;
    u.x = pkt(e0, e1); u.y = pkt(e2, e3); u.z = pkt(e4, e5); u.w = pkt(e6, e7);
    short8 p0 = __builtin_bit_cast(short8, u);
    float f0 = exp2f(fminf(s2[0], 30.f)), f1 = exp2f(fminf(s2[1], 30.f));
    float f2 = exp2f(fminf(s2[2], 30.f)), f3 = exp2f(fminf(s2[3], 30.f));
    float f4 = exp2f(fminf(s3[0], 30.f)), f5 = exp2f(fminf(s3[1], 30.f));
    float f6 = exp2f(fminf(s3[2], 30.f)), f7 = exp2f(fminf(s3[3], 30.f));
    uint4v w;
    w.x = pkt(f0, f1); w.y = pkt(f2, f3); w.z = pkt(f4, f5); w.w = pkt(f6, f7);
    short8 p1 = __builtin_bit_cast(short8, w);
    acc  = __builtin_amdgcn_mfma_f32_16x16x32_bf16(av0, p0, acc, 0, 0, 0);
    acc  = __builtin_amdgcn_mfma_f32_16x16x32_bf16(av1, p1, acc, 0, 0, 0);
    acc2 = __builtin_amdgcn_mfma_f32_16x16x32_bf16(ones, p0, acc2, 0, 0, 0);
    acc2 = __builtin_amdgcn_mfma_f32_16x16x32_bf16(ones, p1, acc2, 0, 0, 0);
  }
  float4 a4; a4.x = acc[0]; a4.y = acc[1]; a4.z = acc[2]; a4.w = acc[3];
  *(float4*)&LO[wave][m16][quad * 4] = a4;
  if (lane < 16) LL[wave][lane] = acc2[0];
  __syncthreads();
  if (wave == 0) {
    float4 o = *(float4*)&LO[0][m16][quad * 4];
    float lt = LL[0][m16];
#pragma unroll
    for (int w2 = 1; w2 < 4; w2++) {
      float4 t = *(float4*)&LO[w2][m16][quad * 4];
      o.x += t.x; o.y += t.y; o.z += t.z; o.w += t.w;
      lt += LL[w2][m16];
    }
    float inv = 1.0f / fmaxf(lt, 1e-30f);
    float4 r4; r4.x = o.x * inv; r4.y = o.y * inv; r4.z = o.z * inv; r4.w = o.w * inv;
    *(float4*)(O + (size_t)(r0 + m16) * DM + h * 16 + quad * 4) = r4;
  }
}

// ---------------- LayerNorm ----------------
__global__ __launch_bounds__(256) void k_ln(const float* __restrict__ X,
    const float* __restrict__ G, const float* __restrict__ B, float* __restrict__ O) {
  int row = blockIdx.x * 4 + (threadIdx.x >> 6);
  int lane = threadIdx.x & 63;
  float v0 = X[(size_t)row*DM + lane];
  float v1 = X[(size_t)row*DM + 64 + lane];
  float s = v0 + v1;
  for (int off = 1; off < 64; off <<= 1) s += __shfl_xor(s, off);
  float mean = s * (1.0f/128.0f);
  float d0 = v0 - mean, d1 = v1 - mean;
  float s2 = d0*d0 + d1*d1;
  for (int off = 1; off < 64; off <<= 1) s2 += __shfl_xor(s2, off);
  float rstd = rsqrtf(s2 * (1.0f/128.0f) + 1e-5f);
  O[(size_t)row*DM + lane]      = d0*rstd*G[lane]    + B[lane];
  O[(size_t)row*DM + 64 + lane] = d1*rstd*G[64+lane] + B[64+lane];
}

// ---------------- fused: H = X + relu(ln1(T)); H2 = ln2(H) ----------------
__global__ __launch_bounds__(256) void k_ln2(const float* __restrict__ T,
    const float* __restrict__ G1, const float* __restrict__ Be1,
    const float* __restrict__ X,
    const float* __restrict__ G2, const float* __restrict__ Be2,
    float* __restrict__ H, float* __restrict__ H2) {
  int row = blockIdx.x * 4 + (threadIdx.x >> 6);
  int lane = threadIdx.x & 63;
  float v0 = T[(size_t)row*DM + lane];
  float v1 = T[(size_t)row*DM + 64 + lane];
  float s = v0 + v1;
  for (int off = 1; off < 64; off <<= 1) s += __shfl_xor(s, off);
  float mean = s * (1.0f/128.0f);
  float d0 = v0 - mean, d1 = v1 - mean;
  float s2 = d0*d0 + d1*d1;
  for (int off = 1; off < 64; off <<= 1) s2 += __shfl_xor(s2, off);
  float rstd = rsqrtf(s2 * (1.0f/128.0f) + 1e-5f);
  float f0 = d0*rstd*G1[lane]    + Be1[lane];
  float f1 = d1*rstd*G1[64+lane] + Be1[64+lane];
  f0 = f0 > 0.f ? f0 : 0.f;
  f1 = f1 > 0.f ? f1 : 0.f;
  float h0 = X[(size_t)row*DM + lane]      + f0;
  float h1 = X[(size_t)row*DM + 64 + lane] + f1;
  H[(size_t)row*DM + lane]      = h0;
  H[(size_t)row*DM + 64 + lane] = h1;
  float t = h0 + h1;
  for (int off = 1; off < 64; off <<= 1) t += __shfl_xor(t, off);
  float mean2 = t * (1.0f/128.0f);
  float e0 = h0 - mean2, e1 = h1 - mean2;
  float t2 = e0*e0 + e1*e1;
  for (int off = 1; off < 64; off <<= 1) t2 += __shfl_xor(t2, off);
  float rstd2 = rsqrtf(t2 * (1.0f/128.0f) + 1e-5f);
  H2[(size_t)row*DM + lane]      = e0*rstd2*G2[lane]    + Be2[lane];
  H2[(size_t)row*DM + 64 + lane] = e1*rstd2*G2[64+lane] + Be2[64+lane];
}

// ---------------- edge attention: exp(score) per (edge, head) -> EB (bf16) ----------------
__global__ __launch_bounds__(256) void k_edge_attn(const int* __restrict__ EI,
    const float* __restrict__ Q, const float* __restrict__ Kl,
    unsigned short* __restrict__ EB) {
  int is64 = detect64(EI);
  int e = blockIdx.x * 256 + threadIdx.x;
  int s = is64 ? EI[2*e]      : EI[e];
  int d = is64 ? EI[2*(NE+e)] : EI[NE+e];
  s = min(max(s, 0), NN-1); d = min(max(d, 0), NN-1);
  const float4* q4 = (const float4*)(Q  + (size_t)d * DM);
  const float4* k4 = (const float4*)(Kl + (size_t)s * DM);
  float acc[8] = {};
#pragma unroll
  for (int c = 0; c < 32; c++) {
    float4 qa = q4[c], ka = k4[c];
    acc[c >> 2] += qa.x*ka.x + qa.y*ka.y + qa.z*ka.z + qa.w*ka.w;
  }
#pragma unroll
  for (int h = 0; h < 8; h++)
    EB[(size_t)e*8 + h] = f2bh(exp2f(fminf(acc[h] * ESCALE, 43.0f)));
}

// ---------------- CSR-by-dst build ----------------
__global__ __launch_bounds__(256) void k_hist(const int* __restrict__ EI, int* __restrict__ deg) {
  int is64 = detect64(EI);
  int e = blockIdx.x * 256 + threadIdx.x;
  int d = is64 ? EI[2*(NE+e)] : EI[NE+e];
  d = min(max(d, 0), NN-1);
  atomicAdd(&deg[d], 1);
}
__global__ __launch_bounds__(256) void k_scan(const int* __restrict__ deg,
    int* __restrict__ offs, int* __restrict__ cursor) {
  __shared__ int sums[256];
  int t = threadIdx.x;
  int loc[16];
  int s = 0;
#pragma unroll
  for (int i = 0; i < 16; i++) { loc[i] = s; s += deg[t*16 + i]; }
  sums[t] = s;
  __syncthreads();
  for (int d = 1; d < 256; d <<= 1) {
    int v = (t >= d) ? sums[t - d] : 0;
    __syncthreads();
    sums[t] += v;
    __syncthreads();
  }
  int base = sums[t] - s;
#pragma unroll
  for (int i = 0; i < 16; i++) {
    offs[t*16 + i] = base + loc[i];
    cursor[t*16 + i] = base + loc[i];
  }
}
__global__ __launch_bounds__(256) void k_scatter(const int* __restrict__ EI,
    int* __restrict__ cursor, int* __restrict__ elist) {
  int is64 = detect64(EI);
  int e = blockIdx.x * 256 + threadIdx.x;
  int d = is64 ? EI[2*(NE+e)] : EI[NE+e];
  d = min(max(d, 0), NN-1);
  int slot = atomicAdd(&cursor[d], 1);
  elist[slot] = e;
}

// ---------------- per-dst aggregation (atomic-free; V and EB bf16) ----------------
__global__ __launch_bounds__(256) void k_edge_agg2(const int* __restrict__ EI,
    const int* __restrict__ deg, const int* __restrict__ offs,
    const int* __restrict__ elist, const unsigned short* __restrict__ Vl,
    const unsigned short* __restrict__ EB, float* __restrict__ AG) {
  int is64 = detect64(EI);
  int d = blockIdx.x * 4 + (threadIdx.x >> 6);
  int lane = threadIdx.x & 63;
  int degd = deg[d], start = offs[d];
  int hh = lane >> 3;
  float ss = 0.f;
  for (int i = lane & 7; i < degd; i += 8)
    ss += b2f16(EB[(size_t)elist[start + i] * 8 + hh]);
  for (int o = 1; o < 8; o <<= 1) ss += __shfl_xor(ss, o);
  float inv = 1.0f / fmaxf(ss, 1e-30f);
  float ax = 0.f, ay = 0.f;
  for (int i = 0; i < degd; i++) {
    int e = elist[start + i];
    int s = is64 ? EI[2*e] : EI[e];
    s = min(max(s, 0), NN-1);
    float a = b2f16(EB[(size_t)e*8 + hh]) * inv;
    unsigned v = *(const unsigned*)(Vl + (size_t)s * DM + 2 * lane);
    ax += a * b2f16((unsigned short)(v & 0xffffu));
    ay += a * b2f16((unsigned short)(v >> 16));
  }
  float2 r; r.x = ax; r.y = ay;
  *(float2*)(AG + (size_t)d * DM + 2 * lane) = r;
}

extern "C" void kernel_launch(void* const* d_in, const int* in_sizes, int n_in,
                              void* d_out, int out_size, void* d_ws, size_t ws_size,
                              hipStream_t stream) {
  const float* x     = (const float*)d_in[0];
  const int*   ei    = (const int*)  d_in[1];
  const float* wq_l  = (const float*)d_in[2];  const float* bq_l = (const float*)d_in[3];
  const float* wk_l  = (const float*)d_in[4];  const float* bk_l = (const float*)d_in[5];
  const float* wv_l  = (const float*)d_in[6];  const float* bv_l = (const float*)d_in[7];
  const float* wg    = (const float*)d_in[8];  const float* bg   = (const float*)d_in[9];
  const float* wq_g  = (const float*)d_in[10]; const float* bq_g = (const float*)d_in[11];
  const float* wk_g  = (const float*)d_in[12]; const float* bk_g = (const float*)d_in[13];
  const float* wv_g  = (const float*)d_in[14]; const float* bv_g = (const float*)d_in[15];
  const float* wo_g  = (const float*)d_in[16]; const float* bo_g = (const float*)d_in[17];
  const float* wf    = (const float*)d_in[18]; const float* bff  = (const float*)d_in[19];
  const float* gf    = (const float*)d_in[20]; const float* betaf= (const float*)d_in[21];
  const float* w1    = (const float*)d_in[22]; const float* b1   = (const float*)d_in[23];
  const float* w2    = (const float*)d_in[24]; const float* b2   = (const float*)d_in[25];
  const float* g1    = (const float*)d_in[26]; const float* be1  = (const float*)d_in[27];
  const float* g2    = (const float*)d_in[28]; const float* be2  = (const float*)d_in[29];
  float* out = (float*)d_out;

  const size_t NEED = (size_t)3289088 * 4;
  if (ws_size < NEED) {
    k_fill<<<2048, 256, 0, stream>>>(out, 100.0f, NN*DM);
    return;
  }

  // float-offset workspace slots (lifetime-reused; see per-launch hazard audit)
  float* W = (float*)d_ws;
  float*          lQ    = W + 0;        // localQ fp32 -> go -> t1[0:]
  float*          lK    = W + 524288;   // localK fp32 -> local -> t1
  unsigned short* lV    = (unsigned short*)(W + 1048576);  // localV bf16 -> t1
  float*          xn    = W + 1310720;  // xn -> eb(bf16) -> tmpf -> t1
  unsigned short* eb    = (unsigned short*)(W + 1310720);
  float*          tmpf  = W + 1310720;
  float*          agg   = W + 1835008;  // agg -> (t1/h2 overlap after death)
  float*          h2    = W + 2097152;
  unsigned short* qgb   = (unsigned short*)(W + 2359296);  // -> gop
  float*          gop   = W + 2359296;
  unsigned short* kgb   = (unsigned short*)(W + 2621440);  // -> h
  float*          h     = W + 2621440;
  unsigned short* vgT   = (unsigned short*)(W + 2883584);
  float*          go    = W + 0;
  float*          local_= W + 524288;
  float*          t1    = W + 0;        // 4096x512 fp32 spans 0..2097152
  int* deg    = (int*)(W + 3145728);
  int* cursor = (int*)(W + 3149824);
  int* offs   = (int*)(W + 3153920);
  int* elist  = (int*)(W + 3158016);

  dim3 b256(256);

  // CSR build first (depends only on ei)
  hipMemsetAsync(deg, 0, 4096 * sizeof(int), stream);
  k_hist<<<512, b256, 0, stream>>>(ei, deg);
  k_scan<<<1, b256, 0, stream>>>(deg, offs, cursor);
  k_scatter<<<512, b256, 0, stream>>>(ei, cursor, elist);

  // ln(x) then all six projections in one dispatch
  k_ln<<<1024, b256, 0, stream>>>(x, g1, be1, xn);
  gemm_six<<<dim3(64,12), b256, 0, stream>>>(x, xn,
      wq_l, wk_l, wv_l, wq_g, wk_g, wv_g,
      bq_l, bk_l, bv_l, bq_g, bk_g, bv_g,
      lQ, lK, lV, qgb, kgb, vgT);

  // edge scores (lQ,lK) -> eb; global attention (independent) -> go; then aggregation
  k_edge_attn<<<512, b256, 0, stream>>>(ei, lQ, lK, eb);
  k_gattn4<<<2048, b256, 0, stream>>>(qgb, kgb, vgT, go);
  k_edge_agg2<<<1024, b256, 0, stream>>>(ei, deg, offs, elist, lV, eb, agg);

  // gate + wo fused (independent GEMMs)
  gemm_dual<<<dim3(64,4), b256, 0, stream>>>(x, agg, go, wg, bg, wo_g, bo_g, local_, gop);

  // fusion + residual
  gemm_mfma<<<dim3(64,2), b256, 0, stream>>>(local_,128, gop,128,128, wf, bff,
      nullptr,nullptr,nullptr, tmpf, 128, 256, 0, 0, 1.f);
  k_ln2<<<1024, b256, 0, stream>>>(tmpf, gf, betaf, x, g2, be2, h, h2);

  // FFN
  gemm_mfma<<<dim3(64,8), b256, 0, stream>>>(h2,128, nullptr,0,128, w1, b1,
      nullptr,nullptr,nullptr, t1, 512, 128, 1, 0, 1.f);
  gemm_mfma<<<dim3(64,2), b256, 0, stream>>>(t1,512, nullptr,0,512, w2, b2,
      h, nullptr,nullptr, out, 128, 512, 0, 0, 1.f);
}

// Round 10
// 304.583 us; speedup vs baseline: 2.5847x; 1.0743x over previous
//
#include <hip/hip_runtime.h>
#include <math.h>

#define NN 4096
#define DM 128
#define NE 131072
#define QSCALE 0.36067376022224085f   // 0.25 * log2(e): exp(S/4) == exp2(S_prescaled)
#define ESCALE 0.36067376022224085f

typedef short short8 __attribute__((ext_vector_type(8)));
typedef float f32x4  __attribute__((ext_vector_type(4)));
typedef unsigned int uint4v __attribute__((ext_vector_type(4)));

static __device__ __forceinline__ unsigned pk2(float lo, float hi) {
  union { float f; unsigned u; } a, b; a.f = lo; b.f = hi;
  return ((b.u + 0x8000u) & 0xffff0000u) | ((a.u + 0x8000u) >> 16);
}
static __device__ __forceinline__ unsigned pkt(float lo, float hi) {
  union { float f; unsigned u; } a, b; a.f = lo; b.f = hi;
  return (b.u & 0xffff0000u) | (a.u >> 16);
}
static __device__ __forceinline__ unsigned short f2bh(float f) {
  union { float f; unsigned u; } v; v.f = f;
  return (unsigned short)((v.u + 0x8000u) >> 16);
}
static __device__ __forceinline__ float b2f16(unsigned short u) {
  union { unsigned u; float f; } v; v.u = ((unsigned)u) << 16; return v.f;
}
static __device__ __forceinline__ short8 cvt8(float4 a, float4 b) {
  unsigned u0 = pk2(a.x, a.y), u1 = pk2(a.z, a.w);
  unsigned u2 = pk2(b.x, b.y), u3 = pk2(b.z, b.w);
  short8 r;
  r[0]=(short)(u0 & 0xffffu); r[1]=(short)(u0 >> 16);
  r[2]=(short)(u1 & 0xffffu); r[3]=(short)(u1 >> 16);
  r[4]=(short)(u2 & 0xffffu); r[5]=(short)(u2 >> 16);
  r[6]=(short)(u3 & 0xffffu); r[7]=(short)(u3 >> 16);
  return r;
}
static __device__ __forceinline__ int detect64(const int* __restrict__ EI) {
  int v = EI[2 * (threadIdx.x & 63) + 1];
  for (int off = 1; off < 64; off <<= 1) v |= __shfl_xor(v, off);
  return (v == 0) ? 1 : 0;
}

__global__ __launch_bounds__(256) void k_fill(float* __restrict__ out, float v, int n) {
  int i = blockIdx.x * 256 + threadIdx.x;
  if (i < n) out[i] = v;
}

// ---------------- MFMA GEMM: C = epi(A @ W^T + Bias) * oscale ----------------
__global__ __launch_bounds__(256) void gemm_mfma(
    const float* __restrict__ A0, int lda0,
    const float* __restrict__ A1, int lda1, int ksplit,
    const float* __restrict__ Wt, const float* __restrict__ Bias,
    const float* __restrict__ Res, const float* __restrict__ E0, const float* __restrict__ E1,
    void* __restrict__ Cp, int Nt, int K, int act, int omode, float oscale)
{
  __shared__ short Asm[64][40];
  __shared__ short Wsm[64][40];
  const int m0 = blockIdx.x * 64, n0 = blockIdx.y * 64;
  const int tid = threadIdx.x;
  const int srow = tid >> 2, koff = (tid & 3) * 8;
  const int lane = tid & 63, wave = tid >> 6;
  const int quad = lane >> 4, m16 = lane & 15;
  f32x4 acc[4];
#pragma unroll
  for (int i = 0; i < 4; i++) acc[i] = {0.f, 0.f, 0.f, 0.f};

  for (int k0 = 0; k0 < K; k0 += 32) {
    const int kg = k0 + koff;
    const float* ap = (kg < ksplit) ? (A0 + (size_t)(m0 + srow) * lda0 + kg)
                                    : (A1 + (size_t)(m0 + srow) * lda1 + (kg - ksplit));
    float4 a0 = *(const float4*)ap, a1 = *(const float4*)(ap + 4);
    const float* wp = Wt + (size_t)(n0 + srow) * K + kg;
    float4 w0 = *(const float4*)wp, w1v = *(const float4*)(wp + 4);
    __syncthreads();
    *(short8*)&Asm[srow][koff] = cvt8(a0, a1);
    *(short8*)&Wsm[srow][koff] = cvt8(w0, w1v);
    __syncthreads();
    short8 af = *(short8*)&Asm[wave * 16 + m16][quad * 8];
#pragma unroll
    for (int nt = 0; nt < 4; nt++) {
      short8 bf = *(short8*)&Wsm[nt * 16 + m16][quad * 8];
      acc[nt] = __builtin_amdgcn_mfma_f32_16x16x32_bf16(af, bf, acc[nt], 0, 0, 0);
    }
  }
#pragma unroll
  for (int nt = 0; nt < 4; nt++) {
#pragma unroll
    for (int r = 0; r < 4; r++) {
      const int m = m0 + wave * 16 + quad * 4 + r;
      const int n = n0 + nt * 16 + m16;
      float v = acc[nt][r] + Bias[n];
      size_t oi = (size_t)m * Nt + n;
      if (act == 1) v = 0.5f * v * (1.0f + erff(v * 0.70710678118654752f));
      else if (act == 2) {
        float g = 1.0f / (1.0f + __expf(fminf(fmaxf(-v, -80.f), 80.f)));
        v = g * E0[oi] + (1.0f - g) * E1[oi];
      }
      if (Res) v += Res[oi];
      v *= oscale;
      if (omode == 0)      ((float*)Cp)[oi] = v;
      else if (omode == 1) ((unsigned short*)Cp)[oi] = f2bh(v);
      else                 ((unsigned short*)Cp)[(size_t)n * NN + m] = f2bh(v);
    }
  }
}

// ---------------- six-way QKV GEMM with inline LN for global branch ----------------
// grid (64,12); g = y>>1: 0..2 local Q,K,V from x; 3..5 global Q,K,V from ln(x) computed in-reg.
#define LN1(V, GV, BV) V = (V - mean) * rstd * GV + BV
__global__ __launch_bounds__(256) void gemm_six(
    const float* __restrict__ X,
    const float* __restrict__ G1, const float* __restrict__ Be1,
    const float* __restrict__ W0, const float* __restrict__ W1, const float* __restrict__ W2,
    const float* __restrict__ W3, const float* __restrict__ W4, const float* __restrict__ W5,
    const float* __restrict__ B0, const float* __restrict__ B1, const float* __restrict__ B2,
    const float* __restrict__ B3, const float* __restrict__ B4, const float* __restrict__ B5,
    void* __restrict__ O0, void* __restrict__ O1, void* __restrict__ O2,
    void* __restrict__ O3, void* __restrict__ O4, void* __restrict__ O5)
{
  __shared__ short Asm[64][40];
  __shared__ short Wsm[64][40];
  const int g = blockIdx.y >> 1;
  const float* Wt  = (g==0)?W0:(g==1)?W1:(g==2)?W2:(g==3)?W3:(g==4)?W4:W5;
  const float* Bia = (g==0)?B0:(g==1)?B1:(g==2)?B2:(g==3)?B3:(g==4)?B4:B5;
  void* Cp         = (g==0)?O0:(g==1)?O1:(g==2)?O2:(g==3)?O3:(g==4)?O4:O5;
  const int omode  = (g==2)?1:(g>=3)?((g==5)?2:1):0;   // lV bf16, qg/kg bf16, vgT feat-major
  const float osc  = (g==3)? QSCALE : 1.f;
  const int m0 = blockIdx.x * 64, n0 = (blockIdx.y & 1) * 64;
  const int tid = threadIdx.x;
  const int srow = tid >> 2, koff = (tid & 3) * 8;
  const int lane = tid & 63, wave = tid >> 6;
  const int quad = lane >> 4, m16 = lane & 15;

  // preload this thread's quarter-row slices of A (4 chunks x 8)
  const float* arow = X + (size_t)(m0 + srow) * 128 + koff;
  float4 a0[4], a1[4];
#pragma unroll
  for (int c = 0; c < 4; c++) {
    a0[c] = *(const float4*)(arow + c * 32);
    a1[c] = *(const float4*)(arow + c * 32 + 4);
  }
  if (g >= 3) {  // inline LayerNorm over the row (4 lanes share a row)
    float s = 0.f;
#pragma unroll
    for (int c = 0; c < 4; c++)
      s += a0[c].x + a0[c].y + a0[c].z + a0[c].w + a1[c].x + a1[c].y + a1[c].z + a1[c].w;
    s += __shfl_xor(s, 1); s += __shfl_xor(s, 2);
    float mean = s * (1.0f / 128.0f);
    float v = 0.f;
#pragma unroll
    for (int c = 0; c < 4; c++) {
      float d;
      d = a0[c].x - mean; v += d*d;  d = a0[c].y - mean; v += d*d;
      d = a0[c].z - mean; v += d*d;  d = a0[c].w - mean; v += d*d;
      d = a1[c].x - mean; v += d*d;  d = a1[c].y - mean; v += d*d;
      d = a1[c].z - mean; v += d*d;  d = a1[c].w - mean; v += d*d;
    }
    v += __shfl_xor(v, 1); v += __shfl_xor(v, 2);
    float rstd = rsqrtf(v * (1.0f / 128.0f) + 1e-5f);
#pragma unroll
    for (int c = 0; c < 4; c++) {
      const int col = c * 32 + koff;
      float4 gv0 = *(const float4*)(G1 + col),  gv1 = *(const float4*)(G1 + col + 4);
      float4 bv0 = *(const float4*)(Be1 + col), bv1 = *(const float4*)(Be1 + col + 4);
      LN1(a0[c].x, gv0.x, bv0.x); LN1(a0[c].y, gv0.y, bv0.y);
      LN1(a0[c].z, gv0.z, bv0.z); LN1(a0[c].w, gv0.w, bv0.w);
      LN1(a1[c].x, gv1.x, bv1.x); LN1(a1[c].y, gv1.y, bv1.y);
      LN1(a1[c].z, gv1.z, bv1.z); LN1(a1[c].w, gv1.w, bv1.w);
    }
  }

  f32x4 acc[4];
#pragma unroll
  for (int i = 0; i < 4; i++) acc[i] = {0.f, 0.f, 0.f, 0.f};
#pragma unroll
  for (int c = 0; c < 4; c++) {
    const float* wp = Wt + (size_t)(n0 + srow) * 128 + c * 32 + koff;
    float4 w0 = *(const float4*)wp, w1v = *(const float4*)(wp + 4);
    __syncthreads();
    *(short8*)&Asm[srow][koff] = cvt8(a0[c], a1[c]);
    *(short8*)&Wsm[srow][koff] = cvt8(w0, w1v);
    __syncthreads();
    short8 af = *(short8*)&Asm[wave * 16 + m16][quad * 8];
#pragma unroll
    for (int nt = 0; nt < 4; nt++) {
      short8 bf = *(short8*)&Wsm[nt * 16 + m16][quad * 8];
      acc[nt] = __builtin_amdgcn_mfma_f32_16x16x32_bf16(af, bf, acc[nt], 0, 0, 0);
    }
  }
#pragma unroll
  for (int nt = 0; nt < 4; nt++) {
#pragma unroll
    for (int r = 0; r < 4; r++) {
      const int m = m0 + wave * 16 + quad * 4 + r;
      const int n = n0 + nt * 16 + m16;
      float v = (acc[nt][r] + Bia[n]) * osc;
      size_t oi = (size_t)m * 128 + n;
      if (omode == 0)      ((float*)Cp)[oi] = v;
      else if (omode == 1) ((unsigned short*)Cp)[oi] = f2bh(v);
      else                 ((unsigned short*)Cp)[(size_t)n * NN + m] = f2bh(v);
    }
  }
}

// ---------------- dual GEMM: y<2 = gate (K=256, act2), y>=2 = wo (K=128) ----------------
__global__ __launch_bounds__(256) void gemm_dual(
    const float* __restrict__ X, const float* __restrict__ AGG,
    const float* __restrict__ GO,
    const float* __restrict__ Wg, const float* __restrict__ Bg,
    const float* __restrict__ Wo, const float* __restrict__ Bo,
    float* __restrict__ LOCAL, float* __restrict__ GOP)
{
  __shared__ short Asm[64][40];
  __shared__ short Wsm[64][40];
  const int isGate = (blockIdx.y < 2);
  const float* A0  = isGate ? X   : GO;
  const float* A1  = isGate ? AGG : GO;
  const int ksplit = 128;
  const int K      = isGate ? 256 : 128;
  const float* Wt  = isGate ? Wg : Wo;
  const float* Bia = isGate ? Bg : Bo;
  float* Cp        = isGate ? LOCAL : GOP;
  const int m0 = blockIdx.x * 64, n0 = (blockIdx.y & 1) * 64;
  const int tid = threadIdx.x;
  const int srow = tid >> 2, koff = (tid & 3) * 8;
  const int lane = tid & 63, wave = tid >> 6;
  const int quad = lane >> 4, m16 = lane & 15;
  f32x4 acc[4];
#pragma unroll
  for (int i = 0; i < 4; i++) acc[i] = {0.f, 0.f, 0.f, 0.f};

  for (int k0 = 0; k0 < K; k0 += 32) {
    const int kg = k0 + koff;
    const float* ap = (kg < ksplit) ? (A0 + (size_t)(m0 + srow) * 128 + kg)
                                    : (A1 + (size_t)(m0 + srow) * 128 + (kg - ksplit));
    float4 a0 = *(const float4*)ap, a1 = *(const float4*)(ap + 4);
    const float* wp = Wt + (size_t)(n0 + srow) * K + kg;
    float4 w0 = *(const float4*)wp, w1v = *(const float4*)(wp + 4);
    __syncthreads();
    *(short8*)&Asm[srow][koff] = cvt8(a0, a1);
    *(short8*)&Wsm[srow][koff] = cvt8(w0, w1v);
    __syncthreads();
    short8 af = *(short8*)&Asm[wave * 16 + m16][quad * 8];
#pragma unroll
    for (int nt = 0; nt < 4; nt++) {
      short8 bf = *(short8*)&Wsm[nt * 16 + m16][quad * 8];
      acc[nt] = __builtin_amdgcn_mfma_f32_16x16x32_bf16(af, bf, acc[nt], 0, 0, 0);
    }
  }
#pragma unroll
  for (int nt = 0; nt < 4; nt++) {
#pragma unroll
    for (int r = 0; r < 4; r++) {
      const int m = m0 + wave * 16 + quad * 4 + r;
      const int n = n0 + nt * 16 + m16;
      float v = acc[nt][r] + Bia[n];
      size_t oi = (size_t)m * 128 + n;
      if (isGate) {
        float g = 1.0f / (1.0f + __expf(fminf(fmaxf(-v, -80.f), 80.f)));
        v = g * AGG[oi] + (1.0f - g) * X[oi];
      }
      Cp[oi] = v;
    }
  }
}

// ---------------- global attention: 64 q-rows/block, 4x K/V-load reuse ----------------
// grid 512 = head(8) x 64-row q-tile(64); 4 waves = 4 key quarters; LDS combine at end.
// Same validated S^T/P^T register dataflow as R8; each K-load set feeds 4 q-fragments.
__global__ __launch_bounds__(256) void k_gattn5(
    const unsigned short* __restrict__ Qb, const unsigned short* __restrict__ Kb,
    const unsigned short* __restrict__ VT, float* __restrict__ O)
{
  __shared__ float LO[4][4][16][16];
  __shared__ float LL[4][4][16];
  const int h = blockIdx.x >> 6, qt = blockIdx.x & 63;
  const int tid = threadIdx.x, lane = tid & 63, wave = tid >> 6;
  const int quad = lane >> 4, m16 = lane & 15;
  const int r0 = qt * 64;
  const short8 z8 = {0,0,0,0,0,0,0,0};
  const f32x4  z4 = {0.f,0.f,0.f,0.f};
  short8 qf[4] = {z8, z8, z8, z8};
  if (quad < 2) {
#pragma unroll
    for (int j = 0; j < 4; j++)
      qf[j] = *(const short8*)(Qb + (size_t)(r0 + j * 16 + m16) * DM + h * 16 + quad * 8);
  }
  short8 ones;
#pragma unroll
  for (int i = 0; i < 8; i++) ones[i] = (short)0x3F80;
  const int kperm = (m16 >> 2) * 8 + (m16 & 3);
  const int kbase = wave * 1024;
  f32x4 acc[4] = {z4, z4, z4, z4};
  f32x4 acc2[4] = {z4, z4, z4, z4};
  short8 a0 = z8, a1 = z8, a2 = z8, a3 = z8;
  for (int kt = 0; kt < 16; kt++) {
    const int key0 = kbase + kt * 64;
    if (quad < 2) {
      const unsigned short* kp = Kb + (size_t)(key0 + kperm) * DM + h * 16 + quad * 8;
      a0 = *(const short8*)kp;
      a1 = *(const short8*)(kp + 4 * DM);
      a2 = *(const short8*)(kp + 32 * DM);
      a3 = *(const short8*)(kp + 36 * DM);
    }
    const unsigned short* vp = VT + (size_t)(h * 16 + m16) * NN + key0 + quad * 8;
    short8 av0 = *(const short8*)vp;
    short8 av1 = *(const short8*)(vp + 32);
#pragma unroll
    for (int j = 0; j < 4; j++) {
      f32x4 s0 = __builtin_amdgcn_mfma_f32_16x16x32_bf16(a0, qf[j], z4, 0, 0, 0);
      f32x4 s1 = __builtin_amdgcn_mfma_f32_16x16x32_bf16(a1, qf[j], z4, 0, 0, 0);
      f32x4 s2 = __builtin_amdgcn_mfma_f32_16x16x32_bf16(a2, qf[j], z4, 0, 0, 0);
      f32x4 s3 = __builtin_amdgcn_mfma_f32_16x16x32_bf16(a3, qf[j], z4, 0, 0, 0);
      float e0 = exp2f(fminf(s0[0], 30.f)), e1 = exp2f(fminf(s0[1], 30.f));
      float e2 = exp2f(fminf(s0[2], 30.f)), e3 = exp2f(fminf(s0[3], 30.f));
      float e4 = exp2f(fminf(s1[0], 30.f)), e5 = exp2f(fminf(s1[1], 30.f));
      float e6 = exp2f(fminf(s1[2], 30.f)), e7 = exp2f(fminf(s1[3], 30.f));
      uint4v u;
      u.x = pkt(e0, e1); u.y = pkt(e2, e3); u.z = pkt(e4, e5); u.w = pkt(e6, e7);
      short8 p0 = __builtin_bit_cast(short8, u);
      float f0 = exp2f(fminf(s2[0], 30.f)), f1 = exp2f(fminf(s2[1], 30.f));
      float f2 = exp2f(fminf(s2[2], 30.f)), f3 = exp2f(fminf(s2[3], 30.f));
      float f4 = exp2f(fminf(s3[0], 30.f)), f5 = exp2f(fminf(s3[1], 30.f));
      float f6 = exp2f(fminf(s3[2], 30.f)), f7 = exp2f(fminf(s3[3], 30.f));
      uint4v w;
      w.x = pkt(f0, f1); w.y = pkt(f2, f3); w.z = pkt(f4, f5); w.w = pkt(f6, f7);
      short8 p1 = __builtin_bit_cast(short8, w);
      acc[j]  = __builtin_amdgcn_mfma_f32_16x16x32_bf16(av0, p0, acc[j], 0, 0, 0);
      acc[j]  = __builtin_amdgcn_mfma_f32_16x16x32_bf16(av1, p1, acc[j], 0, 0, 0);
      acc2[j] = __builtin_amdgcn_mfma_f32_16x16x32_bf16(ones, p0, acc2[j], 0, 0, 0);
      acc2[j] = __builtin_amdgcn_mfma_f32_16x16x32_bf16(ones, p1, acc2[j], 0, 0, 0);
    }
  }
#pragma unroll
  for (int j = 0; j < 4; j++) {
    float4 a4; a4.x = acc[j][0]; a4.y = acc[j][1]; a4.z = acc[j][2]; a4.w = acc[j][3];
    *(float4*)&LO[wave][j][m16][quad * 4] = a4;
    if (lane < 16) LL[wave][j][lane] = acc2[j][0];   // colsum: all C rows identical
  }
  __syncthreads();
  {
    const int j = wave;   // each wave combines its own q-subtile
    float4 o = *(float4*)&LO[0][j][m16][quad * 4];
    float lt = LL[0][j][m16];
#pragma unroll
    for (int w2 = 1; w2 < 4; w2++) {
      float4 t = *(float4*)&LO[w2][j][m16][quad * 4];
      o.x += t.x; o.y += t.y; o.z += t.z; o.w += t.w;
      lt += LL[w2][j][m16];
    }
    float inv = 1.0f / fmaxf(lt, 1e-30f);
    float4 r4; r4.x = o.x * inv; r4.y = o.y * inv; r4.z = o.z * inv; r4.w = o.w * inv;
    *(float4*)(O + (size_t)(r0 + j * 16 + m16) * DM + h * 16 + quad * 4) = r4;
  }
}

// ---------------- fused: H = X + relu(ln1(T)); H2 = ln2(H) ----------------
__global__ __launch_bounds__(256) void k_ln2(const float* __restrict__ T,
    const float* __restrict__ G1, const float* __restrict__ Be1,
    const float* __restrict__ X,
    const float* __restrict__ G2, const float* __restrict__ Be2,
    float* __restrict__ H, float* __restrict__ H2) {
  int row = blockIdx.x * 4 + (threadIdx.x >> 6);
  int lane = threadIdx.x & 63;
  float v0 = T[(size_t)row*DM + lane];
  float v1 = T[(size_t)row*DM + 64 + lane];
  float s = v0 + v1;
  for (int off = 1; off < 64; off <<= 1) s += __shfl_xor(s, off);
  float mean = s * (1.0f/128.0f);
  float d0 = v0 - mean, d1 = v1 - mean;
  float s2 = d0*d0 + d1*d1;
  for (int off = 1; off < 64; off <<= 1) s2 += __shfl_xor(s2, off);
  float rstd = rsqrtf(s2 * (1.0f/128.0f) + 1e-5f);
  float f0 = d0*rstd*G1[lane]    + Be1[lane];
  float f1 = d1*rstd*G1[64+lane] + Be1[64+lane];
  f0 = f0 > 0.f ? f0 : 0.f;
  f1 = f1 > 0.f ? f1 : 0.f;
  float h0 = X[(size_t)row*DM + lane]      + f0;
  float h1 = X[(size_t)row*DM + 64 + lane] + f1;
  H[(size_t)row*DM + lane]      = h0;
  H[(size_t)row*DM + 64 + lane] = h1;
  float t = h0 + h1;
  for (int off = 1; off < 64; off <<= 1) t += __shfl_xor(t, off);
  float mean2 = t * (1.0f/128.0f);
  float e0 = h0 - mean2, e1 = h1 - mean2;
  float t2 = e0*e0 + e1*e1;
  for (int off = 1; off < 64; off <<= 1) t2 += __shfl_xor(t2, off);
  float rstd2 = rsqrtf(t2 * (1.0f/128.0f) + 1e-5f);
  H2[(size_t)row*DM + lane]      = e0*rstd2*G2[lane]    + Be2[lane];
  H2[(size_t)row*DM + 64 + lane] = e1*rstd2*G2[64+lane] + Be2[64+lane];
}

// ---------------- edge attention + degree histogram fused ----------------
__global__ __launch_bounds__(256) void k_edge_attn(const int* __restrict__ EI,
    const float* __restrict__ Q, const float* __restrict__ Kl,
    unsigned short* __restrict__ EB, int* __restrict__ deg) {
  int is64 = detect64(EI);
  int e = blockIdx.x * 256 + threadIdx.x;
  int s = is64 ? EI[2*e]      : EI[e];
  int d = is64 ? EI[2*(NE+e)] : EI[NE+e];
  s = min(max(s, 0), NN-1); d = min(max(d, 0), NN-1);
  const float4* q4 = (const float4*)(Q  + (size_t)d * DM);
  const float4* k4 = (const float4*)(Kl + (size_t)s * DM);
  float acc[8] = {};
#pragma unroll
  for (int c = 0; c < 32; c++) {
    float4 qa = q4[c], ka = k4[c];
    acc[c >> 2] += qa.x*ka.x + qa.y*ka.y + qa.z*ka.z + qa.w*ka.w;
  }
#pragma unroll
  for (int h = 0; h < 8; h++)
    EB[(size_t)e*8 + h] = f2bh(exp2f(fminf(acc[h] * ESCALE, 43.0f)));
  atomicAdd(&deg[d], 1);
}

// ---------------- CSR scan + scatter ----------------
__global__ __launch_bounds__(256) void k_scan(const int* __restrict__ deg,
    int* __restrict__ offs, int* __restrict__ cursor) {
  __shared__ int sums[256];
  int t = threadIdx.x;
  int loc[16];
  int s = 0;
#pragma unroll
  for (int i = 0; i < 16; i++) { loc[i] = s; s += deg[t*16 + i]; }
  sums[t] = s;
  __syncthreads();
  for (int d = 1; d < 256; d <<= 1) {
    int v = (t >= d) ? sums[t - d] : 0;
    __syncthreads();
    sums[t] += v;
    __syncthreads();
  }
  int base = sums[t] - s;
#pragma unroll
  for (int i = 0; i < 16; i++) {
    offs[t*16 + i] = base + loc[i];
    cursor[t*16 + i] = base + loc[i];
  }
}
__global__ __launch_bounds__(256) void k_scatter(const int* __restrict__ EI,
    int* __restrict__ cursor, int* __restrict__ elist) {
  int is64 = detect64(EI);
  int e = blockIdx.x * 256 + threadIdx.x;
  int d = is64 ? EI[2*(NE+e)] : EI[NE+e];
  d = min(max(d, 0), NN-1);
  int slot = atomicAdd(&cursor[d], 1);
  elist[slot] = e;
}

// ---------------- per-dst aggregation (atomic-free; V and EB bf16) ----------------
__global__ __launch_bounds__(256) void k_edge_agg2(const int* __restrict__ EI,
    const int* __restrict__ deg, const int* __restrict__ offs,
    const int* __restrict__ elist, const unsigned short* __restrict__ Vl,
    const unsigned short* __restrict__ EB, float* __restrict__ AG) {
  int is64 = detect64(EI);
  int d = blockIdx.x * 4 + (threadIdx.x >> 6);
  int lane = threadIdx.x & 63;
  int degd = deg[d], start = offs[d];
  int hh = lane >> 3;
  float ss = 0.f;
  for (int i = lane & 7; i < degd; i += 8)
    ss += b2f16(EB[(size_t)elist[start + i] * 8 + hh]);
  for (int o = 1; o < 8; o <<= 1) ss += __shfl_xor(ss, o);
  float inv = 1.0f / fmaxf(ss, 1e-30f);
  float ax = 0.f, ay = 0.f;
  for (int i = 0; i < degd; i++) {
    int e = elist[start + i];
    int s = is64 ? EI[2*e] : EI[e];
    s = min(max(s, 0), NN-1);
    float a = b2f16(EB[(size_t)e*8 + hh]) * inv;
    unsigned v = *(const unsigned*)(Vl + (size_t)s * DM + 2 * lane);
    ax += a * b2f16((unsigned short)(v & 0xffffu));
    ay += a * b2f16((unsigned short)(v >> 16));
  }
  float2 r; r.x = ax; r.y = ay;
  *(float2*)(AG + (size_t)d * DM + 2 * lane) = r;
}

extern "C" void kernel_launch(void* const* d_in, const int* in_sizes, int n_in,
                              void* d_out, int out_size, void* d_ws, size_t ws_size,
                              hipStream_t stream) {
  const float* x     = (const float*)d_in[0];
  const int*   ei    = (const int*)  d_in[1];
  const float* wq_l  = (const float*)d_in[2];  const float* bq_l = (const float*)d_in[3];
  const float* wk_l  = (const float*)d_in[4];  const float* bk_l = (const float*)d_in[5];
  const float* wv_l  = (const float*)d_in[6];  const float* bv_l = (const float*)d_in[7];
  const float* wg    = (const float*)d_in[8];  const float* bg   = (const float*)d_in[9];
  const float* wq_g  = (const float*)d_in[10]; const float* bq_g = (const float*)d_in[11];
  const float* wk_g  = (const float*)d_in[12]; const float* bk_g = (const float*)d_in[13];
  const float* wv_g  = (const float*)d_in[14]; const float* bv_g = (const float*)d_in[15];
  const float* wo_g  = (const float*)d_in[16]; const float* bo_g = (const float*)d_in[17];
  const float* wf    = (const float*)d_in[18]; const float* bff  = (const float*)d_in[19];
  const float* gf    = (const float*)d_in[20]; const float* betaf= (const float*)d_in[21];
  const float* w1    = (const float*)d_in[22]; const float* b1   = (const float*)d_in[23];
  const float* w2    = (const float*)d_in[24]; const float* b2   = (const float*)d_in[25];
  const float* g1    = (const float*)d_in[26]; const float* be1  = (const float*)d_in[27];
  const float* g2    = (const float*)d_in[28]; const float* be2  = (const float*)d_in[29];
  float* out = (float*)d_out;

  const size_t NEED = (size_t)3289088 * 4;
  if (ws_size < NEED) {
    k_fill<<<2048, 256, 0, stream>>>(out, 100.0f, NN*DM);
    return;
  }

  // float-offset workspace slots (lifetime-reused; hazard-audited serially)
  float* W = (float*)d_ws;
  float*          lQ    = W + 0;        // localQ fp32 -> go -> t1[0:]
  float*          lK    = W + 524288;   // localK fp32 -> local -> t1
  unsigned short* lV    = (unsigned short*)(W + 1048576);  // localV bf16 -> t1
  unsigned short* eb    = (unsigned short*)(W + 1310720);  // eb bf16 -> tmpf -> t1
  float*          tmpf  = W + 1310720;
  float*          agg   = W + 1835008;  // agg -> t1 tail
  float*          h2    = W + 2097152;
  unsigned short* qgb   = (unsigned short*)(W + 2359296);  // -> gop
  float*          gop   = W + 2359296;
  unsigned short* kgb   = (unsigned short*)(W + 2621440);  // -> h
  float*          h     = W + 2621440;
  unsigned short* vgT   = (unsigned short*)(W + 2883584);
  float*          go    = W + 0;
  float*          local_= W + 524288;
  float*          t1    = W + 0;        // 4096x512 fp32 spans 0..2097152
  int* deg    = (int*)(W + 3145728);
  int* cursor = (int*)(W + 3149824);
  int* offs   = (int*)(W + 3153920);
  int* elist  = (int*)(W + 3158016);

  dim3 b256(256);

  hipMemsetAsync(deg, 0, 4096 * sizeof(int), stream);

  // all six projections (LN for global branch computed inline)
  gemm_six<<<dim3(64,12), b256, 0, stream>>>(x, g1, be1,
      wq_l, wk_l, wv_l, wq_g, wk_g, wv_g,
      bq_l, bk_l, bv_l, bq_g, bk_g, bv_g,
      lQ, lK, lV, qgb, kgb, vgT);

  // edge scores + degree histogram; CSR; aggregation
  k_edge_attn<<<512, b256, 0, stream>>>(ei, lQ, lK, eb, deg);
  k_scan<<<1, b256, 0, stream>>>(deg, offs, cursor);
  k_scatter<<<512, b256, 0, stream>>>(ei, cursor, elist);
  k_edge_agg2<<<1024, b256, 0, stream>>>(ei, deg, offs, elist, lV, eb, agg);

  // global attention (64 q-rows/block, 4x K/V reuse)
  k_gattn5<<<512, b256, 0, stream>>>(qgb, kgb, vgT, go);

  // gate + wo fused
  gemm_dual<<<dim3(64,4), b256, 0, stream>>>(x, agg, go, wg, bg, wo_g, bo_g, local_, gop);

  // fusion + residual
  gemm_mfma<<<dim3(64,2), b256, 0, stream>>>(local_,128, gop,128,128, wf, bff,
      nullptr,nullptr,nullptr, tmpf, 128, 256, 0, 0, 1.f);
  k_ln2<<<1024, b256, 0, stream>>>(tmpf, gf, betaf, x, g2, be2, h, h2);

  // FFN
  gemm_mfma<<<dim3(64,8), b256, 0, stream>>>(h2,128, nullptr,0,128, w1, b1,
      nullptr,nullptr,nullptr, t1, 512, 128, 1, 0, 1.f);
  gemm_mfma<<<dim3(64,2), b256, 0, stream>>>(t1,512, nullptr,0,512, w2, b2,
      h, nullptr,nullptr, out, 128, 512, 0, 0, 1.f);
}

// Round 11
// 257.163 us; speedup vs baseline: 3.0613x; 1.1844x over previous
//
#include <hip/hip_runtime.h>
#include <math.h>

#define NN 4096
#define DM 128
#define NE 131072
#define QSCALE 0.36067376022224085f   // 0.25 * log2(e): exp(S/4) == exp2(S_prescaled)
#define ESCALE 0.36067376022224085f

typedef short short8 __attribute__((ext_vector_type(8)));
typedef float f32x4  __attribute__((ext_vector_type(4)));
typedef unsigned int uint4v __attribute__((ext_vector_type(4)));

static __device__ __forceinline__ unsigned pk2(float lo, float hi) {
  union { float f; unsigned u; } a, b; a.f = lo; b.f = hi;
  return ((b.u + 0x8000u) & 0xffff0000u) | ((a.u + 0x8000u) >> 16);
}
static __device__ __forceinline__ unsigned pkt(float lo, float hi) {
  union { float f; unsigned u; } a, b; a.f = lo; b.f = hi;
  return (b.u & 0xffff0000u) | (a.u >> 16);
}
static __device__ __forceinline__ unsigned short f2bh(float f) {
  union { float f; unsigned u; } v; v.f = f;
  return (unsigned short)((v.u + 0x8000u) >> 16);
}
static __device__ __forceinline__ float b2f16(unsigned short u) {
  union { unsigned u; float f; } v; v.u = ((unsigned)u) << 16; return v.f;
}
static __device__ __forceinline__ short8 cvt8(float4 a, float4 b) {
  unsigned u0 = pk2(a.x, a.y), u1 = pk2(a.z, a.w);
  unsigned u2 = pk2(b.x, b.y), u3 = pk2(b.z, b.w);
  short8 r;
  r[0]=(short)(u0 & 0xffffu); r[1]=(short)(u0 >> 16);
  r[2]=(short)(u1 & 0xffffu); r[3]=(short)(u1 >> 16);
  r[4]=(short)(u2 & 0xffffu); r[5]=(short)(u2 >> 16);
  r[6]=(short)(u3 & 0xffffu); r[7]=(short)(u3 >> 16);
  return r;
}
static __device__ __forceinline__ int detect64(const int* __restrict__ EI) {
  int v = EI[2 * (threadIdx.x & 63) + 1];
  for (int off = 1; off < 64; off <<= 1) v |= __shfl_xor(v, off);
  return (v == 0) ? 1 : 0;
}

__global__ __launch_bounds__(256) void k_fill(float* __restrict__ out, float v, int n) {
  int i = blockIdx.x * 256 + threadIdx.x;
  if (i < n) out[i] = v;
}

// ---------------- MFMA GEMM: C = epi(A @ W^T + Bias) * oscale ----------------
__global__ __launch_bounds__(256) void gemm_mfma(
    const float* __restrict__ A0, int lda0,
    const float* __restrict__ A1, int lda1, int ksplit,
    const float* __restrict__ Wt, const float* __restrict__ Bias,
    const float* __restrict__ Res, const float* __restrict__ E0, const float* __restrict__ E1,
    void* __restrict__ Cp, int Nt, int K, int act, int omode, float oscale)
{
  __shared__ short Asm[64][40];
  __shared__ short Wsm[64][40];
  const int m0 = blockIdx.x * 64, n0 = blockIdx.y * 64;
  const int tid = threadIdx.x;
  const int srow = tid >> 2, koff = (tid & 3) * 8;
  const int lane = tid & 63, wave = tid >> 6;
  const int quad = lane >> 4, m16 = lane & 15;
  f32x4 acc[4];
#pragma unroll
  for (int i = 0; i < 4; i++) acc[i] = {0.f, 0.f, 0.f, 0.f};

  for (int k0 = 0; k0 < K; k0 += 32) {
    const int kg = k0 + koff;
    const float* ap = (kg < ksplit) ? (A0 + (size_t)(m0 + srow) * lda0 + kg)
                                    : (A1 + (size_t)(m0 + srow) * lda1 + (kg - ksplit));
    float4 a0 = *(const float4*)ap, a1 = *(const float4*)(ap + 4);
    const float* wp = Wt + (size_t)(n0 + srow) * K + kg;
    float4 w0 = *(const float4*)wp, w1v = *(const float4*)(wp + 4);
    __syncthreads();
    *(short8*)&Asm[srow][koff] = cvt8(a0, a1);
    *(short8*)&Wsm[srow][koff] = cvt8(w0, w1v);
    __syncthreads();
    short8 af = *(short8*)&Asm[wave * 16 + m16][quad * 8];
#pragma unroll
    for (int nt = 0; nt < 4; nt++) {
      short8 bf = *(short8*)&Wsm[nt * 16 + m16][quad * 8];
      acc[nt] = __builtin_amdgcn_mfma_f32_16x16x32_bf16(af, bf, acc[nt], 0, 0, 0);
    }
  }
#pragma unroll
  for (int nt = 0; nt < 4; nt++) {
#pragma unroll
    for (int r = 0; r < 4; r++) {
      const int m = m0 + wave * 16 + quad * 4 + r;
      const int n = n0 + nt * 16 + m16;
      float v = acc[nt][r] + Bias[n];
      size_t oi = (size_t)m * Nt + n;
      if (act == 1) v = 0.5f * v * (1.0f + erff(v * 0.70710678118654752f));
      else if (act == 2) {
        float g = 1.0f / (1.0f + __expf(fminf(fmaxf(-v, -80.f), 80.f)));
        v = g * E0[oi] + (1.0f - g) * E1[oi];
      }
      if (Res) v += Res[oi];
      v *= oscale;
      if (omode == 0)      ((float*)Cp)[oi] = v;
      else if (omode == 1) ((unsigned short*)Cp)[oi] = f2bh(v);
      else                 ((unsigned short*)Cp)[(size_t)n * NN + m] = f2bh(v);
    }
  }
}

// ---------------- six-way QKV GEMM with inline LN for global branch ----------------
#define LN1(V, GV, BV) V = (V - mean) * rstd * GV + BV
__global__ __launch_bounds__(256) void gemm_six(
    const float* __restrict__ X,
    const float* __restrict__ G1, const float* __restrict__ Be1,
    const float* __restrict__ W0, const float* __restrict__ W1, const float* __restrict__ W2,
    const float* __restrict__ W3, const float* __restrict__ W4, const float* __restrict__ W5,
    const float* __restrict__ B0, const float* __restrict__ B1, const float* __restrict__ B2,
    const float* __restrict__ B3, const float* __restrict__ B4, const float* __restrict__ B5,
    void* __restrict__ O0, void* __restrict__ O1, void* __restrict__ O2,
    void* __restrict__ O3, void* __restrict__ O4, void* __restrict__ O5)
{
  __shared__ short Asm[64][40];
  __shared__ short Wsm[64][40];
  const int g = blockIdx.y >> 1;
  const float* Wt  = (g==0)?W0:(g==1)?W1:(g==2)?W2:(g==3)?W3:(g==4)?W4:W5;
  const float* Bia = (g==0)?B0:(g==1)?B1:(g==2)?B2:(g==3)?B3:(g==4)?B4:B5;
  void* Cp         = (g==0)?O0:(g==1)?O1:(g==2)?O2:(g==3)?O3:(g==4)?O4:O5;
  const int omode  = (g==2)?1:(g>=3)?((g==5)?2:1):0;
  const float osc  = (g==3)? QSCALE : (g==0)? ESCALE : 1.f;   // Q_l pre-scaled for edge softmax
  const int m0 = blockIdx.x * 64, n0 = (blockIdx.y & 1) * 64;
  const int tid = threadIdx.x;
  const int srow = tid >> 2, koff = (tid & 3) * 8;
  const int lane = tid & 63, wave = tid >> 6;
  const int quad = lane >> 4, m16 = lane & 15;

  const float* arow = X + (size_t)(m0 + srow) * 128 + koff;
  float4 a0[4], a1[4];
#pragma unroll
  for (int c = 0; c < 4; c++) {
    a0[c] = *(const float4*)(arow + c * 32);
    a1[c] = *(const float4*)(arow + c * 32 + 4);
  }
  if (g >= 3) {
    float s = 0.f;
#pragma unroll
    for (int c = 0; c < 4; c++)
      s += a0[c].x + a0[c].y + a0[c].z + a0[c].w + a1[c].x + a1[c].y + a1[c].z + a1[c].w;
    s += __shfl_xor(s, 1); s += __shfl_xor(s, 2);
    float mean = s * (1.0f / 128.0f);
    float v = 0.f;
#pragma unroll
    for (int c = 0; c < 4; c++) {
      float d;
      d = a0[c].x - mean; v += d*d;  d = a0[c].y - mean; v += d*d;
      d = a0[c].z - mean; v += d*d;  d = a0[c].w - mean; v += d*d;
      d = a1[c].x - mean; v += d*d;  d = a1[c].y - mean; v += d*d;
      d = a1[c].z - mean; v += d*d;  d = a1[c].w - mean; v += d*d;
    }
    v += __shfl_xor(v, 1); v += __shfl_xor(v, 2);
    float rstd = rsqrtf(v * (1.0f / 128.0f) + 1e-5f);
#pragma unroll
    for (int c = 0; c < 4; c++) {
      const int col = c * 32 + koff;
      float4 gv0 = *(const float4*)(G1 + col),  gv1 = *(const float4*)(G1 + col + 4);
      float4 bv0 = *(const float4*)(Be1 + col), bv1 = *(const float4*)(Be1 + col + 4);
      LN1(a0[c].x, gv0.x, bv0.x); LN1(a0[c].y, gv0.y, bv0.y);
      LN1(a0[c].z, gv0.z, bv0.z); LN1(a0[c].w, gv0.w, bv0.w);
      LN1(a1[c].x, gv1.x, bv1.x); LN1(a1[c].y, gv1.y, bv1.y);
      LN1(a1[c].z, gv1.z, bv1.z); LN1(a1[c].w, gv1.w, bv1.w);
    }
  }

  f32x4 acc[4];
#pragma unroll
  for (int i = 0; i < 4; i++) acc[i] = {0.f, 0.f, 0.f, 0.f};
#pragma unroll
  for (int c = 0; c < 4; c++) {
    const float* wp = Wt + (size_t)(n0 + srow) * 128 + c * 32 + koff;
    float4 w0 = *(const float4*)wp, w1v = *(const float4*)(wp + 4);
    __syncthreads();
    *(short8*)&Asm[srow][koff] = cvt8(a0[c], a1[c]);
    *(short8*)&Wsm[srow][koff] = cvt8(w0, w1v);
    __syncthreads();
    short8 af = *(short8*)&Asm[wave * 16 + m16][quad * 8];
#pragma unroll
    for (int nt = 0; nt < 4; nt++) {
      short8 bf = *(short8*)&Wsm[nt * 16 + m16][quad * 8];
      acc[nt] = __builtin_amdgcn_mfma_f32_16x16x32_bf16(af, bf, acc[nt], 0, 0, 0);
    }
  }
#pragma unroll
  for (int nt = 0; nt < 4; nt++) {
#pragma unroll
    for (int r = 0; r < 4; r++) {
      const int m = m0 + wave * 16 + quad * 4 + r;
      const int n = n0 + nt * 16 + m16;
      float v = (acc[nt][r] + Bia[n]) * osc;
      size_t oi = (size_t)m * 128 + n;
      if (omode == 0)      ((float*)Cp)[oi] = v;
      else if (omode == 1) ((unsigned short*)Cp)[oi] = f2bh(v);
      else                 ((unsigned short*)Cp)[(size_t)n * NN + m] = f2bh(v);
    }
  }
}

// ---------------- dual GEMM: y<2 = gate (K=256, act2), y>=2 = wo (K=128) ----------------
__global__ __launch_bounds__(256) void gemm_dual(
    const float* __restrict__ X, const float* __restrict__ AGG,
    const float* __restrict__ GO,
    const float* __restrict__ Wg, const float* __restrict__ Bg,
    const float* __restrict__ Wo, const float* __restrict__ Bo,
    float* __restrict__ LOCAL, float* __restrict__ GOP)
{
  __shared__ short Asm[64][40];
  __shared__ short Wsm[64][40];
  const int isGate = (blockIdx.y < 2);
  const float* A0  = isGate ? X   : GO;
  const float* A1  = isGate ? AGG : GO;
  const int ksplit = 128;
  const int K      = isGate ? 256 : 128;
  const float* Wt  = isGate ? Wg : Wo;
  const float* Bia = isGate ? Bg : Bo;
  float* Cp        = isGate ? LOCAL : GOP;
  const int m0 = blockIdx.x * 64, n0 = (blockIdx.y & 1) * 64;
  const int tid = threadIdx.x;
  const int srow = tid >> 2, koff = (tid & 3) * 8;
  const int lane = tid & 63, wave = tid >> 6;
  const int quad = lane >> 4, m16 = lane & 15;
  f32x4 acc[4];
#pragma unroll
  for (int i = 0; i < 4; i++) acc[i] = {0.f, 0.f, 0.f, 0.f};

  for (int k0 = 0; k0 < K; k0 += 32) {
    const int kg = k0 + koff;
    const float* ap = (kg < ksplit) ? (A0 + (size_t)(m0 + srow) * 128 + kg)
                                    : (A1 + (size_t)(m0 + srow) * 128 + (kg - ksplit));
    float4 a0 = *(const float4*)ap, a1 = *(const float4*)(ap + 4);
    const float* wp = Wt + (size_t)(n0 + srow) * K + kg;
    float4 w0 = *(const float4*)wp, w1v = *(const float4*)(wp + 4);
    __syncthreads();
    *(short8*)&Asm[srow][koff] = cvt8(a0, a1);
    *(short8*)&Wsm[srow][koff] = cvt8(w0, w1v);
    __syncthreads();
    short8 af = *(short8*)&Asm[wave * 16 + m16][quad * 8];
#pragma unroll
    for (int nt = 0; nt < 4; nt++) {
      short8 bf = *(short8*)&Wsm[nt * 16 + m16][quad * 8];
      acc[nt] = __builtin_amdgcn_mfma_f32_16x16x32_bf16(af, bf, acc[nt], 0, 0, 0);
    }
  }
#pragma unroll
  for (int nt = 0; nt < 4; nt++) {
#pragma unroll
    for (int r = 0; r < 4; r++) {
      const int m = m0 + wave * 16 + quad * 4 + r;
      const int n = n0 + nt * 16 + m16;
      float v = acc[nt][r] + Bia[n];
      size_t oi = (size_t)m * 128 + n;
      if (isGate) {
        float g = 1.0f / (1.0f + __expf(fminf(fmaxf(-v, -80.f), 80.f)));
        v = g * AGG[oi] + (1.0f - g) * X[oi];
      }
      Cp[oi] = v;
    }
  }
}

// ---------------- global attention: 64 q-rows, 8 waves (keys 8-way), 512 threads ----------------
// grid 512 = head(8) x 64-row q-tile(64); same validated S^T/P^T register dataflow.
__global__ __launch_bounds__(512) void k_gattn6(
    const unsigned short* __restrict__ Qb, const unsigned short* __restrict__ Kb,
    const unsigned short* __restrict__ VT, float* __restrict__ O)
{
  __shared__ float LO[8][4][16][16];
  __shared__ float LL[8][4][16];
  const int h = blockIdx.x >> 6, qt = blockIdx.x & 63;
  const int tid = threadIdx.x, lane = tid & 63, wave = tid >> 6;   // wave 0..7
  const int quad = lane >> 4, m16 = lane & 15;
  const int r0 = qt * 64;
  const short8 z8 = {0,0,0,0,0,0,0,0};
  const f32x4  z4 = {0.f,0.f,0.f,0.f};
  short8 qf[4] = {z8, z8, z8, z8};
  if (quad < 2) {
#pragma unroll
    for (int j = 0; j < 4; j++)
      qf[j] = *(const short8*)(Qb + (size_t)(r0 + j * 16 + m16) * DM + h * 16 + quad * 8);
  }
  short8 ones;
#pragma unroll
  for (int i = 0; i < 8; i++) ones[i] = (short)0x3F80;
  const int kperm = (m16 >> 2) * 8 + (m16 & 3);
  const int kbase = wave * 512;
  f32x4 acc[4] = {z4, z4, z4, z4};
  f32x4 acc2[4] = {z4, z4, z4, z4};
  short8 a0 = z8, a1 = z8, a2 = z8, a3 = z8;
  for (int kt = 0; kt < 8; kt++) {
    const int key0 = kbase + kt * 64;
    if (quad < 2) {
      const unsigned short* kp = Kb + (size_t)(key0 + kperm) * DM + h * 16 + quad * 8;
      a0 = *(const short8*)kp;
      a1 = *(const short8*)(kp + 4 * DM);
      a2 = *(const short8*)(kp + 32 * DM);
      a3 = *(const short8*)(kp + 36 * DM);
    }
    const unsigned short* vp = VT + (size_t)(h * 16 + m16) * NN + key0 + quad * 8;
    short8 av0 = *(const short8*)vp;
    short8 av1 = *(const short8*)(vp + 32);
#pragma unroll
    for (int j = 0; j < 4; j++) {
      f32x4 s0 = __builtin_amdgcn_mfma_f32_16x16x32_bf16(a0, qf[j], z4, 0, 0, 0);
      f32x4 s1 = __builtin_amdgcn_mfma_f32_16x16x32_bf16(a1, qf[j], z4, 0, 0, 0);
      f32x4 s2 = __builtin_amdgcn_mfma_f32_16x16x32_bf16(a2, qf[j], z4, 0, 0, 0);
      f32x4 s3 = __builtin_amdgcn_mfma_f32_16x16x32_bf16(a3, qf[j], z4, 0, 0, 0);
      float e0 = exp2f(fminf(s0[0], 30.f)), e1 = exp2f(fminf(s0[1], 30.f));
      float e2 = exp2f(fminf(s0[2], 30.f)), e3 = exp2f(fminf(s0[3], 30.f));
      float e4 = exp2f(fminf(s1[0], 30.f)), e5 = exp2f(fminf(s1[1], 30.f));
      float e6 = exp2f(fminf(s1[2], 30.f)), e7 = exp2f(fminf(s1[3], 30.f));
      uint4v u;
      u.x = pkt(e0, e1); u.y = pkt(e2, e3); u.z = pkt(e4, e5); u.w = pkt(e6, e7);
      short8 p0 = __builtin_bit_cast(short8, u);
      float f0 = exp2f(fminf(s2[0], 30.f)), f1 = exp2f(fminf(s2[1], 30.f));
      float f2 = exp2f(fminf(s2[2], 30.f)), f3 = exp2f(fminf(s2[3], 30.f));
      float f4 = exp2f(fminf(s3[0], 30.f)), f5 = exp2f(fminf(s3[1], 30.f));
      float f6 = exp2f(fminf(s3[2], 30.f)), f7 = exp2f(fminf(s3[3], 30.f));
      uint4v w;
      w.x = pkt(f0, f1); w.y = pkt(f2, f3); w.z = pkt(f4, f5); w.w = pkt(f6, f7);
      short8 p1 = __builtin_bit_cast(short8, w);
      acc[j]  = __builtin_amdgcn_mfma_f32_16x16x32_bf16(av0, p0, acc[j], 0, 0, 0);
      acc[j]  = __builtin_amdgcn_mfma_f32_16x16x32_bf16(av1, p1, acc[j], 0, 0, 0);
      acc2[j] = __builtin_amdgcn_mfma_f32_16x16x32_bf16(ones, p0, acc2[j], 0, 0, 0);
      acc2[j] = __builtin_amdgcn_mfma_f32_16x16x32_bf16(ones, p1, acc2[j], 0, 0, 0);
    }
  }
#pragma unroll
  for (int j = 0; j < 4; j++) {
    float4 a4; a4.x = acc[j][0]; a4.y = acc[j][1]; a4.z = acc[j][2]; a4.w = acc[j][3];
    *(float4*)&LO[wave][j][m16][quad * 4] = a4;
    if (lane < 16) LL[wave][j][lane] = acc2[j][0];
  }
  __syncthreads();
  if (wave < 4) {
    const int j = wave;
    float4 o = *(float4*)&LO[0][j][m16][quad * 4];
    float lt = LL[0][j][m16];
#pragma unroll
    for (int w2 = 1; w2 < 8; w2++) {
      float4 t = *(float4*)&LO[w2][j][m16][quad * 4];
      o.x += t.x; o.y += t.y; o.z += t.z; o.w += t.w;
      lt += LL[w2][j][m16];
    }
    float inv = 1.0f / fmaxf(lt, 1e-30f);
    float4 r4; r4.x = o.x * inv; r4.y = o.y * inv; r4.z = o.z * inv; r4.w = o.w * inv;
    *(float4*)(O + (size_t)(r0 + j * 16 + m16) * DM + h * 16 + quad * 4) = r4;
  }
}

// ---------------- FFN first GEMM with inline h = x+relu(ln1(T)) and ln2 ----------------
// grid (64, 8). h written only by blockIdx.y==0 blocks.
__global__ __launch_bounds__(256) void gemm_ffn1(
    const float* __restrict__ T, const float* __restrict__ X,
    const float* __restrict__ Gf, const float* __restrict__ Bef,
    const float* __restrict__ G2, const float* __restrict__ Be2,
    const float* __restrict__ W1, const float* __restrict__ B1,
    float* __restrict__ H, float* __restrict__ T1)
{
  __shared__ short Asm[64][40];
  __shared__ short Wsm[64][40];
  const int m0 = blockIdx.x * 64, n0 = blockIdx.y * 64;
  const int tid = threadIdx.x;
  const int srow = tid >> 2, koff = (tid & 3) * 8;
  const int lane = tid & 63, wave = tid >> 6;
  const int quad = lane >> 4, m16 = lane & 15;

  const float* trow = T + (size_t)(m0 + srow) * 128 + koff;
  const float* xrow = X + (size_t)(m0 + srow) * 128 + koff;
  float4 a0[4], a1[4];
#pragma unroll
  for (int c = 0; c < 4; c++) {
    a0[c] = *(const float4*)(trow + c * 32);
    a1[c] = *(const float4*)(trow + c * 32 + 4);
  }
  // ln1 over T row
  {
    float s = 0.f;
#pragma unroll
    for (int c = 0; c < 4; c++)
      s += a0[c].x + a0[c].y + a0[c].z + a0[c].w + a1[c].x + a1[c].y + a1[c].z + a1[c].w;
    s += __shfl_xor(s, 1); s += __shfl_xor(s, 2);
    float mean = s * (1.0f / 128.0f);
    float v = 0.f;
#pragma unroll
    for (int c = 0; c < 4; c++) {
      float d;
      d = a0[c].x - mean; v += d*d;  d = a0[c].y - mean; v += d*d;
      d = a0[c].z - mean; v += d*d;  d = a0[c].w - mean; v += d*d;
      d = a1[c].x - mean; v += d*d;  d = a1[c].y - mean; v += d*d;
      d = a1[c].z - mean; v += d*d;  d = a1[c].w - mean; v += d*d;
    }
    v += __shfl_xor(v, 1); v += __shfl_xor(v, 2);
    float rstd = rsqrtf(v * (1.0f / 128.0f) + 1e-5f);
#pragma unroll
    for (int c = 0; c < 4; c++) {
      const int col = c * 32 + koff;
      float4 gv0 = *(const float4*)(Gf + col),  gv1 = *(const float4*)(Gf + col + 4);
      float4 bv0 = *(const float4*)(Bef + col), bv1 = *(const float4*)(Bef + col + 4);
      float4 x0 = *(const float4*)(xrow + c * 32), x1 = *(const float4*)(xrow + c * 32 + 4);
      LN1(a0[c].x, gv0.x, bv0.x); LN1(a0[c].y, gv0.y, bv0.y);
      LN1(a0[c].z, gv0.z, bv0.z); LN1(a0[c].w, gv0.w, bv0.w);
      LN1(a1[c].x, gv1.x, bv1.x); LN1(a1[c].y, gv1.y, bv1.y);
      LN1(a1[c].z, gv1.z, bv1.z); LN1(a1[c].w, gv1.w, bv1.w);
      a0[c].x = x0.x + fmaxf(a0[c].x, 0.f); a0[c].y = x0.y + fmaxf(a0[c].y, 0.f);
      a0[c].z = x0.z + fmaxf(a0[c].z, 0.f); a0[c].w = x0.w + fmaxf(a0[c].w, 0.f);
      a1[c].x = x1.x + fmaxf(a1[c].x, 0.f); a1[c].y = x1.y + fmaxf(a1[c].y, 0.f);
      a1[c].z = x1.z + fmaxf(a1[c].z, 0.f); a1[c].w = x1.w + fmaxf(a1[c].w, 0.f);
      if (blockIdx.y == 0) {
        *(float4*)(H + (size_t)(m0 + srow) * 128 + c * 32 + koff)     = a0[c];
        *(float4*)(H + (size_t)(m0 + srow) * 128 + c * 32 + koff + 4) = a1[c];
      }
    }
  }
  // ln2 over h row
  {
    float s = 0.f;
#pragma unroll
    for (int c = 0; c < 4; c++)
      s += a0[c].x + a0[c].y + a0[c].z + a0[c].w + a1[c].x + a1[c].y + a1[c].z + a1[c].w;
    s += __shfl_xor(s, 1); s += __shfl_xor(s, 2);
    float mean = s * (1.0f / 128.0f);
    float v = 0.f;
#pragma unroll
    for (int c = 0; c < 4; c++) {
      float d;
      d = a0[c].x - mean; v += d*d;  d = a0[c].y - mean; v += d*d;
      d = a0[c].z - mean; v += d*d;  d = a0[c].w - mean; v += d*d;
      d = a1[c].x - mean; v += d*d;  d = a1[c].y - mean; v += d*d;
      d = a1[c].z - mean; v += d*d;  d = a1[c].w - mean; v += d*d;
    }
    v += __shfl_xor(v, 1); v += __shfl_xor(v, 2);
    float rstd = rsqrtf(v * (1.0f / 128.0f) + 1e-5f);
#pragma unroll
    for (int c = 0; c < 4; c++) {
      const int col = c * 32 + koff;
      float4 gv0 = *(const float4*)(G2 + col),  gv1 = *(const float4*)(G2 + col + 4);
      float4 bv0 = *(const float4*)(Be2 + col), bv1 = *(const float4*)(Be2 + col + 4);
      LN1(a0[c].x, gv0.x, bv0.x); LN1(a0[c].y, gv0.y, bv0.y);
      LN1(a0[c].z, gv0.z, bv0.z); LN1(a0[c].w, gv0.w, bv0.w);
      LN1(a1[c].x, gv1.x, bv1.x); LN1(a1[c].y, gv1.y, bv1.y);
      LN1(a1[c].z, gv1.z, bv1.z); LN1(a1[c].w, gv1.w, bv1.w);
    }
  }

  f32x4 acc[4];
#pragma unroll
  for (int i = 0; i < 4; i++) acc[i] = {0.f, 0.f, 0.f, 0.f};
#pragma unroll
  for (int c = 0; c < 4; c++) {
    const float* wp = W1 + (size_t)(n0 + srow) * 128 + c * 32 + koff;
    float4 w0 = *(const float4*)wp, w1v = *(const float4*)(wp + 4);
    __syncthreads();
    *(short8*)&Asm[srow][koff] = cvt8(a0[c], a1[c]);
    *(short8*)&Wsm[srow][koff] = cvt8(w0, w1v);
    __syncthreads();
    short8 af = *(short8*)&Asm[wave * 16 + m16][quad * 8];
#pragma unroll
    for (int nt = 0; nt < 4; nt++) {
      short8 bf = *(short8*)&Wsm[nt * 16 + m16][quad * 8];
      acc[nt] = __builtin_amdgcn_mfma_f32_16x16x32_bf16(af, bf, acc[nt], 0, 0, 0);
    }
  }
#pragma unroll
  for (int nt = 0; nt < 4; nt++) {
#pragma unroll
    for (int r = 0; r < 4; r++) {
      const int m = m0 + wave * 16 + quad * 4 + r;
      const int n = n0 + nt * 16 + m16;
      float v = acc[nt][r] + B1[n];
      v = 0.5f * v * (1.0f + erff(v * 0.70710678118654752f));
      T1[(size_t)m * 512 + n] = v;
    }
  }
}

// ---------------- edge attention, 8 lanes/edge (lane = head), coalesced ----------------
__global__ __launch_bounds__(256) void k_edge_attn8(const int* __restrict__ EI,
    const float* __restrict__ Q, const float* __restrict__ Kl,
    unsigned short* __restrict__ EB, int* __restrict__ deg) {
  int is64 = detect64(EI);
  int gid = blockIdx.x * 256 + threadIdx.x;
  int e = gid >> 3, hh = gid & 7;
  int s = is64 ? EI[2*e]      : EI[e];
  int d = is64 ? EI[2*(NE+e)] : EI[NE+e];
  s = min(max(s, 0), NN-1); d = min(max(d, 0), NN-1);
  const float4* qp = (const float4*)(Q  + (size_t)d * DM + hh * 16);
  const float4* kp = (const float4*)(Kl + (size_t)s * DM + hh * 16);
  float acc = 0.f;
#pragma unroll
  for (int c = 0; c < 4; c++) {
    float4 qa = qp[c], ka = kp[c];
    acc += qa.x*ka.x + qa.y*ka.y + qa.z*ka.z + qa.w*ka.w;
  }
  EB[(size_t)e*8 + hh] = f2bh(exp2f(fminf(acc, 43.0f)));   // Q pre-scaled by ESCALE
  if (hh == 0) atomicAdd(&deg[d], 1);
}

// ---------------- CSR scan + scatter ----------------
__global__ __launch_bounds__(256) void k_scan(const int* __restrict__ deg,
    int* __restrict__ offs, int* __restrict__ cursor) {
  __shared__ int sums[256];
  int t = threadIdx.x;
  int loc[16];
  int s = 0;
#pragma unroll
  for (int i = 0; i < 16; i++) { loc[i] = s; s += deg[t*16 + i]; }
  sums[t] = s;
  __syncthreads();
  for (int d = 1; d < 256; d <<= 1) {
    int v = (t >= d) ? sums[t - d] : 0;
    __syncthreads();
    sums[t] += v;
    __syncthreads();
  }
  int base = sums[t] - s;
#pragma unroll
  for (int i = 0; i < 16; i++) {
    offs[t*16 + i] = base + loc[i];
    cursor[t*16 + i] = base + loc[i];
  }
}
__global__ __launch_bounds__(256) void k_scatter(const int* __restrict__ EI,
    int* __restrict__ cursor, int* __restrict__ elist) {
  int is64 = detect64(EI);
  int e = blockIdx.x * 256 + threadIdx.x;
  int d = is64 ? EI[2*(NE+e)] : EI[NE+e];
  d = min(max(d, 0), NN-1);
  int slot = atomicAdd(&cursor[d], 1);
  elist[slot] = e;
}

// ---------------- per-dst aggregation (atomic-free; 4x unrolled gather) ----------------
__global__ __launch_bounds__(256) void k_edge_agg2(const int* __restrict__ EI,
    const int* __restrict__ deg, const int* __restrict__ offs,
    const int* __restrict__ elist, const unsigned short* __restrict__ Vl,
    const unsigned short* __restrict__ EB, float* __restrict__ AG) {
  int is64 = detect64(EI);
  int d = blockIdx.x * 4 + (threadIdx.x >> 6);
  int lane = threadIdx.x & 63;
  int degd = deg[d], start = offs[d];
  int hh = lane >> 3;
  float ss = 0.f;
  for (int i = lane & 7; i < degd; i += 8)
    ss += b2f16(EB[(size_t)elist[start + i] * 8 + hh]);
  for (int o = 1; o < 8; o <<= 1) ss += __shfl_xor(ss, o);
  float inv = 1.0f / fmaxf(ss, 1e-30f);
  float ax = 0.f, ay = 0.f;
  int i = 0;
  for (; i + 4 <= degd; i += 4) {
    int e0 = elist[start+i], e1 = elist[start+i+1], e2 = elist[start+i+2], e3 = elist[start+i+3];
    int s0 = is64 ? EI[2*e0] : EI[e0];
    int s1 = is64 ? EI[2*e1] : EI[e1];
    int s2 = is64 ? EI[2*e2] : EI[e2];
    int s3 = is64 ? EI[2*e3] : EI[e3];
    s0 = min(max(s0,0),NN-1); s1 = min(max(s1,0),NN-1);
    s2 = min(max(s2,0),NN-1); s3 = min(max(s3,0),NN-1);
    float w0 = b2f16(EB[(size_t)e0*8 + hh]) * inv;
    float w1 = b2f16(EB[(size_t)e1*8 + hh]) * inv;
    float w2 = b2f16(EB[(size_t)e2*8 + hh]) * inv;
    float w3 = b2f16(EB[(size_t)e3*8 + hh]) * inv;
    unsigned v0 = *(const unsigned*)(Vl + (size_t)s0 * DM + 2 * lane);
    unsigned v1 = *(const unsigned*)(Vl + (size_t)s1 * DM + 2 * lane);
    unsigned v2 = *(const unsigned*)(Vl + (size_t)s2 * DM + 2 * lane);
    unsigned v3 = *(const unsigned*)(Vl + (size_t)s3 * DM + 2 * lane);
    ax += w0 * b2f16((unsigned short)(v0 & 0xffffu)) + w1 * b2f16((unsigned short)(v1 & 0xffffu))
        + w2 * b2f16((unsigned short)(v2 & 0xffffu)) + w3 * b2f16((unsigned short)(v3 & 0xffffu));
    ay += w0 * b2f16((unsigned short)(v0 >> 16)) + w1 * b2f16((unsigned short)(v1 >> 16))
        + w2 * b2f16((unsigned short)(v2 >> 16)) + w3 * b2f16((unsigned short)(v3 >> 16));
  }
  for (; i < degd; i++) {
    int e = elist[start + i];
    int s = is64 ? EI[2*e] : EI[e];
    s = min(max(s, 0), NN-1);
    float a = b2f16(EB[(size_t)e*8 + hh]) * inv;
    unsigned v = *(const unsigned*)(Vl + (size_t)s * DM + 2 * lane);
    ax += a * b2f16((unsigned short)(v & 0xffffu));
    ay += a * b2f16((unsigned short)(v >> 16));
  }
  float2 r; r.x = ax; r.y = ay;
  *(float2*)(AG + (size_t)d * DM + 2 * lane) = r;
}

extern "C" void kernel_launch(void* const* d_in, const int* in_sizes, int n_in,
                              void* d_out, int out_size, void* d_ws, size_t ws_size,
                              hipStream_t stream) {
  const float* x     = (const float*)d_in[0];
  const int*   ei    = (const int*)  d_in[1];
  const float* wq_l  = (const float*)d_in[2];  const float* bq_l = (const float*)d_in[3];
  const float* wk_l  = (const float*)d_in[4];  const float* bk_l = (const float*)d_in[5];
  const float* wv_l  = (const float*)d_in[6];  const float* bv_l = (const float*)d_in[7];
  const float* wg    = (const float*)d_in[8];  const float* bg   = (const float*)d_in[9];
  const float* wq_g  = (const float*)d_in[10]; const float* bq_g = (const float*)d_in[11];
  const float* wk_g  = (const float*)d_in[12]; const float* bk_g = (const float*)d_in[13];
  const float* wv_g  = (const float*)d_in[14]; const float* bv_g = (const float*)d_in[15];
  const float* wo_g  = (const float*)d_in[16]; const float* bo_g = (const float*)d_in[17];
  const float* wf    = (const float*)d_in[18]; const float* bff  = (const float*)d_in[19];
  const float* gf    = (const float*)d_in[20]; const float* betaf= (const float*)d_in[21];
  const float* w1    = (const float*)d_in[22]; const float* b1   = (const float*)d_in[23];
  const float* w2    = (const float*)d_in[24]; const float* b2   = (const float*)d_in[25];
  const float* g1    = (const float*)d_in[26]; const float* be1  = (const float*)d_in[27];
  const float* g2    = (const float*)d_in[28]; const float* be2  = (const float*)d_in[29];
  float* out = (float*)d_out;

  const size_t NEED = (size_t)3289088 * 4;
  if (ws_size < NEED) {
    k_fill<<<2048, 256, 0, stream>>>(out, 100.0f, NN*DM);
    return;
  }

  // workspace (float offsets), serial hazard audit in comments:
  float* W = (float*)d_ws;
  float*          lQ    = W + 0;        // gemm_six out -> dead after edge_attn8
  float*          lK    = W + 524288;   // gemm_six out -> dead after edge_attn8 -> local_
  unsigned short* lV    = (unsigned short*)(W + 1048576); // [1048576,1310720) -> dead after agg2
  unsigned short* eb    = (unsigned short*)(W + 1310720); // [1310720,1835008) -> dead after agg2
  float*          agg   = W + 1835008;  // [1835008,2359296) agg2 out -> dead after dual
  unsigned short* qgb   = (unsigned short*)(W + 2359296); // [2359296,2621440) -> dead after gattn6
  unsigned short* kgb   = (unsigned short*)(W + 2621440); // [2621440,2883584) -> dead after gattn6
  unsigned short* vgT   = (unsigned short*)(W + 2883584); // [2883584,3145728) -> dead after gattn6
  float*          go    = W + 0;        // gattn6 out (over lQ) -> dead after dual
  float*          local_= W + 524288;   // dual out (over lK) -> dead after fusion
  float*          gop   = W + 1048576;  // [1048576,1572864) dual out (over lV/eb lo) -> dead after fusion
  float*          tmpf  = W + 2097152;  // [2097152,2621440) fusion out (over agg hi/qgb) -> dead after ffn1
  float*          h     = W + 2621440;  // [2621440,3145728) ffn1 out (over kgb/vgT)
  float*          t1    = W + 0;        // [0,2097152) ffn1 out (over go/local_/gop/agg lo)
  int* deg    = (int*)(W + 3145728);
  int* cursor = (int*)(W + 3149824);
  int* offs   = (int*)(W + 3153920);
  int* elist  = (int*)(W + 3158016);

  dim3 b256(256);

  hipMemsetAsync(deg, 0, 4096 * sizeof(int), stream);

  // all six projections (inline LN for global branch; Q_l pre-scaled by ESCALE)
  gemm_six<<<dim3(64,12), b256, 0, stream>>>(x, g1, be1,
      wq_l, wk_l, wv_l, wq_g, wk_g, wv_g,
      bq_l, bk_l, bv_l, bq_g, bk_g, bv_g,
      lQ, lK, lV, qgb, kgb, vgT);

  // edge pipeline
  k_edge_attn8<<<4096, b256, 0, stream>>>(ei, lQ, lK, eb, deg);
  k_scan<<<1, b256, 0, stream>>>(deg, offs, cursor);
  k_scatter<<<512, b256, 0, stream>>>(ei, cursor, elist);
  k_edge_agg2<<<1024, b256, 0, stream>>>(ei, deg, offs, elist, lV, eb, agg);

  // global attention (8 waves, 2x latency hiding)
  k_gattn6<<<512, dim3(512), 0, stream>>>(qgb, kgb, vgT, go);

  // gate + wo fused
  gemm_dual<<<dim3(64,4), b256, 0, stream>>>(x, agg, go, wg, bg, wo_g, bo_g, local_, gop);

  // fusion GEMM
  gemm_mfma<<<dim3(64,2), b256, 0, stream>>>(local_,128, gop,128,128, wf, bff,
      nullptr,nullptr,nullptr, tmpf, 128, 256, 0, 0, 1.f);

  // FFN: w1 with inline h/ln2; then w2 + residual
  gemm_ffn1<<<dim3(64,8), b256, 0, stream>>>(tmpf, x, gf, betaf, g2, be2, w1, b1, h, t1);
  gemm_mfma<<<dim3(64,2), b256, 0, stream>>>(t1,512, nullptr,0,512, w2, b2,
      h, nullptr,nullptr, out, 128, 512, 0, 0, 1.f);
}

// Round 12
// 236.646 us; speedup vs baseline: 3.3267x; 1.0867x over previous
//
#include <hip/hip_runtime.h>
#include <math.h>

#define NN 4096
#define DM 128
#define NE 131072
#define QSCALE 0.36067376022224085f   // 0.25 * log2(e): exp(S/4) == exp2(S_prescaled)
#define ESCALE 0.36067376022224085f

typedef short short8 __attribute__((ext_vector_type(8)));
typedef float f32x4  __attribute__((ext_vector_type(4)));
typedef unsigned int uint4v __attribute__((ext_vector_type(4)));

static __device__ __forceinline__ unsigned pk2(float lo, float hi) {
  union { float f; unsigned u; } a, b; a.f = lo; b.f = hi;
  return ((b.u + 0x8000u) & 0xffff0000u) | ((a.u + 0x8000u) >> 16);
}
// truncating pack via v_perm_b32: result = [hi.hi16, lo.hi16]
static __device__ __forceinline__ unsigned pkp(float lo, float hi) {
  union { float f; unsigned u; } a, b; a.f = lo; b.f = hi;
  return __builtin_amdgcn_perm(b.u, a.u, 0x07060302u);
}
static __device__ __forceinline__ unsigned short f2bh(float f) {
  union { float f; unsigned u; } v; v.f = f;
  return (unsigned short)((v.u + 0x8000u) >> 16);
}
static __device__ __forceinline__ float b2f16(unsigned short u) {
  union { unsigned u; float f; } v; v.u = ((unsigned)u) << 16; return v.f;
}
static __device__ __forceinline__ short8 cvt8(float4 a, float4 b) {
  unsigned u0 = pk2(a.x, a.y), u1 = pk2(a.z, a.w);
  unsigned u2 = pk2(b.x, b.y), u3 = pk2(b.z, b.w);
  short8 r;
  r[0]=(short)(u0 & 0xffffu); r[1]=(short)(u0 >> 16);
  r[2]=(short)(u1 & 0xffffu); r[3]=(short)(u1 >> 16);
  r[4]=(short)(u2 & 0xffffu); r[5]=(short)(u2 >> 16);
  r[6]=(short)(u3 & 0xffffu); r[7]=(short)(u3 >> 16);
  return r;
}
static __device__ __forceinline__ int detect64(const int* __restrict__ EI) {
  int v = EI[2 * (threadIdx.x & 63) + 1];
  for (int off = 1; off < 64; off <<= 1) v |= __shfl_xor(v, off);
  return (v == 0) ? 1 : 0;
}

__global__ __launch_bounds__(256) void k_fill(float* __restrict__ out, float v, int n) {
  int i = blockIdx.x * 256 + threadIdx.x;
  if (i < n) out[i] = v;
}

// ---------------- MFMA GEMM: C = epi(A @ W^T + Bias) * oscale ----------------
__global__ __launch_bounds__(256) void gemm_mfma(
    const float* __restrict__ A0, int lda0,
    const float* __restrict__ A1, int lda1, int ksplit,
    const float* __restrict__ Wt, const float* __restrict__ Bias,
    const float* __restrict__ Res, const float* __restrict__ E0, const float* __restrict__ E1,
    void* __restrict__ Cp, int Nt, int K, int act, int omode, float oscale)
{
  __shared__ short Asm[64][40];
  __shared__ short Wsm[64][40];
  const int m0 = blockIdx.x * 64, n0 = blockIdx.y * 64;
  const int tid = threadIdx.x;
  const int srow = tid >> 2, koff = (tid & 3) * 8;
  const int lane = tid & 63, wave = tid >> 6;
  const int quad = lane >> 4, m16 = lane & 15;
  f32x4 acc[4];
#pragma unroll
  for (int i = 0; i < 4; i++) acc[i] = {0.f, 0.f, 0.f, 0.f};

  for (int k0 = 0; k0 < K; k0 += 32) {
    const int kg = k0 + koff;
    const float* ap = (kg < ksplit) ? (A0 + (size_t)(m0 + srow) * lda0 + kg)
                                    : (A1 + (size_t)(m0 + srow) * lda1 + (kg - ksplit));
    float4 a0 = *(const float4*)ap, a1 = *(const float4*)(ap + 4);
    const float* wp = Wt + (size_t)(n0 + srow) * K + kg;
    float4 w0 = *(const float4*)wp, w1v = *(const float4*)(wp + 4);
    __syncthreads();
    *(short8*)&Asm[srow][koff] = cvt8(a0, a1);
    *(short8*)&Wsm[srow][koff] = cvt8(w0, w1v);
    __syncthreads();
    short8 af = *(short8*)&Asm[wave * 16 + m16][quad * 8];
#pragma unroll
    for (int nt = 0; nt < 4; nt++) {
      short8 bf = *(short8*)&Wsm[nt * 16 + m16][quad * 8];
      acc[nt] = __builtin_amdgcn_mfma_f32_16x16x32_bf16(af, bf, acc[nt], 0, 0, 0);
    }
  }
#pragma unroll
  for (int nt = 0; nt < 4; nt++) {
#pragma unroll
    for (int r = 0; r < 4; r++) {
      const int m = m0 + wave * 16 + quad * 4 + r;
      const int n = n0 + nt * 16 + m16;
      float v = acc[nt][r] + Bias[n];
      size_t oi = (size_t)m * Nt + n;
      if (act == 1) v = 0.5f * v * (1.0f + erff(v * 0.70710678118654752f));
      else if (act == 2) {
        float g = 1.0f / (1.0f + __expf(fminf(fmaxf(-v, -80.f), 80.f)));
        v = g * E0[oi] + (1.0f - g) * E1[oi];
      }
      if (Res) v += Res[oi];
      v *= oscale;
      if (omode == 0)      ((float*)Cp)[oi] = v;
      else if (omode == 1) ((unsigned short*)Cp)[oi] = f2bh(v);
      else                 ((unsigned short*)Cp)[(size_t)n * NN + m] = f2bh(v);
    }
  }
}

// ---------------- six-way QKV GEMM with inline LN for global branch ----------------
#define LN1(V, GV, BV) V = (V - mean) * rstd * GV + BV
__global__ __launch_bounds__(256) void gemm_six(
    const float* __restrict__ X,
    const float* __restrict__ G1, const float* __restrict__ Be1,
    const float* __restrict__ W0, const float* __restrict__ W1, const float* __restrict__ W2,
    const float* __restrict__ W3, const float* __restrict__ W4, const float* __restrict__ W5,
    const float* __restrict__ B0, const float* __restrict__ B1, const float* __restrict__ B2,
    const float* __restrict__ B3, const float* __restrict__ B4, const float* __restrict__ B5,
    void* __restrict__ O0, void* __restrict__ O1, void* __restrict__ O2,
    void* __restrict__ O3, void* __restrict__ O4, void* __restrict__ O5)
{
  __shared__ short Asm[64][40];
  __shared__ short Wsm[64][40];
  const int g = blockIdx.y >> 1;
  const float* Wt  = (g==0)?W0:(g==1)?W1:(g==2)?W2:(g==3)?W3:(g==4)?W4:W5;
  const float* Bia = (g==0)?B0:(g==1)?B1:(g==2)?B2:(g==3)?B3:(g==4)?B4:B5;
  void* Cp         = (g==0)?O0:(g==1)?O1:(g==2)?O2:(g==3)?O3:(g==4)?O4:O5;
  const int omode  = (g==2)?1:(g>=3)?((g==5)?2:1):0;
  const float osc  = (g==3)? QSCALE : (g==0)? ESCALE : 1.f;
  const int m0 = blockIdx.x * 64, n0 = (blockIdx.y & 1) * 64;
  const int tid = threadIdx.x;
  const int srow = tid >> 2, koff = (tid & 3) * 8;
  const int lane = tid & 63, wave = tid >> 6;
  const int quad = lane >> 4, m16 = lane & 15;

  const float* arow = X + (size_t)(m0 + srow) * 128 + koff;
  float4 a0[4], a1[4];
#pragma unroll
  for (int c = 0; c < 4; c++) {
    a0[c] = *(const float4*)(arow + c * 32);
    a1[c] = *(const float4*)(arow + c * 32 + 4);
  }
  if (g >= 3) {
    float s = 0.f;
#pragma unroll
    for (int c = 0; c < 4; c++)
      s += a0[c].x + a0[c].y + a0[c].z + a0[c].w + a1[c].x + a1[c].y + a1[c].z + a1[c].w;
    s += __shfl_xor(s, 1); s += __shfl_xor(s, 2);
    float mean = s * (1.0f / 128.0f);
    float v = 0.f;
#pragma unroll
    for (int c = 0; c < 4; c++) {
      float d;
      d = a0[c].x - mean; v += d*d;  d = a0[c].y - mean; v += d*d;
      d = a0[c].z - mean; v += d*d;  d = a0[c].w - mean; v += d*d;
      d = a1[c].x - mean; v += d*d;  d = a1[c].y - mean; v += d*d;
      d = a1[c].z - mean; v += d*d;  d = a1[c].w - mean; v += d*d;
    }
    v += __shfl_xor(v, 1); v += __shfl_xor(v, 2);
    float rstd = rsqrtf(v * (1.0f / 128.0f) + 1e-5f);
#pragma unroll
    for (int c = 0; c < 4; c++) {
      const int col = c * 32 + koff;
      float4 gv0 = *(const float4*)(G1 + col),  gv1 = *(const float4*)(G1 + col + 4);
      float4 bv0 = *(const float4*)(Be1 + col), bv1 = *(const float4*)(Be1 + col + 4);
      LN1(a0[c].x, gv0.x, bv0.x); LN1(a0[c].y, gv0.y, bv0.y);
      LN1(a0[c].z, gv0.z, bv0.z); LN1(a0[c].w, gv0.w, bv0.w);
      LN1(a1[c].x, gv1.x, bv1.x); LN1(a1[c].y, gv1.y, bv1.y);
      LN1(a1[c].z, gv1.z, bv1.z); LN1(a1[c].w, gv1.w, bv1.w);
    }
  }

  f32x4 acc[4];
#pragma unroll
  for (int i = 0; i < 4; i++) acc[i] = {0.f, 0.f, 0.f, 0.f};
#pragma unroll
  for (int c = 0; c < 4; c++) {
    const float* wp = Wt + (size_t)(n0 + srow) * 128 + c * 32 + koff;
    float4 w0 = *(const float4*)wp, w1v = *(const float4*)(wp + 4);
    __syncthreads();
    *(short8*)&Asm[srow][koff] = cvt8(a0[c], a1[c]);
    *(short8*)&Wsm[srow][koff] = cvt8(w0, w1v);
    __syncthreads();
    short8 af = *(short8*)&Asm[wave * 16 + m16][quad * 8];
#pragma unroll
    for (int nt = 0; nt < 4; nt++) {
      short8 bf = *(short8*)&Wsm[nt * 16 + m16][quad * 8];
      acc[nt] = __builtin_amdgcn_mfma_f32_16x16x32_bf16(af, bf, acc[nt], 0, 0, 0);
    }
  }
#pragma unroll
  for (int nt = 0; nt < 4; nt++) {
#pragma unroll
    for (int r = 0; r < 4; r++) {
      const int m = m0 + wave * 16 + quad * 4 + r;
      const int n = n0 + nt * 16 + m16;
      float v = (acc[nt][r] + Bia[n]) * osc;
      size_t oi = (size_t)m * 128 + n;
      if (omode == 0)      ((float*)Cp)[oi] = v;
      else if (omode == 1) ((unsigned short*)Cp)[oi] = f2bh(v);
      else                 ((unsigned short*)Cp)[(size_t)n * NN + m] = f2bh(v);
    }
  }
}

// ---------------- dual GEMM: y<2 = gate (K=256, act2), y>=2 = wo (K=128) ----------------
__global__ __launch_bounds__(256) void gemm_dual(
    const float* __restrict__ X, const float* __restrict__ AGG,
    const float* __restrict__ GO,
    const float* __restrict__ Wg, const float* __restrict__ Bg,
    const float* __restrict__ Wo, const float* __restrict__ Bo,
    float* __restrict__ LOCAL, float* __restrict__ GOP)
{
  __shared__ short Asm[64][40];
  __shared__ short Wsm[64][40];
  const int isGate = (blockIdx.y < 2);
  const float* A0  = isGate ? X   : GO;
  const float* A1  = isGate ? AGG : GO;
  const int ksplit = 128;
  const int K      = isGate ? 256 : 128;
  const float* Wt  = isGate ? Wg : Wo;
  const float* Bia = isGate ? Bg : Bo;
  float* Cp        = isGate ? LOCAL : GOP;
  const int m0 = blockIdx.x * 64, n0 = (blockIdx.y & 1) * 64;
  const int tid = threadIdx.x;
  const int srow = tid >> 2, koff = (tid & 3) * 8;
  const int lane = tid & 63, wave = tid >> 6;
  const int quad = lane >> 4, m16 = lane & 15;
  f32x4 acc[4];
#pragma unroll
  for (int i = 0; i < 4; i++) acc[i] = {0.f, 0.f, 0.f, 0.f};

  for (int k0 = 0; k0 < K; k0 += 32) {
    const int kg = k0 + koff;
    const float* ap = (kg < ksplit) ? (A0 + (size_t)(m0 + srow) * 128 + kg)
                                    : (A1 + (size_t)(m0 + srow) * 128 + (kg - ksplit));
    float4 a0 = *(const float4*)ap, a1 = *(const float4*)(ap + 4);
    const float* wp = Wt + (size_t)(n0 + srow) * K + kg;
    float4 w0 = *(const float4*)wp, w1v = *(const float4*)(wp + 4);
    __syncthreads();
    *(short8*)&Asm[srow][koff] = cvt8(a0, a1);
    *(short8*)&Wsm[srow][koff] = cvt8(w0, w1v);
    __syncthreads();
    short8 af = *(short8*)&Asm[wave * 16 + m16][quad * 8];
#pragma unroll
    for (int nt = 0; nt < 4; nt++) {
      short8 bf = *(short8*)&Wsm[nt * 16 + m16][quad * 8];
      acc[nt] = __builtin_amdgcn_mfma_f32_16x16x32_bf16(af, bf, acc[nt], 0, 0, 0);
    }
  }
#pragma unroll
  for (int nt = 0; nt < 4; nt++) {
#pragma unroll
    for (int r = 0; r < 4; r++) {
      const int m = m0 + wave * 16 + quad * 4 + r;
      const int n = n0 + nt * 16 + m16;
      float v = acc[nt][r] + Bia[n];
      size_t oi = (size_t)m * 128 + n;
      if (isGate) {
        float g = 1.0f / (1.0f + __expf(fminf(fmaxf(-v, -80.f), 80.f)));
        v = g * AGG[oi] + (1.0f - g) * X[oi];
      }
      Cp[oi] = v;
    }
  }
}

// ---------------- global attention: 64 q-rows, 8 waves, raw-exp VALU diet ----------------
// grid 512 = head(8) x 64-row q-tile(64); same validated S^T/P^T register dataflow.
// exp2 via raw v_exp_f32 (inputs bounded: LN'd activations through bf16 GEMMs, |s| < ~25);
// bf16 truncation pack via single v_perm_b32.
__global__ __launch_bounds__(512) void k_gattn7(
    const unsigned short* __restrict__ Qb, const unsigned short* __restrict__ Kb,
    const unsigned short* __restrict__ VT, float* __restrict__ O)
{
  __shared__ float LO[8][4][16][16];
  __shared__ float LL[8][4][16];
  const int h = blockIdx.x >> 6, qt = blockIdx.x & 63;
  const int tid = threadIdx.x, lane = tid & 63, wave = tid >> 6;   // wave 0..7
  const int quad = lane >> 4, m16 = lane & 15;
  const int r0 = qt * 64;
  const short8 z8 = {0,0,0,0,0,0,0,0};
  const f32x4  z4 = {0.f,0.f,0.f,0.f};
  short8 qf[4] = {z8, z8, z8, z8};
  if (quad < 2) {
#pragma unroll
    for (int j = 0; j < 4; j++)
      qf[j] = *(const short8*)(Qb + (size_t)(r0 + j * 16 + m16) * DM + h * 16 + quad * 8);
  }
  short8 ones;
#pragma unroll
  for (int i = 0; i < 8; i++) ones[i] = (short)0x3F80;
  const int kperm = (m16 >> 2) * 8 + (m16 & 3);
  const int kbase = wave * 512;
  f32x4 acc[4] = {z4, z4, z4, z4};
  f32x4 acc2[4] = {z4, z4, z4, z4};
  short8 a0 = z8, a1 = z8, a2 = z8, a3 = z8;
  for (int kt = 0; kt < 8; kt++) {
    const int key0 = kbase + kt * 64;
    if (quad < 2) {
      const unsigned short* kp = Kb + (size_t)(key0 + kperm) * DM + h * 16 + quad * 8;
      a0 = *(const short8*)kp;
      a1 = *(const short8*)(kp + 4 * DM);
      a2 = *(const short8*)(kp + 32 * DM);
      a3 = *(const short8*)(kp + 36 * DM);
    }
    const unsigned short* vp = VT + (size_t)(h * 16 + m16) * NN + key0 + quad * 8;
    short8 av0 = *(const short8*)vp;
    short8 av1 = *(const short8*)(vp + 32);
#pragma unroll
    for (int j = 0; j < 4; j++) {
      f32x4 s0 = __builtin_amdgcn_mfma_f32_16x16x32_bf16(a0, qf[j], z4, 0, 0, 0);
      f32x4 s1 = __builtin_amdgcn_mfma_f32_16x16x32_bf16(a1, qf[j], z4, 0, 0, 0);
      f32x4 s2 = __builtin_amdgcn_mfma_f32_16x16x32_bf16(a2, qf[j], z4, 0, 0, 0);
      f32x4 s3 = __builtin_amdgcn_mfma_f32_16x16x32_bf16(a3, qf[j], z4, 0, 0, 0);
      float e0 = __builtin_amdgcn_exp2f(s0[0]), e1 = __builtin_amdgcn_exp2f(s0[1]);
      float e2 = __builtin_amdgcn_exp2f(s0[2]), e3 = __builtin_amdgcn_exp2f(s0[3]);
      float e4 = __builtin_amdgcn_exp2f(s1[0]), e5 = __builtin_amdgcn_exp2f(s1[1]);
      float e6 = __builtin_amdgcn_exp2f(s1[2]), e7 = __builtin_amdgcn_exp2f(s1[3]);
      uint4v u;
      u.x = pkp(e0, e1); u.y = pkp(e2, e3); u.z = pkp(e4, e5); u.w = pkp(e6, e7);
      short8 p0 = __builtin_bit_cast(short8, u);
      float f0 = __builtin_amdgcn_exp2f(s2[0]), f1 = __builtin_amdgcn_exp2f(s2[1]);
      float f2 = __builtin_amdgcn_exp2f(s2[2]), f3 = __builtin_amdgcn_exp2f(s2[3]);
      float f4 = __builtin_amdgcn_exp2f(s3[0]), f5 = __builtin_amdgcn_exp2f(s3[1]);
      float f6 = __builtin_amdgcn_exp2f(s3[2]), f7 = __builtin_amdgcn_exp2f(s3[3]);
      uint4v w;
      w.x = pkp(f0, f1); w.y = pkp(f2, f3); w.z = pkp(f4, f5); w.w = pkp(f6, f7);
      short8 p1 = __builtin_bit_cast(short8, w);
      acc[j]  = __builtin_amdgcn_mfma_f32_16x16x32_bf16(av0, p0, acc[j], 0, 0, 0);
      acc[j]  = __builtin_amdgcn_mfma_f32_16x16x32_bf16(av1, p1, acc[j], 0, 0, 0);
      acc2[j] = __builtin_amdgcn_mfma_f32_16x16x32_bf16(ones, p0, acc2[j], 0, 0, 0);
      acc2[j] = __builtin_amdgcn_mfma_f32_16x16x32_bf16(ones, p1, acc2[j], 0, 0, 0);
    }
  }
#pragma unroll
  for (int j = 0; j < 4; j++) {
    float4 a4; a4.x = acc[j][0]; a4.y = acc[j][1]; a4.z = acc[j][2]; a4.w = acc[j][3];
    *(float4*)&LO[wave][j][m16][quad * 4] = a4;
    if (lane < 16) LL[wave][j][lane] = acc2[j][0];
  }
  __syncthreads();
  if (wave < 4) {
    const int j = wave;
    float4 o = *(float4*)&LO[0][j][m16][quad * 4];
    float lt = LL[0][j][m16];
#pragma unroll
    for (int w2 = 1; w2 < 8; w2++) {
      float4 t = *(float4*)&LO[w2][j][m16][quad * 4];
      o.x += t.x; o.y += t.y; o.z += t.z; o.w += t.w;
      lt += LL[w2][j][m16];
    }
    float inv = 1.0f / fmaxf(lt, 1e-30f);
    float4 r4; r4.x = o.x * inv; r4.y = o.y * inv; r4.z = o.z * inv; r4.w = o.w * inv;
    *(float4*)(O + (size_t)(r0 + j * 16 + m16) * DM + h * 16 + quad * 4) = r4;
  }
}

// ---------------- FFN first GEMM with inline h = x+relu(ln1(T)) and ln2 ----------------
__global__ __launch_bounds__(256) void gemm_ffn1(
    const float* __restrict__ T, const float* __restrict__ X,
    const float* __restrict__ Gf, const float* __restrict__ Bef,
    const float* __restrict__ G2, const float* __restrict__ Be2,
    const float* __restrict__ W1, const float* __restrict__ B1,
    float* __restrict__ H, float* __restrict__ T1)
{
  __shared__ short Asm[64][40];
  __shared__ short Wsm[64][40];
  const int m0 = blockIdx.x * 64, n0 = blockIdx.y * 64;
  const int tid = threadIdx.x;
  const int srow = tid >> 2, koff = (tid & 3) * 8;
  const int lane = tid & 63, wave = tid >> 6;
  const int quad = lane >> 4, m16 = lane & 15;

  const float* trow = T + (size_t)(m0 + srow) * 128 + koff;
  const float* xrow = X + (size_t)(m0 + srow) * 128 + koff;
  float4 a0[4], a1[4];
#pragma unroll
  for (int c = 0; c < 4; c++) {
    a0[c] = *(const float4*)(trow + c * 32);
    a1[c] = *(const float4*)(trow + c * 32 + 4);
  }
  {
    float s = 0.f;
#pragma unroll
    for (int c = 0; c < 4; c++)
      s += a0[c].x + a0[c].y + a0[c].z + a0[c].w + a1[c].x + a1[c].y + a1[c].z + a1[c].w;
    s += __shfl_xor(s, 1); s += __shfl_xor(s, 2);
    float mean = s * (1.0f / 128.0f);
    float v = 0.f;
#pragma unroll
    for (int c = 0; c < 4; c++) {
      float d;
      d = a0[c].x - mean; v += d*d;  d = a0[c].y - mean; v += d*d;
      d = a0[c].z - mean; v += d*d;  d = a0[c].w - mean; v += d*d;
      d = a1[c].x - mean; v += d*d;  d = a1[c].y - mean; v += d*d;
      d = a1[c].z - mean; v += d*d;  d = a1[c].w - mean; v += d*d;
    }
    v += __shfl_xor(v, 1); v += __shfl_xor(v, 2);
    float rstd = rsqrtf(v * (1.0f / 128.0f) + 1e-5f);
#pragma unroll
    for (int c = 0; c < 4; c++) {
      const int col = c * 32 + koff;
      float4 gv0 = *(const float4*)(Gf + col),  gv1 = *(const float4*)(Gf + col + 4);
      float4 bv0 = *(const float4*)(Bef + col), bv1 = *(const float4*)(Bef + col + 4);
      float4 x0 = *(const float4*)(xrow + c * 32), x1 = *(const float4*)(xrow + c * 32 + 4);
      LN1(a0[c].x, gv0.x, bv0.x); LN1(a0[c].y, gv0.y, bv0.y);
      LN1(a0[c].z, gv0.z, bv0.z); LN1(a0[c].w, gv0.w, bv0.w);
      LN1(a1[c].x, gv1.x, bv1.x); LN1(a1[c].y, gv1.y, bv1.y);
      LN1(a1[c].z, gv1.z, bv1.z); LN1(a1[c].w, gv1.w, bv1.w);
      a0[c].x = x0.x + fmaxf(a0[c].x, 0.f); a0[c].y = x0.y + fmaxf(a0[c].y, 0.f);
      a0[c].z = x0.z + fmaxf(a0[c].z, 0.f); a0[c].w = x0.w + fmaxf(a0[c].w, 0.f);
      a1[c].x = x1.x + fmaxf(a1[c].x, 0.f); a1[c].y = x1.y + fmaxf(a1[c].y, 0.f);
      a1[c].z = x1.z + fmaxf(a1[c].z, 0.f); a1[c].w = x1.w + fmaxf(a1[c].w, 0.f);
      if (blockIdx.y == 0) {
        *(float4*)(H + (size_t)(m0 + srow) * 128 + c * 32 + koff)     = a0[c];
        *(float4*)(H + (size_t)(m0 + srow) * 128 + c * 32 + koff + 4) = a1[c];
      }
    }
  }
  {
    float s = 0.f;
#pragma unroll
    for (int c = 0; c < 4; c++)
      s += a0[c].x + a0[c].y + a0[c].z + a0[c].w + a1[c].x + a1[c].y + a1[c].z + a1[c].w;
    s += __shfl_xor(s, 1); s += __shfl_xor(s, 2);
    float mean = s * (1.0f / 128.0f);
    float v = 0.f;
#pragma unroll
    for (int c = 0; c < 4; c++) {
      float d;
      d = a0[c].x - mean; v += d*d;  d = a0[c].y - mean; v += d*d;
      d = a0[c].z - mean; v += d*d;  d = a0[c].w - mean; v += d*d;
      d = a1[c].x - mean; v += d*d;  d = a1[c].y - mean; v += d*d;
      d = a1[c].z - mean; v += d*d;  d = a1[c].w - mean; v += d*d;
    }
    v += __shfl_xor(v, 1); v += __shfl_xor(v, 2);
    float rstd = rsqrtf(v * (1.0f / 128.0f) + 1e-5f);
#pragma unroll
    for (int c = 0; c < 4; c++) {
      const int col = c * 32 + koff;
      float4 gv0 = *(const float4*)(G2 + col),  gv1 = *(const float4*)(G2 + col + 4);
      float4 bv0 = *(const float4*)(Be2 + col), bv1 = *(const float4*)(Be2 + col + 4);
      LN1(a0[c].x, gv0.x, bv0.x); LN1(a0[c].y, gv0.y, bv0.y);
      LN1(a0[c].z, gv0.z, bv0.z); LN1(a0[c].w, gv0.w, bv0.w);
      LN1(a1[c].x, gv1.x, bv1.x); LN1(a1[c].y, gv1.y, bv1.y);
      LN1(a1[c].z, gv1.z, bv1.z); LN1(a1[c].w, gv1.w, bv1.w);
    }
  }

  f32x4 acc[4];
#pragma unroll
  for (int i = 0; i < 4; i++) acc[i] = {0.f, 0.f, 0.f, 0.f};
#pragma unroll
  for (int c = 0; c < 4; c++) {
    const float* wp = W1 + (size_t)(n0 + srow) * 128 + c * 32 + koff;
    float4 w0 = *(const float4*)wp, w1v = *(const float4*)(wp + 4);
    __syncthreads();
    *(short8*)&Asm[srow][koff] = cvt8(a0[c], a1[c]);
    *(short8*)&Wsm[srow][koff] = cvt8(w0, w1v);
    __syncthreads();
    short8 af = *(short8*)&Asm[wave * 16 + m16][quad * 8];
#pragma unroll
    for (int nt = 0; nt < 4; nt++) {
      short8 bf = *(short8*)&Wsm[nt * 16 + m16][quad * 8];
      acc[nt] = __builtin_amdgcn_mfma_f32_16x16x32_bf16(af, bf, acc[nt], 0, 0, 0);
    }
  }
#pragma unroll
  for (int nt = 0; nt < 4; nt++) {
#pragma unroll
    for (int r = 0; r < 4; r++) {
      const int m = m0 + wave * 16 + quad * 4 + r;
      const int n = n0 + nt * 16 + m16;
      float v = acc[nt][r] + B1[n];
      v = 0.5f * v * (1.0f + erff(v * 0.70710678118654752f));
      T1[(size_t)m * 512 + n] = v;
    }
  }
}

// ---------------- edge attention, 8 lanes/edge (lane = head), raw exp ----------------
__global__ __launch_bounds__(256) void k_edge_attn8(const int* __restrict__ EI,
    const float* __restrict__ Q, const float* __restrict__ Kl,
    unsigned short* __restrict__ EB, int* __restrict__ deg) {
  int is64 = detect64(EI);
  int gid = blockIdx.x * 256 + threadIdx.x;
  int e = gid >> 3, hh = gid & 7;
  int s = is64 ? EI[2*e]      : EI[e];
  int d = is64 ? EI[2*(NE+e)] : EI[NE+e];
  s = min(max(s, 0), NN-1); d = min(max(d, 0), NN-1);
  const float4* qp = (const float4*)(Q  + (size_t)d * DM + hh * 16);
  const float4* kp = (const float4*)(Kl + (size_t)s * DM + hh * 16);
  float acc = 0.f;
#pragma unroll
  for (int c = 0; c < 4; c++) {
    float4 qa = qp[c], ka = kp[c];
    acc += qa.x*ka.x + qa.y*ka.y + qa.z*ka.z + qa.w*ka.w;
  }
  EB[(size_t)e*8 + hh] = f2bh(__builtin_amdgcn_exp2f(fminf(acc, 43.0f)));
  if (hh == 0) atomicAdd(&deg[d], 1);
}

// ---------------- CSR scan + scatter ----------------
__global__ __launch_bounds__(256) void k_scan(const int* __restrict__ deg,
    int* __restrict__ offs, int* __restrict__ cursor) {
  __shared__ int sums[256];
  int t = threadIdx.x;
  int loc[16];
  int s = 0;
#pragma unroll
  for (int i = 0; i < 16; i++) { loc[i] = s; s += deg[t*16 + i]; }
  sums[t] = s;
  __syncthreads();
  for (int d = 1; d < 256; d <<= 1) {
    int v = (t >= d) ? sums[t - d] : 0;
    __syncthreads();
    sums[t] += v;
    __syncthreads();
  }
  int base = sums[t] - s;
#pragma unroll
  for (int i = 0; i < 16; i++) {
    offs[t*16 + i] = base + loc[i];
    cursor[t*16 + i] = base + loc[i];
  }
}
__global__ __launch_bounds__(256) void k_scatter(const int* __restrict__ EI,
    int* __restrict__ cursor, int* __restrict__ elist) {
  int is64 = detect64(EI);
  int e = blockIdx.x * 256 + threadIdx.x;
  int d = is64 ? EI[2*(NE+e)] : EI[NE+e];
  d = min(max(d, 0), NN-1);
  int slot = atomicAdd(&cursor[d], 1);
  elist[slot] = e;
}

// ---------------- per-dst aggregation (atomic-free; 4x unrolled gather) ----------------
__global__ __launch_bounds__(256) void k_edge_agg2(const int* __restrict__ EI,
    const int* __restrict__ deg, const int* __restrict__ offs,
    const int* __restrict__ elist, const unsigned short* __restrict__ Vl,
    const unsigned short* __restrict__ EB, float* __restrict__ AG) {
  int is64 = detect64(EI);
  int d = blockIdx.x * 4 + (threadIdx.x >> 6);
  int lane = threadIdx.x & 63;
  int degd = deg[d], start = offs[d];
  int hh = lane >> 3;
  float ss = 0.f;
  for (int i = lane & 7; i < degd; i += 8)
    ss += b2f16(EB[(size_t)elist[start + i] * 8 + hh]);
  for (int o = 1; o < 8; o <<= 1) ss += __shfl_xor(ss, o);
  float inv = 1.0f / fmaxf(ss, 1e-30f);
  float ax = 0.f, ay = 0.f;
  int i = 0;
  for (; i + 4 <= degd; i += 4) {
    int e0 = elist[start+i], e1 = elist[start+i+1], e2 = elist[start+i+2], e3 = elist[start+i+3];
    int s0 = is64 ? EI[2*e0] : EI[e0];
    int s1 = is64 ? EI[2*e1] : EI[e1];
    int s2 = is64 ? EI[2*e2] : EI[e2];
    int s3 = is64 ? EI[2*e3] : EI[e3];
    s0 = min(max(s0,0),NN-1); s1 = min(max(s1,0),NN-1);
    s2 = min(max(s2,0),NN-1); s3 = min(max(s3,0),NN-1);
    float w0 = b2f16(EB[(size_t)e0*8 + hh]) * inv;
    float w1 = b2f16(EB[(size_t)e1*8 + hh]) * inv;
    float w2 = b2f16(EB[(size_t)e2*8 + hh]) * inv;
    float w3 = b2f16(EB[(size_t)e3*8 + hh]) * inv;
    unsigned v0 = *(const unsigned*)(Vl + (size_t)s0 * DM + 2 * lane);
    unsigned v1 = *(const unsigned*)(Vl + (size_t)s1 * DM + 2 * lane);
    unsigned v2 = *(const unsigned*)(Vl + (size_t)s2 * DM + 2 * lane);
    unsigned v3 = *(const unsigned*)(Vl + (size_t)s3 * DM + 2 * lane);
    ax += w0 * b2f16((unsigned short)(v0 & 0xffffu)) + w1 * b2f16((unsigned short)(v1 & 0xffffu))
        + w2 * b2f16((unsigned short)(v2 & 0xffffu)) + w3 * b2f16((unsigned short)(v3 & 0xffffu));
    ay += w0 * b2f16((unsigned short)(v0 >> 16)) + w1 * b2f16((unsigned short)(v1 >> 16))
        + w2 * b2f16((unsigned short)(v2 >> 16)) + w3 * b2f16((unsigned short)(v3 >> 16));
  }
  for (; i < degd; i++) {
    int e = elist[start + i];
    int s = is64 ? EI[2*e] : EI[e];
    s = min(max(s, 0), NN-1);
    float a = b2f16(EB[(size_t)e*8 + hh]) * inv;
    unsigned v = *(const unsigned*)(Vl + (size_t)s * DM + 2 * lane);
    ax += a * b2f16((unsigned short)(v & 0xffffu));
    ay += a * b2f16((unsigned short)(v >> 16));
  }
  float2 r; r.x = ax; r.y = ay;
  *(float2*)(AG + (size_t)d * DM + 2 * lane) = r;
}

extern "C" void kernel_launch(void* const* d_in, const int* in_sizes, int n_in,
                              void* d_out, int out_size, void* d_ws, size_t ws_size,
                              hipStream_t stream) {
  const float* x     = (const float*)d_in[0];
  const int*   ei    = (const int*)  d_in[1];
  const float* wq_l  = (const float*)d_in[2];  const float* bq_l = (const float*)d_in[3];
  const float* wk_l  = (const float*)d_in[4];  const float* bk_l = (const float*)d_in[5];
  const float* wv_l  = (const float*)d_in[6];  const float* bv_l = (const float*)d_in[7];
  const float* wg    = (const float*)d_in[8];  const float* bg   = (const float*)d_in[9];
  const float* wq_g  = (const float*)d_in[10]; const float* bq_g = (const float*)d_in[11];
  const float* wk_g  = (const float*)d_in[12]; const float* bk_g = (const float*)d_in[13];
  const float* wv_g  = (const float*)d_in[14]; const float* bv_g = (const float*)d_in[15];
  const float* wo_g  = (const float*)d_in[16]; const float* bo_g = (const float*)d_in[17];
  const float* wf    = (const float*)d_in[18]; const float* bff  = (const float*)d_in[19];
  const float* gf    = (const float*)d_in[20]; const float* betaf= (const float*)d_in[21];
  const float* w1    = (const float*)d_in[22]; const float* b1   = (const float*)d_in[23];
  const float* w2    = (const float*)d_in[24]; const float* b2   = (const float*)d_in[25];
  const float* g1    = (const float*)d_in[26]; const float* be1  = (const float*)d_in[27];
  const float* g2    = (const float*)d_in[28]; const float* be2  = (const float*)d_in[29];
  float* out = (float*)d_out;

  const size_t NEED = (size_t)3289088 * 4;
  if (ws_size < NEED) {
    k_fill<<<2048, 256, 0, stream>>>(out, 100.0f, NN*DM);
    return;
  }

  float* W = (float*)d_ws;
  float*          lQ    = W + 0;
  float*          lK    = W + 524288;
  unsigned short* lV    = (unsigned short*)(W + 1048576);
  unsigned short* eb    = (unsigned short*)(W + 1310720);
  float*          agg   = W + 1835008;
  unsigned short* qgb   = (unsigned short*)(W + 2359296);
  unsigned short* kgb   = (unsigned short*)(W + 2621440);
  unsigned short* vgT   = (unsigned short*)(W + 2883584);
  float*          go    = W + 0;
  float*          local_= W + 524288;
  float*          gop   = W + 1048576;
  float*          tmpf  = W + 2097152;
  float*          h     = W + 2621440;
  float*          t1    = W + 0;
  int* deg    = (int*)(W + 3145728);
  int* cursor = (int*)(W + 3149824);
  int* offs   = (int*)(W + 3153920);
  int* elist  = (int*)(W + 3158016);

  dim3 b256(256);

  hipMemsetAsync(deg, 0, 4096 * sizeof(int), stream);

  gemm_six<<<dim3(64,12), b256, 0, stream>>>(x, g1, be1,
      wq_l, wk_l, wv_l, wq_g, wk_g, wv_g,
      bq_l, bk_l, bv_l, bq_g, bk_g, bv_g,
      lQ, lK, lV, qgb, kgb, vgT);

  k_edge_attn8<<<4096, b256, 0, stream>>>(ei, lQ, lK, eb, deg);
  k_scan<<<1, b256, 0, stream>>>(deg, offs, cursor);
  k_scatter<<<512, b256, 0, stream>>>(ei, cursor, elist);
  k_edge_agg2<<<1024, b256, 0, stream>>>(ei, deg, offs, elist, lV, eb, agg);

  k_gattn7<<<512, dim3(512), 0, stream>>>(qgb, kgb, vgT, go);

  gemm_dual<<<dim3(64,4), b256, 0, stream>>>(x, agg, go, wg, bg, wo_g, bo_g, local_, gop);

  gemm_mfma<<<dim3(64,2), b256, 0, stream>>>(local_,128, gop,128,128, wf, bff,
      nullptr,nullptr,nullptr, tmpf, 128, 256, 0, 0, 1.f);

  gemm_ffn1<<<dim3(64,8), b256, 0, stream>>>(tmpf, x, gf, betaf, g2, be2, w1, b1, h, t1);
  gemm_mfma<<<dim3(64,2), b256, 0, stream>>>(t1,512, nullptr,0,512, w2, b2,
      h, nullptr,nullptr, out, 128, 512, 0, 0, 1.f);
}